// Round 1
// baseline (580.676 us; speedup 1.0000x reference)
//
#include <hip/hip_runtime.h>

#define N_NODES   50000
#define N_EDGES   800000
#define G_GRAPHS  512
#define D_IN      10
#define D_CL      6
#define HID       64
#define NH        4
#define C1        256   // NH*HID
#define D_OUT     4
#define BN_EPS    1e-5f

__device__ __forceinline__ float leaky(float x){ return x > 0.f ? x : 0.2f*x; }

// ---------------- K1: h1 = x@W1, e_src1/e_dst1 per node ----------------
__global__ __launch_bounds__(256) void k_node1(const float* __restrict__ x,
    const float* __restrict__ W1, const float* __restrict__ a1s, const float* __restrict__ a1d,
    float* __restrict__ h1, float* __restrict__ es1, float* __restrict__ ed1){
  __shared__ float W1s[D_IN*C1];
  __shared__ float as_s[C1], ad_s[C1];
  int t = threadIdx.x;
  for (int idx = t; idx < D_IN*C1; idx += 256) W1s[idx] = W1[idx];
  as_s[t] = a1s[t]; ad_s[t] = a1d[t];
  __syncthreads();
  int lane = t & 63, wid = t >> 6;
  for (int nn = 0; nn < 16; ++nn){
    int i = blockIdx.x*16 + nn;
    if (i >= N_NODES) return;
    const float* xr = x + (long)i*D_IN;
    float acc = 0.f;
    #pragma unroll
    for (int k = 0; k < D_IN; ++k) acc += xr[k]*W1s[k*C1 + t];
    h1[(long)i*C1 + t] = acc;
    float ps = acc*as_s[t], pd = acc*ad_s[t];
    #pragma unroll
    for (int o = 32; o >= 1; o >>= 1){ ps += __shfl_xor(ps,o); pd += __shfl_xor(pd,o); }
    if (lane == 0){ es1[i*NH + wid] = ps; ed1[i*NH + wid] = pd; }
  }
}

// ---------------- CSR build ----------------
__global__ void k_hist(const int* __restrict__ dst, int* __restrict__ cnt){
  int e = blockIdx.x*blockDim.x + threadIdx.x;
  if (e < N_EDGES) atomicAdd(&cnt[dst[e]], 1);
}

__global__ __launch_bounds__(1024) void k_scan1(const int* __restrict__ cnt, int* __restrict__ off, int* __restrict__ bsum){
  __shared__ int s[1024];
  int t = threadIdx.x;
  int i = blockIdx.x*1024 + t;
  int v = (i < N_NODES) ? cnt[i] : 0;
  s[t] = v;
  __syncthreads();
  for (int o = 1; o < 1024; o <<= 1){
    int xv = (t >= o) ? s[t-o] : 0;
    __syncthreads();
    s[t] += xv;
    __syncthreads();
  }
  if (i < N_NODES) off[i] = s[t] - v;
  if (t == 1023) bsum[blockIdx.x] = s[t];
}

__global__ void k_scan2(int* bsum, int nb){
  int lane = threadIdx.x;
  int v = (lane < nb) ? bsum[lane] : 0;
  int orig = v;
  for (int o = 1; o < 64; o <<= 1){
    int xv = __shfl_up(v, o);
    if (lane >= o) v += xv;
  }
  if (lane < nb) bsum[lane] = v - orig;
}

__global__ void k_scan3(int* __restrict__ off, const int* __restrict__ bsum){
  int i = blockIdx.x*blockDim.x + threadIdx.x;
  if (i < N_NODES) off[i] += bsum[i >> 10];
  if (i == 0) off[N_NODES] = N_EDGES;
}

__global__ void k_scatter(const int* __restrict__ src, const int* __restrict__ dst,
                          const int* __restrict__ off, int* __restrict__ cur, int* __restrict__ csr){
  int e = blockIdx.x*blockDim.x + threadIdx.x;
  if (e < N_EDGES){
    int d = dst[e];
    int r = atomicAdd(&cur[d], 1);
    csr[off[d] + r] = src[e];
  }
}

// ---------------- K3: layer-1 GAT aggregation, wave per dst ----------------
__global__ __launch_bounds__(256) void k_agg1(const float* __restrict__ h1,
    const float* __restrict__ es1, const float* __restrict__ ed1,
    const int* __restrict__ off, const int* __restrict__ csr,
    const float* __restrict__ b1, float* __restrict__ y1){
  int lane = threadIdx.x & 63, wid = threadIdx.x >> 6;
  int i = blockIdx.x*4 + wid;
  if (i >= N_NODES) return;
  int head = lane >> 4;
  float4 edv4 = *(const float4*)&ed1[i*NH];
  float4 esv4 = *(const float4*)&es1[i*NH];
  float m0 = leaky(esv4.x + edv4.x);
  float m1 = leaky(esv4.y + edv4.y);
  float m2 = leaky(esv4.z + edv4.z);
  float m3 = leaky(esv4.w + edv4.w);
  int start = off[i], end = off[i+1];
  for (int j = start + lane; j < end; j += 64){
    int s = csr[j];
    float4 es = *(const float4*)&es1[s*NH];
    m0 = fmaxf(m0, leaky(es.x + edv4.x));
    m1 = fmaxf(m1, leaky(es.y + edv4.y));
    m2 = fmaxf(m2, leaky(es.z + edv4.z));
    m3 = fmaxf(m3, leaky(es.w + edv4.w));
  }
  #pragma unroll
  for (int o = 32; o >= 1; o >>= 1){
    m0 = fmaxf(m0, __shfl_xor(m0,o));
    m1 = fmaxf(m1, __shfl_xor(m1,o));
    m2 = fmaxf(m2, __shfl_xor(m2,o));
    m3 = fmaxf(m3, __shfl_xor(m3,o));
  }
  float mh  = (head==0)?m0:(head==1)?m1:(head==2)?m2:m3;
  float edh = (head==0)?edv4.x:(head==1)?edv4.y:(head==2)?edv4.z:edv4.w;
  float esS = (head==0)?esv4.x:(head==1)?esv4.y:(head==2)?esv4.z:esv4.w;
  const float4* h1v = (const float4*)h1;
  // self loop
  float w = __expf(leaky(esS + edh) - mh);
  float ssum = w;
  float4 hv = h1v[(long)i*64 + lane];
  float ax = hv.x*w, ay = hv.y*w, az = hv.z*w, aw = hv.w*w;
  for (int j = start; j < end; ++j){
    int s = csr[j];
    float esv = es1[s*NH + head];
    float wj = __expf(leaky(esv + edh) - mh);
    float4 h = h1v[(long)s*64 + lane];
    ax += h.x*wj; ay += h.y*wj; az += h.z*wj; aw += h.w*wj;
    ssum += wj;
  }
  float inv = 1.f/(ssum + 1e-16f);
  float4 bb = *(const float4*)&b1[lane*4];
  float4 yo;
  yo.x = ax*inv + bb.x; yo.y = ay*inv + bb.y; yo.z = az*inv + bb.z; yo.w = aw*inv + bb.w;
  ((float4*)y1)[(long)i*64 + lane] = yo;
}

// ---------------- BN column stats ----------------
template<int C, int RPB>
__global__ __launch_bounds__(256) void k_colstats(const float* __restrict__ y, float* __restrict__ st){
  int c = threadIdx.x % C;
  int rl = threadIdx.x / C;
  const int rpb = 256 / C;
  long r0 = (long)blockIdx.x * RPB;
  float s = 0.f, q = 0.f;
  for (int r = rl; r < RPB; r += rpb){
    long rr = r0 + r;
    if (rr < N_NODES){ float v = y[rr*C + c]; s += v; q += v*v; }
  }
  atomicAdd(&st[c], s); atomicAdd(&st[C + c], q);
}

__global__ void k_prep(const float* __restrict__ st, const float* __restrict__ g, const float* __restrict__ be,
                       float* __restrict__ ss, int C){
  int c = blockIdx.x*blockDim.x + threadIdx.x;
  if (c < C){
    float mean = st[c] / (float)N_NODES;
    float var  = st[C + c] / (float)N_NODES - mean*mean;
    float sc = g[c] * rsqrtf(var + BN_EPS);
    ss[c] = sc;
    ss[C + c] = be[c] - mean*sc;
  }
}

// ---------------- K6: h2 = relu(bn(y1)) @ W2, 64x64 tile GEMM ----------------
__global__ __launch_bounds__(256) void k_gemm2(const float* __restrict__ y1, const float* __restrict__ W2,
    const float* __restrict__ ss1, float* __restrict__ h2){
  __shared__ float As[64][68];
  __shared__ float Bs[64][64];
  int t = threadIdx.x;
  int tx = t & 15, ty = t >> 4;
  long i0 = (long)blockIdx.x * 64;
  float acc[4][4] = {};
  for (int kc = 0; kc < C1; kc += 64){
    for (int idx = t; idx < 64*64; idx += 256){
      int r = idx >> 6, kk = idx & 63;
      long gi = i0 + r;
      int k = kc + kk;
      float v = 0.f;
      if (gi < N_NODES){
        v = y1[gi*C1 + k];
        v = fmaxf(v*ss1[k] + ss1[C1+k], 0.f);
      }
      As[r][kk] = v;
    }
    for (int idx = t; idx < 64*64; idx += 256){
      Bs[idx >> 6][idx & 63] = W2[(kc + (idx >> 6))*HID + (idx & 63)];
    }
    __syncthreads();
    #pragma unroll 8
    for (int kk = 0; kk < 64; ++kk){
      float a0 = As[4*ty+0][kk], a1 = As[4*ty+1][kk], a2 = As[4*ty+2][kk], a3 = As[4*ty+3][kk];
      float4 b = *(float4*)&Bs[kk][4*tx];
      acc[0][0] += a0*b.x; acc[0][1] += a0*b.y; acc[0][2] += a0*b.z; acc[0][3] += a0*b.w;
      acc[1][0] += a1*b.x; acc[1][1] += a1*b.y; acc[1][2] += a1*b.z; acc[1][3] += a1*b.w;
      acc[2][0] += a2*b.x; acc[2][1] += a2*b.y; acc[2][2] += a2*b.z; acc[2][3] += a2*b.w;
      acc[3][0] += a3*b.x; acc[3][1] += a3*b.y; acc[3][2] += a3*b.z; acc[3][3] += a3*b.w;
    }
    __syncthreads();
  }
  #pragma unroll
  for (int rr = 0; rr < 4; ++rr){
    long gi = i0 + 4*ty + rr;
    if (gi < N_NODES){
      #pragma unroll
      for (int cc = 0; cc < 4; ++cc) h2[gi*HID + 4*tx + cc] = acc[rr][cc];
    }
  }
}

// ---------------- e_src2 / e_dst2 ----------------
__global__ __launch_bounds__(256) void k_edge2(const float* __restrict__ h2,
    const float* __restrict__ a2s, const float* __restrict__ a2d,
    float* __restrict__ es2, float* __restrict__ ed2){
  int lane = threadIdx.x & 63, wid = threadIdx.x >> 6;
  int i = blockIdx.x*4 + wid;
  if (i >= N_NODES) return;
  float v = h2[(long)i*HID + lane];
  float ps = v*a2s[lane], pd = v*a2d[lane];
  #pragma unroll
  for (int o = 32; o >= 1; o >>= 1){ ps += __shfl_xor(ps,o); pd += __shfl_xor(pd,o); }
  if (lane == 0){ es2[i] = ps; ed2[i] = pd; }
}

// ---------------- K7: layer-2 GAT aggregation ----------------
__global__ __launch_bounds__(256) void k_agg2(const float* __restrict__ h2,
    const float* __restrict__ es2, const float* __restrict__ ed2,
    const int* __restrict__ off, const int* __restrict__ csr,
    const float* __restrict__ b2, float* __restrict__ y2){
  int lane = threadIdx.x & 63, wid = threadIdx.x >> 6;
  int i = blockIdx.x*4 + wid;
  if (i >= N_NODES) return;
  float edv = ed2[i];
  float esS = es2[i];
  float m = leaky(esS + edv);
  int start = off[i], end = off[i+1];
  for (int j = start + lane; j < end; j += 64)
    m = fmaxf(m, leaky(es2[csr[j]] + edv));
  #pragma unroll
  for (int o = 32; o >= 1; o >>= 1) m = fmaxf(m, __shfl_xor(m,o));
  float w = __expf(leaky(esS + edv) - m);
  float ssum = w;
  float acc = h2[(long)i*HID + lane]*w;
  for (int j = start; j < end; ++j){
    int s = csr[j];
    float wj = __expf(leaky(es2[s] + edv) - m);
    acc += h2[(long)s*HID + lane]*wj;
    ssum += wj;
  }
  y2[(long)i*HID + lane] = acc/(ssum + 1e-16f) + b2[lane];
}

// ---------------- climber MLP ----------------
__global__ void k_climber(const float* __restrict__ cl, const float* __restrict__ Wc,
                          const float* __restrict__ bc, float* __restrict__ cv){
  int idx = blockIdx.x*blockDim.x + threadIdx.x;
  if (idx < G_GRAPHS*HID){
    int g = idx >> 6, j = idx & 63;
    float a = bc[j];
    #pragma unroll
    for (int k = 0; k < D_CL; ++k) a += cl[g*D_CL + k]*Wc[k*HID + j];
    cv[idx] = fmaxf(a, 0.f);
  }
}

// ---------------- final: bn+relu, concat, 2-layer MLP ----------------
__global__ __launch_bounds__(256) void k_final(const float* __restrict__ y2,
    const float* __restrict__ ss2, const int* __restrict__ batch, const float* __restrict__ cv,
    const float* __restrict__ Wcl1, const float* __restrict__ bcl1,
    const float* __restrict__ Wcl2, const float* __restrict__ bcl2,
    float* __restrict__ out){
  __shared__ float W1s[2*HID*HID];
  __shared__ float W2s[HID*D_OUT];
  __shared__ float zs[4][2*HID];
  int t = threadIdx.x;
  for (int idx = t; idx < 2*HID*HID; idx += 256) W1s[idx] = Wcl1[idx];
  if (t < HID*D_OUT) W2s[t] = Wcl2[t];
  __syncthreads();
  int lane = t & 63, wid = t >> 6;
  int i = blockIdx.x*4 + wid;
  if (i >= N_NODES) return;
  float h = y2[(long)i*HID + lane];
  h = fmaxf(h*ss2[lane] + ss2[HID+lane], 0.f);
  int g = batch[i];
  zs[wid][lane] = h;
  zs[wid][HID+lane] = cv[g*HID + lane];
  // intra-wave LDS write->read is in-order; no barrier needed (per-wave buffer)
  float acc = bcl1[lane];
  #pragma unroll 8
  for (int k = 0; k < 2*HID; ++k) acc += zs[wid][k]*W1s[k*HID + lane];
  float z2 = fmaxf(acc, 0.f);
  float p0 = z2*W2s[lane*D_OUT+0];
  float p1 = z2*W2s[lane*D_OUT+1];
  float p2 = z2*W2s[lane*D_OUT+2];
  float p3 = z2*W2s[lane*D_OUT+3];
  #pragma unroll
  for (int o = 32; o >= 1; o >>= 1){
    p0 += __shfl_xor(p0,o); p1 += __shfl_xor(p1,o);
    p2 += __shfl_xor(p2,o); p3 += __shfl_xor(p3,o);
  }
  if (lane == 0){
    out[(long)i*D_OUT+0] = p0 + bcl2[0];
    out[(long)i*D_OUT+1] = p1 + bcl2[1];
    out[(long)i*D_OUT+2] = p2 + bcl2[2];
    out[(long)i*D_OUT+3] = p3 + bcl2[3];
  }
}

extern "C" void kernel_launch(void* const* d_in, const int* in_sizes, int n_in,
                              void* d_out, int out_size, void* d_ws, size_t ws_size,
                              hipStream_t stream){
  const float* x    = (const float*)d_in[0];
  const float* cl   = (const float*)d_in[1];
  const int*   ei   = (const int*)d_in[2];
  const int*   batch= (const int*)d_in[3];
  const float* W1   = (const float*)d_in[4];
  const float* a1s  = (const float*)d_in[5];
  const float* a1d  = (const float*)d_in[6];
  const float* b1   = (const float*)d_in[7];
  const float* g1   = (const float*)d_in[8];
  const float* be1  = (const float*)d_in[9];
  const float* W2   = (const float*)d_in[10];
  const float* a2s  = (const float*)d_in[11];
  const float* a2d  = (const float*)d_in[12];
  const float* b2   = (const float*)d_in[13];
  const float* g2   = (const float*)d_in[14];
  const float* be2  = (const float*)d_in[15];
  const float* Wc   = (const float*)d_in[16];
  const float* bc   = (const float*)d_in[17];
  const float* Wcl1 = (const float*)d_in[18];
  const float* bcl1 = (const float*)d_in[19];
  const float* Wcl2 = (const float*)d_in[20];
  const float* bcl2 = (const float*)d_in[21];
  const int* srcE = ei;
  const int* dstE = ei + N_EDGES;
  float* out = (float*)d_out;

  char* w = (char*)d_ws;
  auto take = [&](size_t bytes)->char*{ char* p = w; w += (bytes + 255) & ~(size_t)255; return p; };
  float* h1  = (float*)take((size_t)N_NODES*C1*4);
  float* y1  = (float*)take((size_t)N_NODES*C1*4);
  float* es1 = (float*)take((size_t)N_NODES*NH*4);
  float* ed1 = (float*)take((size_t)N_NODES*NH*4);
  float* es2 = (float*)take((size_t)N_NODES*4);
  float* ed2 = (float*)take((size_t)N_NODES*4);
  float* cv  = (float*)take((size_t)G_GRAPHS*HID*4);
  float* st1 = (float*)take(2*C1*4);
  float* st2 = (float*)take(2*HID*4);
  float* ss1 = (float*)take(2*C1*4);
  float* ss2 = (float*)take(2*HID*4);
  int* cnt  = (int*)take((size_t)N_NODES*4);
  int* off  = (int*)take((size_t)(N_NODES+1)*4);
  int* bsum = (int*)take(64*4);
  int* csr  = (int*)take((size_t)N_EDGES*4);
  // alias into dead h1 region after k_agg1
  float* h2 = h1;
  float* y2 = h1 + (size_t)N_NODES*HID;

  hipMemsetAsync(cnt, 0, (size_t)N_NODES*4, stream);
  hipMemsetAsync(st1, 0, 2*C1*4, stream);
  hipMemsetAsync(st2, 0, 2*HID*4, stream);

  k_node1<<<(N_NODES+15)/16, 256, 0, stream>>>(x, W1, a1s, a1d, h1, es1, ed1);
  k_hist<<<(N_EDGES+255)/256, 256, 0, stream>>>(dstE, cnt);
  const int NB1 = (N_NODES + 1023)/1024;
  k_scan1<<<NB1, 1024, 0, stream>>>(cnt, off, bsum);
  k_scan2<<<1, 64, 0, stream>>>(bsum, NB1);
  k_scan3<<<(N_NODES+1024)/1024, 1024, 0, stream>>>(off, bsum);
  hipMemsetAsync(cnt, 0, (size_t)N_NODES*4, stream);
  k_scatter<<<(N_EDGES+255)/256, 256, 0, stream>>>(srcE, dstE, off, cnt, csr);

  k_agg1<<<(N_NODES+3)/4, 256, 0, stream>>>(h1, es1, ed1, off, csr, b1, y1);
  k_colstats<C1,128><<<(N_NODES+127)/128, 256, 0, stream>>>(y1, st1);
  k_prep<<<1, 256, 0, stream>>>(st1, g1, be1, ss1, C1);
  k_gemm2<<<(N_NODES+63)/64, 256, 0, stream>>>(y1, W2, ss1, h2);
  k_edge2<<<(N_NODES+3)/4, 256, 0, stream>>>(h2, a2s, a2d, es2, ed2);
  k_agg2<<<(N_NODES+3)/4, 256, 0, stream>>>(h2, es2, ed2, off, csr, b2, y2);
  k_colstats<HID,128><<<(N_NODES+127)/128, 256, 0, stream>>>(y2, st2);
  k_prep<<<1, 64, 0, stream>>>(st2, g2, be2, ss2, HID);
  k_climber<<<(G_GRAPHS*HID+255)/256, 256, 0, stream>>>(cl, Wc, bc, cv);
  k_final<<<(N_NODES+3)/4, 256, 0, stream>>>(y2, ss2, batch, cv, Wcl1, bcl1, Wcl2, bcl2, out);
}

// Round 2
// 483.756 us; speedup vs baseline: 1.2003x; 1.2003x over previous
//
#include <hip/hip_runtime.h>

#define N_NODES   50000
#define N_EDGES   800000
#define G_GRAPHS  512
#define D_IN      10
#define D_CL      6
#define HID       64
#define NH        4
#define C1        256   // NH*HID
#define D_OUT     4
#define BN_EPS    1e-5f

typedef unsigned short ushort_t;
typedef unsigned int uint_t;

__device__ __forceinline__ float leaky(float x){ return x > 0.f ? x : 0.2f*x; }
__device__ __forceinline__ ushort_t f2bf(float f){
  unsigned u = __float_as_uint(f);
  return (ushort_t)((u + 0x7fffu + ((u >> 16) & 1u)) >> 16);
}
__device__ __forceinline__ float bflo(uint_t u){ return __uint_as_float(u << 16); }
__device__ __forceinline__ float bfhi(uint_t u){ return __uint_as_float(u & 0xffff0000u); }

// ---------------- K1: h1 = x@W1 (bf16 out), e_src1/e_dst1 per node ----------------
__global__ __launch_bounds__(256) void k_node1(const float* __restrict__ x,
    const float* __restrict__ W1, const float* __restrict__ a1s, const float* __restrict__ a1d,
    ushort_t* __restrict__ h1b, float* __restrict__ es1, float* __restrict__ ed1){
  __shared__ float W1s[D_IN*C1];
  __shared__ float as_s[C1], ad_s[C1];
  int t = threadIdx.x;
  for (int idx = t; idx < D_IN*C1; idx += 256) W1s[idx] = W1[idx];
  as_s[t] = a1s[t]; ad_s[t] = a1d[t];
  __syncthreads();
  int lane = t & 63, wid = t >> 6;
  for (int nn = 0; nn < 16; ++nn){
    int i = blockIdx.x*16 + nn;
    if (i >= N_NODES) return;
    const float* xr = x + (long)i*D_IN;
    float acc = 0.f;
    #pragma unroll
    for (int k = 0; k < D_IN; ++k) acc += xr[k]*W1s[k*C1 + t];
    h1b[(long)i*C1 + t] = f2bf(acc);
    float ps = acc*as_s[t], pd = acc*ad_s[t];
    #pragma unroll
    for (int o = 32; o >= 1; o >>= 1){ ps += __shfl_xor(ps,o); pd += __shfl_xor(pd,o); }
    if (lane == 0){ es1[i*NH + wid] = ps; ed1[i*NH + wid] = pd; }
  }
}

// ---------------- CSR build ----------------
__global__ void k_hist(const int* __restrict__ dst, int* __restrict__ cnt){
  int e = blockIdx.x*blockDim.x + threadIdx.x;
  if (e < N_EDGES) atomicAdd(&cnt[dst[e]], 1);
}

__global__ __launch_bounds__(1024) void k_scan1(const int* __restrict__ cnt, int* __restrict__ off, int* __restrict__ bsum){
  __shared__ int s[1024];
  int t = threadIdx.x;
  int i = blockIdx.x*1024 + t;
  int v = (i < N_NODES) ? cnt[i] : 0;
  s[t] = v;
  __syncthreads();
  for (int o = 1; o < 1024; o <<= 1){
    int xv = (t >= o) ? s[t-o] : 0;
    __syncthreads();
    s[t] += xv;
    __syncthreads();
  }
  if (i < N_NODES) off[i] = s[t] - v;
  if (t == 1023) bsum[blockIdx.x] = s[t];
}

__global__ void k_scan2(int* bsum, int nb){
  int lane = threadIdx.x;
  int v = (lane < nb) ? bsum[lane] : 0;
  int orig = v;
  for (int o = 1; o < 64; o <<= 1){
    int xv = __shfl_up(v, o);
    if (lane >= o) v += xv;
  }
  if (lane < nb) bsum[lane] = v - orig;
}

__global__ void k_scan3(int* __restrict__ off, const int* __restrict__ bsum){
  int i = blockIdx.x*blockDim.x + threadIdx.x;
  if (i < N_NODES) off[i] += bsum[i >> 10];
  if (i == 0) off[N_NODES] = N_EDGES;
}

__global__ void k_scatter(const int* __restrict__ src, const int* __restrict__ dst,
                          const int* __restrict__ off, int* __restrict__ cur, int* __restrict__ csr){
  int e = blockIdx.x*blockDim.x + threadIdx.x;
  if (e < N_EDGES){
    int d = dst[e];
    int r = atomicAdd(&cur[d], 1);
    csr[off[d] + r] = src[e];
  }
}

// ---------------- K3: layer-1 GAT aggregation, wave per dst, bf16 rows ----------------
__global__ __launch_bounds__(256) void k_agg1(const ushort_t* __restrict__ h1b,
    const float* __restrict__ es1, const float* __restrict__ ed1,
    const int* __restrict__ off, const int* __restrict__ csr,
    const float* __restrict__ b1, float* __restrict__ y1){
  int lane = threadIdx.x & 63, wid = threadIdx.x >> 6;
  int i = blockIdx.x*4 + wid;
  if (i >= N_NODES) return;
  int head = lane >> 4;
  float4 edv4 = *(const float4*)&ed1[i*NH];
  float4 esv4 = *(const float4*)&es1[i*NH];
  float m0 = leaky(esv4.x + edv4.x);
  float m1 = leaky(esv4.y + edv4.y);
  float m2 = leaky(esv4.z + edv4.z);
  float m3 = leaky(esv4.w + edv4.w);
  int start = off[i], end = off[i+1];
  for (int j = start + lane; j < end; j += 64){
    int s = csr[j];
    float4 es = *(const float4*)&es1[s*NH];
    m0 = fmaxf(m0, leaky(es.x + edv4.x));
    m1 = fmaxf(m1, leaky(es.y + edv4.y));
    m2 = fmaxf(m2, leaky(es.z + edv4.z));
    m3 = fmaxf(m3, leaky(es.w + edv4.w));
  }
  #pragma unroll
  for (int o = 32; o >= 1; o >>= 1){
    m0 = fmaxf(m0, __shfl_xor(m0,o));
    m1 = fmaxf(m1, __shfl_xor(m1,o));
    m2 = fmaxf(m2, __shfl_xor(m2,o));
    m3 = fmaxf(m3, __shfl_xor(m3,o));
  }
  float mh  = (head==0)?m0:(head==1)?m1:(head==2)?m2:m3;
  float edh = (head==0)?edv4.x:(head==1)?edv4.y:(head==2)?edv4.z:edv4.w;
  float esS = (head==0)?esv4.x:(head==1)?esv4.y:(head==2)?esv4.z:esv4.w;
  const uint2* h1v = (const uint2*)h1b;   // row = 64 x uint2 (4 bf16 per lane)
  // self loop
  float w = __expf(leaky(esS + edh) - mh);
  float ssum = w;
  uint2 hv = h1v[(long)i*64 + lane];
  float ax = bflo(hv.x)*w, ay = bfhi(hv.x)*w, az = bflo(hv.y)*w, aw = bfhi(hv.y)*w;
  int j = start;
  for (; j + 3 < end; j += 4){
    int s0 = csr[j], s1 = csr[j+1], s2 = csr[j+2], s3 = csr[j+3];
    uint2 r0 = h1v[(long)s0*64 + lane];
    uint2 r1 = h1v[(long)s1*64 + lane];
    uint2 r2 = h1v[(long)s2*64 + lane];
    uint2 r3 = h1v[(long)s3*64 + lane];
    float w0 = __expf(leaky(es1[s0*NH + head] + edh) - mh);
    float w1 = __expf(leaky(es1[s1*NH + head] + edh) - mh);
    float w2 = __expf(leaky(es1[s2*NH + head] + edh) - mh);
    float w3 = __expf(leaky(es1[s3*NH + head] + edh) - mh);
    ax += bflo(r0.x)*w0; ay += bfhi(r0.x)*w0; az += bflo(r0.y)*w0; aw += bfhi(r0.y)*w0;
    ax += bflo(r1.x)*w1; ay += bfhi(r1.x)*w1; az += bflo(r1.y)*w1; aw += bfhi(r1.y)*w1;
    ax += bflo(r2.x)*w2; ay += bfhi(r2.x)*w2; az += bflo(r2.y)*w2; aw += bfhi(r2.y)*w2;
    ax += bflo(r3.x)*w3; ay += bfhi(r3.x)*w3; az += bflo(r3.y)*w3; aw += bfhi(r3.y)*w3;
    ssum += w0 + w1 + w2 + w3;
  }
  for (; j < end; ++j){
    int s = csr[j];
    uint2 r = h1v[(long)s*64 + lane];
    float wj = __expf(leaky(es1[s*NH + head] + edh) - mh);
    ax += bflo(r.x)*wj; ay += bfhi(r.x)*wj; az += bflo(r.y)*wj; aw += bfhi(r.y)*wj;
    ssum += wj;
  }
  float inv = 1.f/(ssum + 1e-16f);
  float4 bb = *(const float4*)&b1[lane*4];
  float4 yo;
  yo.x = ax*inv + bb.x; yo.y = ay*inv + bb.y; yo.z = az*inv + bb.z; yo.w = aw*inv + bb.w;
  ((float4*)y1)[(long)i*64 + lane] = yo;
}

// ---------------- BN column stats ----------------
template<int C, int RPB>
__global__ __launch_bounds__(256) void k_colstats(const float* __restrict__ y, float* __restrict__ st){
  int c = threadIdx.x % C;
  int rl = threadIdx.x / C;
  const int rpb = 256 / C;
  long r0 = (long)blockIdx.x * RPB;
  float s = 0.f, q = 0.f;
  for (int r = rl; r < RPB; r += rpb){
    long rr = r0 + r;
    if (rr < N_NODES){ float v = y[rr*C + c]; s += v; q += v*v; }
  }
  atomicAdd(&st[c], s); atomicAdd(&st[C + c], q);
}

__global__ void k_prep(const float* __restrict__ st, const float* __restrict__ g, const float* __restrict__ be,
                       float* __restrict__ ss, int C){
  int c = blockIdx.x*blockDim.x + threadIdx.x;
  if (c < C){
    float mean = st[c] / (float)N_NODES;
    float var  = st[C + c] / (float)N_NODES - mean*mean;
    float sc = g[c] * rsqrtf(var + BN_EPS);
    ss[c] = sc;
    ss[C + c] = be[c] - mean*sc;
  }
}

// ---------------- K6: h2 = relu(bn(y1)) @ W2 (bf16 out) + fused es2/ed2 ----------------
__global__ __launch_bounds__(256) void k_gemm2(const float* __restrict__ y1, const float* __restrict__ W2,
    const float* __restrict__ ss1, const float* __restrict__ a2s, const float* __restrict__ a2d,
    ushort_t* __restrict__ h2b, float* __restrict__ es2, float* __restrict__ ed2){
  __shared__ float As[64][68];
  __shared__ float Bs[64][64];
  __shared__ float as_s[HID], ad_s[HID];
  int t = threadIdx.x;
  if (t < HID){ as_s[t] = a2s[t]; ad_s[t] = a2d[t]; }
  int tx = t & 15, ty = t >> 4;
  long i0 = (long)blockIdx.x * 64;
  float acc[4][4] = {};
  for (int kc = 0; kc < C1; kc += 64){
    for (int idx = t; idx < 64*64; idx += 256){
      int r = idx >> 6, kk = idx & 63;
      long gi = i0 + r;
      int k = kc + kk;
      float v = 0.f;
      if (gi < N_NODES){
        v = y1[gi*C1 + k];
        v = fmaxf(v*ss1[k] + ss1[C1+k], 0.f);
      }
      As[r][kk] = v;
    }
    for (int idx = t; idx < 64*64; idx += 256){
      Bs[idx >> 6][idx & 63] = W2[(kc + (idx >> 6))*HID + (idx & 63)];
    }
    __syncthreads();
    #pragma unroll 8
    for (int kk = 0; kk < 64; ++kk){
      float a0 = As[4*ty+0][kk], a1 = As[4*ty+1][kk], a2 = As[4*ty+2][kk], a3 = As[4*ty+3][kk];
      float4 b = *(float4*)&Bs[kk][4*tx];
      acc[0][0] += a0*b.x; acc[0][1] += a0*b.y; acc[0][2] += a0*b.z; acc[0][3] += a0*b.w;
      acc[1][0] += a1*b.x; acc[1][1] += a1*b.y; acc[1][2] += a1*b.z; acc[1][3] += a1*b.w;
      acc[2][0] += a2*b.x; acc[2][1] += a2*b.y; acc[2][2] += a2*b.z; acc[2][3] += a2*b.w;
      acc[3][0] += a3*b.x; acc[3][1] += a3*b.y; acc[3][2] += a3*b.z; acc[3][3] += a3*b.w;
    }
    __syncthreads();
  }
  #pragma unroll
  for (int rr = 0; rr < 4; ++rr){
    long gi = i0 + 4*ty + rr;
    if (gi < N_NODES){
      uint_t p0 = (uint_t)f2bf(acc[rr][0]) | ((uint_t)f2bf(acc[rr][1]) << 16);
      uint_t p1 = (uint_t)f2bf(acc[rr][2]) | ((uint_t)f2bf(acc[rr][3]) << 16);
      *(uint2*)&h2b[gi*HID + 4*tx] = make_uint2(p0, p1);
      // fused e_src2/e_dst2: row-dot with a2s/a2d, reduce across the 16 tx lanes
      float ps = acc[rr][0]*as_s[4*tx+0] + acc[rr][1]*as_s[4*tx+1]
               + acc[rr][2]*as_s[4*tx+2] + acc[rr][3]*as_s[4*tx+3];
      float pd = acc[rr][0]*ad_s[4*tx+0] + acc[rr][1]*ad_s[4*tx+1]
               + acc[rr][2]*ad_s[4*tx+2] + acc[rr][3]*ad_s[4*tx+3];
      #pragma unroll
      for (int o = 8; o >= 1; o >>= 1){ ps += __shfl_xor(ps,o); pd += __shfl_xor(pd,o); }
      if (tx == 0){ es2[gi] = ps; ed2[gi] = pd; }
    }
  }
}

// ---------------- K7: layer-2 GAT aggregation (bf16 rows, 2 edges/wave-iter) ----------------
__global__ __launch_bounds__(256) void k_agg2(const ushort_t* __restrict__ h2b,
    const float* __restrict__ es2, const float* __restrict__ ed2,
    const int* __restrict__ off, const int* __restrict__ csr,
    const float* __restrict__ b2, float* __restrict__ y2){
  int lane = threadIdx.x & 63, wid = threadIdx.x >> 6;
  int i = blockIdx.x*4 + wid;
  if (i >= N_NODES) return;
  int lh = lane & 31, hh = lane >> 5;
  float edv = ed2[i];
  float esS = es2[i];
  float m = leaky(esS + edv);
  int start = off[i], end = off[i+1];
  for (int j = start + lane; j < end; j += 64)
    m = fmaxf(m, leaky(es2[csr[j]] + edv));
  #pragma unroll
  for (int o = 32; o >= 1; o >>= 1) m = fmaxf(m, __shfl_xor(m,o));
  const uint_t* h2u = (const uint_t*)h2b;   // row = 32 x uint (2 bf16); half-wave per row
  float acc0, acc1, ssum;
  {
    float wS = __expf(leaky(esS + edv) - m);
    uint_t uS = h2u[(long)i*32 + lh];
    if (hh == 0){ acc0 = bflo(uS)*wS; acc1 = bfhi(uS)*wS; ssum = wS; }
    else        { acc0 = 0.f; acc1 = 0.f; ssum = 0.f; }
  }
  for (int j = start; j < end; j += 4){
    int je0 = j + hh, je1 = j + 2 + hh;
    if (je0 < end){
      int s = csr[je0];
      float w = __expf(leaky(es2[s] + edv) - m);
      uint_t u = h2u[(long)s*32 + lh];
      acc0 += bflo(u)*w; acc1 += bfhi(u)*w; ssum += w;
    }
    if (je1 < end){
      int s = csr[je1];
      float w = __expf(leaky(es2[s] + edv) - m);
      uint_t u = h2u[(long)s*32 + lh];
      acc0 += bflo(u)*w; acc1 += bfhi(u)*w; ssum += w;
    }
  }
  acc0 += __shfl_xor(acc0, 32);
  acc1 += __shfl_xor(acc1, 32);
  ssum += __shfl_xor(ssum, 32);
  if (hh == 0){
    float inv = 1.f/(ssum + 1e-16f);
    float2 o;
    o.x = acc0*inv + b2[2*lh];
    o.y = acc1*inv + b2[2*lh+1];
    ((float2*)y2)[(long)i*32 + lh] = o;
  }
}

// ---------------- climber MLP ----------------
__global__ void k_climber(const float* __restrict__ cl, const float* __restrict__ Wc,
                          const float* __restrict__ bc, float* __restrict__ cv){
  int idx = blockIdx.x*blockDim.x + threadIdx.x;
  if (idx < G_GRAPHS*HID){
    int g = idx >> 6, j = idx & 63;
    float a = bc[j];
    #pragma unroll
    for (int k = 0; k < D_CL; ++k) a += cl[g*D_CL + k]*Wc[k*HID + j];
    cv[idx] = fmaxf(a, 0.f);
  }
}

// ---------------- final: bn+relu, concat, 2-layer MLP ----------------
__global__ __launch_bounds__(256) void k_final(const float* __restrict__ y2,
    const float* __restrict__ ss2, const int* __restrict__ batch, const float* __restrict__ cv,
    const float* __restrict__ Wcl1, const float* __restrict__ bcl1,
    const float* __restrict__ Wcl2, const float* __restrict__ bcl2,
    float* __restrict__ out){
  __shared__ float W1s[2*HID*HID];
  __shared__ float W2s[HID*D_OUT];
  __shared__ float zs[4][2*HID];
  int t = threadIdx.x;
  for (int idx = t; idx < 2*HID*HID; idx += 256) W1s[idx] = Wcl1[idx];
  if (t < HID*D_OUT) W2s[t] = Wcl2[t];
  __syncthreads();
  int lane = t & 63, wid = t >> 6;
  int i = blockIdx.x*4 + wid;
  if (i >= N_NODES) return;
  float h = y2[(long)i*HID + lane];
  h = fmaxf(h*ss2[lane] + ss2[HID+lane], 0.f);
  int g = batch[i];
  zs[wid][lane] = h;
  zs[wid][HID+lane] = cv[g*HID + lane];
  // intra-wave LDS write->read is in-order; no barrier needed (per-wave buffer)
  float acc = bcl1[lane];
  #pragma unroll 8
  for (int k = 0; k < 2*HID; ++k) acc += zs[wid][k]*W1s[k*HID + lane];
  float z2 = fmaxf(acc, 0.f);
  float p0 = z2*W2s[lane*D_OUT+0];
  float p1 = z2*W2s[lane*D_OUT+1];
  float p2 = z2*W2s[lane*D_OUT+2];
  float p3 = z2*W2s[lane*D_OUT+3];
  #pragma unroll
  for (int o = 32; o >= 1; o >>= 1){
    p0 += __shfl_xor(p0,o); p1 += __shfl_xor(p1,o);
    p2 += __shfl_xor(p2,o); p3 += __shfl_xor(p3,o);
  }
  if (lane == 0){
    out[(long)i*D_OUT+0] = p0 + bcl2[0];
    out[(long)i*D_OUT+1] = p1 + bcl2[1];
    out[(long)i*D_OUT+2] = p2 + bcl2[2];
    out[(long)i*D_OUT+3] = p3 + bcl2[3];
  }
}

extern "C" void kernel_launch(void* const* d_in, const int* in_sizes, int n_in,
                              void* d_out, int out_size, void* d_ws, size_t ws_size,
                              hipStream_t stream){
  const float* x    = (const float*)d_in[0];
  const float* cl   = (const float*)d_in[1];
  const int*   ei   = (const int*)d_in[2];
  const int*   batch= (const int*)d_in[3];
  const float* W1   = (const float*)d_in[4];
  const float* a1s  = (const float*)d_in[5];
  const float* a1d  = (const float*)d_in[6];
  const float* b1   = (const float*)d_in[7];
  const float* g1   = (const float*)d_in[8];
  const float* be1  = (const float*)d_in[9];
  const float* W2   = (const float*)d_in[10];
  const float* a2s  = (const float*)d_in[11];
  const float* a2d  = (const float*)d_in[12];
  const float* b2   = (const float*)d_in[13];
  const float* g2   = (const float*)d_in[14];
  const float* be2  = (const float*)d_in[15];
  const float* Wc   = (const float*)d_in[16];
  const float* bc   = (const float*)d_in[17];
  const float* Wcl1 = (const float*)d_in[18];
  const float* bcl1 = (const float*)d_in[19];
  const float* Wcl2 = (const float*)d_in[20];
  const float* bcl2 = (const float*)d_in[21];
  const int* srcE = ei;
  const int* dstE = ei + N_EDGES;
  float* out = (float*)d_out;

  char* w = (char*)d_ws;
  auto take = [&](size_t bytes)->char*{ char* p = w; w += (bytes + 255) & ~(size_t)255; return p; };
  ushort_t* h1b = (ushort_t*)take((size_t)N_NODES*C1*2);   // 25.6 MB, dead after k_agg1
  float* y1  = (float*)take((size_t)N_NODES*C1*4);
  float* es1 = (float*)take((size_t)N_NODES*NH*4);
  float* ed1 = (float*)take((size_t)N_NODES*NH*4);
  float* es2 = (float*)take((size_t)N_NODES*4);
  float* ed2 = (float*)take((size_t)N_NODES*4);
  float* cv  = (float*)take((size_t)G_GRAPHS*HID*4);
  float* st1 = (float*)take(2*C1*4);
  float* st2 = (float*)take(2*HID*4);
  float* ss1 = (float*)take(2*C1*4);
  float* ss2 = (float*)take(2*HID*4);
  int* cnt  = (int*)take((size_t)N_NODES*4);
  int* off  = (int*)take((size_t)(N_NODES+1)*4);
  int* bsum = (int*)take(64*4);
  int* csr  = (int*)take((size_t)N_EDGES*4);
  // alias into dead h1b region after k_agg1: h2b (6.4 MB) at 0, y2 (12.8 MB) at +8 MB
  ushort_t* h2b = h1b;
  float* y2 = (float*)((char*)h1b + ((size_t)8 << 20));

  hipMemsetAsync(cnt, 0, (size_t)N_NODES*4, stream);
  hipMemsetAsync(st1, 0, 2*C1*4, stream);
  hipMemsetAsync(st2, 0, 2*HID*4, stream);

  k_node1<<<(N_NODES+15)/16, 256, 0, stream>>>(x, W1, a1s, a1d, h1b, es1, ed1);
  k_hist<<<(N_EDGES+255)/256, 256, 0, stream>>>(dstE, cnt);
  const int NB1 = (N_NODES + 1023)/1024;
  k_scan1<<<NB1, 1024, 0, stream>>>(cnt, off, bsum);
  k_scan2<<<1, 64, 0, stream>>>(bsum, NB1);
  k_scan3<<<(N_NODES+1024)/1024, 1024, 0, stream>>>(off, bsum);
  hipMemsetAsync(cnt, 0, (size_t)N_NODES*4, stream);
  k_scatter<<<(N_EDGES+255)/256, 256, 0, stream>>>(srcE, dstE, off, cnt, csr);

  k_agg1<<<(N_NODES+3)/4, 256, 0, stream>>>(h1b, es1, ed1, off, csr, b1, y1);
  k_colstats<C1,128><<<(N_NODES+127)/128, 256, 0, stream>>>(y1, st1);
  k_prep<<<1, 256, 0, stream>>>(st1, g1, be1, ss1, C1);
  k_gemm2<<<(N_NODES+63)/64, 256, 0, stream>>>(y1, W2, ss1, a2s, a2d, h2b, es2, ed2);
  k_agg2<<<(N_NODES+3)/4, 256, 0, stream>>>(h2b, es2, ed2, off, csr, b2, y2);
  k_colstats<HID,128><<<(N_NODES+127)/128, 256, 0, stream>>>(y2, st2);
  k_prep<<<1, 64, 0, stream>>>(st2, g2, be2, ss2, HID);
  k_climber<<<(G_GRAPHS*HID+255)/256, 256, 0, stream>>>(cl, Wc, bc, cv);
  k_final<<<(N_NODES+3)/4, 256, 0, stream>>>(y2, ss2, batch, cv, Wcl1, bcl1, Wcl2, bcl2, out);
}

// Round 5
// 474.723 us; speedup vs baseline: 1.2232x; 1.0190x over previous
//
#include <hip/hip_runtime.h>

#define N_NODES   50000
#define N_EDGES   800000
#define G_GRAPHS  512
#define D_IN      10
#define D_CL      6
#define HID       64
#define NH        4
#define C1        256   // NH*HID
#define D_OUT     4
#define BN_EPS    1e-5f
#define CNT_PAD   53248  // 52*1024, padded count buffer for vectorized scan

typedef unsigned short ushort_t;
typedef unsigned int uint_t;

__device__ __forceinline__ float leaky(float x){ return x > 0.f ? x : 0.2f*x; }
__device__ __forceinline__ ushort_t f2bf(float f){
  unsigned u = __float_as_uint(f);
  return (ushort_t)((u + 0x7fffu + ((u >> 16) & 1u)) >> 16);
}
__device__ __forceinline__ float bflo(uint_t u){ return __uint_as_float(u << 16); }
__device__ __forceinline__ float bfhi(uint_t u){ return __uint_as_float(u & 0xffff0000u); }
__device__ __forceinline__ uint_t pack2(float a, float b){
  return (uint_t)f2bf(a) | ((uint_t)f2bf(b) << 16);
}

// ---------------- K1: h1 = x@W1 (bf16 out), e_src1/e_dst1 per node ----------------
__global__ __launch_bounds__(256) void k_node1(const float* __restrict__ x,
    const float* __restrict__ W1, const float* __restrict__ a1s, const float* __restrict__ a1d,
    ushort_t* __restrict__ h1b, float* __restrict__ es1, float* __restrict__ ed1){
  __shared__ float W1s[D_IN*C1];
  __shared__ float as_s[C1], ad_s[C1];
  int t = threadIdx.x;
  for (int idx = t; idx < D_IN*C1; idx += 256) W1s[idx] = W1[idx];
  as_s[t] = a1s[t]; ad_s[t] = a1d[t];
  __syncthreads();
  int lane = t & 63, wid = t >> 6;
  for (int nn = 0; nn < 16; ++nn){
    int i = blockIdx.x*16 + nn;
    if (i >= N_NODES) return;
    const float* xr = x + (long)i*D_IN;
    float acc = 0.f;
    #pragma unroll
    for (int k = 0; k < D_IN; ++k) acc += xr[k]*W1s[k*C1 + t];
    h1b[(long)i*C1 + t] = f2bf(acc);
    float ps = acc*as_s[t], pd = acc*ad_s[t];
    #pragma unroll
    for (int o = 32; o >= 1; o >>= 1){ ps += __shfl_xor(ps,o); pd += __shfl_xor(pd,o); }
    if (lane == 0){ es1[i*NH + wid] = ps; ed1[i*NH + wid] = pd; }
  }
}

// ---------------- CSR build ----------------
__global__ void k_hist(const int* __restrict__ dst, int* __restrict__ cnt){
  int e = blockIdx.x*blockDim.x + threadIdx.x;
  if (e < N_EDGES) atomicAdd(&cnt[dst[e]], 1);
}

// single-block vectorized scan; also re-zeroes cnt for use as scatter cursor
__global__ __launch_bounds__(1024) void k_scan(int* __restrict__ cnt, int* __restrict__ off){
  __shared__ int sh[1024];
  int t = threadIdx.x;
  int4 v[13];
  const int4* c4 = (const int4*)cnt;
  int base4 = t*13;
  int tsum = 0;
  #pragma unroll
  for (int k = 0; k < 13; ++k){
    v[k] = c4[base4 + k];
    tsum += v[k].x + v[k].y + v[k].z + v[k].w;
  }
  sh[t] = tsum;
  __syncthreads();
  for (int o = 1; o < 1024; o <<= 1){
    int xv = (t >= o) ? sh[t-o] : 0;
    __syncthreads();
    sh[t] += xv;
    __syncthreads();
  }
  int run = sh[t] - tsum;   // exclusive prefix of this thread's chunk
  int4* o4 = (int4*)off;
  int base = t*52;
  #pragma unroll
  for (int k = 0; k < 13; ++k){
    int i = base + k*4;
    int4 w_;
    w_.x = run; run += v[k].x;
    w_.y = run; run += v[k].y;
    w_.z = run; run += v[k].z;
    w_.w = run; run += v[k].w;
    if (i + 3 < N_NODES) o4[base4 + k] = w_;
    else {
      if (i+0 < N_NODES) off[i+0] = w_.x;
      if (i+1 < N_NODES) off[i+1] = w_.y;
      if (i+2 < N_NODES) off[i+2] = w_.z;
      if (i+3 < N_NODES) off[i+3] = w_.w;
    }
  }
  int4 z = make_int4(0,0,0,0);
  int4* cz = (int4*)cnt;
  #pragma unroll
  for (int k = 0; k < 13; ++k) cz[base4 + k] = z;
  if (t == 0) off[N_NODES] = N_EDGES;
}

__global__ void k_scatter(const int* __restrict__ src, const int* __restrict__ dst,
                          const int* __restrict__ off, int* __restrict__ cur, int* __restrict__ csr){
  int e = blockIdx.x*blockDim.x + threadIdx.x;
  if (e < N_EDGES){
    int d = dst[e];
    int r = atomicAdd(&cur[d], 1);
    csr[off[d] + r] = src[e];
  }
}

// ---------------- K3: layer-1 GAT aggregation, wave per dst ----------------
// No max-subtraction (logits bounded; softmax shift-invariant).
// Weight phase: lane e*4+h computes w(edge e, head h) for a 16-edge chunk;
// accumulate phase pulls weights via shuffle. ALL loops are wave-uniform
// (nj, jj uniform) so every __shfl executes with all 64 lanes active.
__global__ __launch_bounds__(256) void k_agg1(const ushort_t* __restrict__ h1b,
    const float* __restrict__ es1, const float* __restrict__ ed1,
    const int* __restrict__ off, const int* __restrict__ csr,
    const float* __restrict__ b1, ushort_t* __restrict__ y1b){
  int lane = threadIdx.x & 63, wid = threadIdx.x >> 6;
  int i = blockIdx.x*4 + wid;
  if (i >= N_NODES) return;
  int head = lane >> 4;           // my output head (channels 4*lane..4*lane+3)
  int h    = lane & 3;            // weight-phase head
  int e    = lane >> 2;           // weight-phase edge slot (0..15)
  float4 edv4 = *(const float4*)&ed1[i*NH];
  float4 esv4 = *(const float4*)&es1[i*NH];
  float edh   = (head==0)?edv4.x:(head==1)?edv4.y:(head==2)?edv4.z:edv4.w;
  float esS   = (head==0)?esv4.x:(head==1)?esv4.y:(head==2)?esv4.z:esv4.w;
  float edw   = (h==0)?edv4.x:(h==1)?edv4.y:(h==2)?edv4.z:edv4.w;
  int start = off[i], end = off[i+1];
  const uint2* h1v = (const uint2*)h1b;
  // self loop
  float wS = __expf(leaky(esS + edh));
  float ssum = wS;
  uint2 hv = h1v[(long)i*64 + lane];
  float ax = bflo(hv.x)*wS, ay = bfhi(hv.x)*wS, az = bflo(hv.y)*wS, aw = bfhi(hv.y)*wS;
  for (int j0 = start; j0 < end; j0 += 16){
    int nj = end - j0; if (nj > 16) nj = 16;
    int ce = (e < nj) ? e : nj - 1;
    int sE = csr[j0 + ce];
    float wv = (e < nj) ? __expf(leaky(es1[sE*NH + h] + edw)) : 0.f;
    int jj = 0;
    for (; jj + 3 < nj; jj += 4){
      int s0 = __shfl(sE, (jj+0)<<2);
      int s1 = __shfl(sE, (jj+1)<<2);
      int s2 = __shfl(sE, (jj+2)<<2);
      int s3 = __shfl(sE, (jj+3)<<2);
      float w0 = __shfl(wv, ((jj+0)<<2) | head);
      float w1 = __shfl(wv, ((jj+1)<<2) | head);
      float w2 = __shfl(wv, ((jj+2)<<2) | head);
      float w3 = __shfl(wv, ((jj+3)<<2) | head);
      uint2 r0 = h1v[(long)s0*64 + lane];
      uint2 r1 = h1v[(long)s1*64 + lane];
      uint2 r2 = h1v[(long)s2*64 + lane];
      uint2 r3 = h1v[(long)s3*64 + lane];
      ax += bflo(r0.x)*w0; ay += bfhi(r0.x)*w0; az += bflo(r0.y)*w0; aw += bfhi(r0.y)*w0;
      ax += bflo(r1.x)*w1; ay += bfhi(r1.x)*w1; az += bflo(r1.y)*w1; aw += bfhi(r1.y)*w1;
      ax += bflo(r2.x)*w2; ay += bfhi(r2.x)*w2; az += bflo(r2.y)*w2; aw += bfhi(r2.y)*w2;
      ax += bflo(r3.x)*w3; ay += bfhi(r3.x)*w3; az += bflo(r3.y)*w3; aw += bfhi(r3.y)*w3;
      ssum += w0 + w1 + w2 + w3;
    }
    for (; jj < nj; ++jj){
      int s = __shfl(sE, jj<<2);
      float wj = __shfl(wv, (jj<<2) | head);
      uint2 r = h1v[(long)s*64 + lane];
      ax += bflo(r.x)*wj; ay += bfhi(r.x)*wj; az += bflo(r.y)*wj; aw += bfhi(r.y)*wj;
      ssum += wj;
    }
  }
  float inv = 1.f/(ssum + 1e-16f);
  float4 bb = *(const float4*)&b1[lane*4];
  uint2 o;
  o.x = pack2(ax*inv + bb.x, ay*inv + bb.y);
  o.y = pack2(az*inv + bb.z, aw*inv + bb.w);
  ((uint2*)y1b)[(long)i*64 + lane] = o;
}

// ---------------- BN column stats (bf16 input, C1 channels) ----------------
__global__ __launch_bounds__(256) void k_colstats1(const ushort_t* __restrict__ y, float* __restrict__ st){
  const uint_t* yu = (const uint_t*)y;
  int c2 = threadIdx.x & 127, half = threadIdx.x >> 7;
  long r0 = (long)blockIdx.x * 128;
  float s0=0,q0=0,s1=0,q1=0;
  for (int r = half; r < 128; r += 2){
    long rr = r0 + r;
    if (rr < N_NODES){
      uint_t u = yu[rr*128 + c2];
      float a = bflo(u), b = bfhi(u);
      s0 += a; q0 += a*a; s1 += b; q1 += b*b;
    }
  }
  int c = c2*2;
  atomicAdd(&st[c], s0);      atomicAdd(&st[C1 + c], q0);
  atomicAdd(&st[c+1], s1);    atomicAdd(&st[C1 + c+1], q1);
}

// ---------------- BN column stats (f32 input) ----------------
template<int C, int RPB>
__global__ __launch_bounds__(256) void k_colstats(const float* __restrict__ y, float* __restrict__ st){
  int c = threadIdx.x % C;
  int rl = threadIdx.x / C;
  const int rpb = 256 / C;
  long r0 = (long)blockIdx.x * RPB;
  float s = 0.f, q = 0.f;
  for (int r = rl; r < RPB; r += rpb){
    long rr = r0 + r;
    if (rr < N_NODES){ float v = y[rr*C + c]; s += v; q += v*v; }
  }
  atomicAdd(&st[c], s); atomicAdd(&st[C + c], q);
}

__global__ void k_prep(const float* __restrict__ st, const float* __restrict__ g, const float* __restrict__ be,
                       float* __restrict__ ss, int C){
  int c = blockIdx.x*blockDim.x + threadIdx.x;
  if (c < C){
    float mean = st[c] / (float)N_NODES;
    float var  = st[C + c] / (float)N_NODES - mean*mean;
    float sc = g[c] * rsqrtf(var + BN_EPS);
    ss[c] = sc;
    ss[C + c] = be[c] - mean*sc;
  }
}

// ---------------- K6: h2 = relu(bn(y1)) @ W2 (bf16 out) + fused es2/ed2 ----------------
__global__ __launch_bounds__(256) void k_gemm2(const ushort_t* __restrict__ y1b, const float* __restrict__ W2,
    const float* __restrict__ ss1, const float* __restrict__ a2s, const float* __restrict__ a2d,
    ushort_t* __restrict__ h2b, float* __restrict__ es2, float* __restrict__ ed2){
  __shared__ float As[64][68];
  __shared__ float Bs[64][64];
  __shared__ float as_s[HID], ad_s[HID];
  __shared__ float ss_s[2*C1];
  int t = threadIdx.x;
  if (t < HID){ as_s[t] = a2s[t]; ad_s[t] = a2d[t]; }
  for (int idx = t; idx < 2*C1; idx += 256) ss_s[idx] = ss1[idx];
  int tx = t & 15, ty = t >> 4;
  long i0 = (long)blockIdx.x * 64;
  float acc[4][4] = {};
  __syncthreads();
  for (int kc = 0; kc < C1; kc += 64){
    const uint_t* yu = (const uint_t*)y1b;
    for (int idx = t; idx < 64*32; idx += 256){
      int r = idx >> 5, k2 = idx & 31;
      long gi = i0 + r;
      int k = kc + k2*2;
      float v0 = 0.f, v1 = 0.f;
      if (gi < N_NODES){
        uint_t u = yu[gi*128 + (k >> 1)];
        v0 = fmaxf(bflo(u)*ss_s[k]   + ss_s[C1+k],   0.f);
        v1 = fmaxf(bfhi(u)*ss_s[k+1] + ss_s[C1+k+1], 0.f);
      }
      As[r][k2*2]   = v0;
      As[r][k2*2+1] = v1;
    }
    for (int idx = t; idx < 64*64; idx += 256){
      Bs[idx >> 6][idx & 63] = W2[(kc + (idx >> 6))*HID + (idx & 63)];
    }
    __syncthreads();
    #pragma unroll 8
    for (int kk = 0; kk < 64; ++kk){
      float a0 = As[4*ty+0][kk], a1 = As[4*ty+1][kk], a2 = As[4*ty+2][kk], a3 = As[4*ty+3][kk];
      float4 b = *(float4*)&Bs[kk][4*tx];
      acc[0][0] += a0*b.x; acc[0][1] += a0*b.y; acc[0][2] += a0*b.z; acc[0][3] += a0*b.w;
      acc[1][0] += a1*b.x; acc[1][1] += a1*b.y; acc[1][2] += a1*b.z; acc[1][3] += a1*b.w;
      acc[2][0] += a2*b.x; acc[2][1] += a2*b.y; acc[2][2] += a2*b.z; acc[2][3] += a2*b.w;
      acc[3][0] += a3*b.x; acc[3][1] += a3*b.y; acc[3][2] += a3*b.z; acc[3][3] += a3*b.w;
    }
    __syncthreads();
  }
  #pragma unroll
  for (int rr = 0; rr < 4; ++rr){
    long gi = i0 + 4*ty + rr;
    if (gi < N_NODES){
      uint_t p0 = pack2(acc[rr][0], acc[rr][1]);
      uint_t p1 = pack2(acc[rr][2], acc[rr][3]);
      *(uint2*)&h2b[gi*HID + 4*tx] = make_uint2(p0, p1);
      float ps = acc[rr][0]*as_s[4*tx+0] + acc[rr][1]*as_s[4*tx+1]
               + acc[rr][2]*as_s[4*tx+2] + acc[rr][3]*as_s[4*tx+3];
      float pd = acc[rr][0]*ad_s[4*tx+0] + acc[rr][1]*ad_s[4*tx+1]
               + acc[rr][2]*ad_s[4*tx+2] + acc[rr][3]*ad_s[4*tx+3];
      #pragma unroll
      for (int o = 8; o >= 1; o >>= 1){ ps += __shfl_xor(ps,o); pd += __shfl_xor(pd,o); }
      if (tx == 0){ es2[gi] = ps; ed2[gi] = pd; }
    }
  }
}

// ---------------- K7: layer-2 GAT aggregation (bf16 rows, no max) ----------------
// FIX vs R3: inner loop is now exec-UNIFORM (uniform jj2 step 4; half-waves
// take slots jj2+hh / jj2+2+hh; OOB slots neutralized via w=0 ternary).
// Every __shfl executes with all 64 lanes active.
__global__ __launch_bounds__(256) void k_agg2(const ushort_t* __restrict__ h2b,
    const float* __restrict__ es2, const float* __restrict__ ed2,
    const int* __restrict__ off, const int* __restrict__ csr,
    const float* __restrict__ b2, float* __restrict__ y2){
  int lane = threadIdx.x & 63, wid = threadIdx.x >> 6;
  int i = blockIdx.x*4 + wid;
  if (i >= N_NODES) return;
  int lh = lane & 31, hh = lane >> 5;
  float edv = ed2[i];
  int start = off[i], end = off[i+1];
  const uint_t* h2u = (const uint_t*)h2b;   // row = 32 uints; half-wave per row
  float acc0 = 0.f, acc1 = 0.f, ssum = 0.f;
  {
    float wS = (hh == 0) ? __expf(leaky(es2[i] + edv)) : 0.f;
    uint_t uS = h2u[(long)i*32 + lh];
    acc0 = bflo(uS)*wS; acc1 = bfhi(uS)*wS; ssum = wS;
  }
  for (int j0 = start; j0 < end; j0 += 64){
    int nj = end - j0; if (nj > 64) nj = 64;
    int ce = (lane < nj) ? lane : nj - 1;
    int sE = csr[j0 + ce];
    float wv = (lane < nj) ? __expf(leaky(es2[sE] + edv)) : 0.f;
    for (int jj2 = 0; jj2 < nj; jj2 += 4){   // uniform trip count
      int sl0 = jj2 + hh;                     // <= nj <= 64-1 when used
      int s0 = __shfl(sE, sl0);
      float w0 = __shfl(wv, sl0);
      if (sl0 >= nj) w0 = 0.f;
      uint_t u0 = h2u[(long)s0*32 + lh];
      acc0 += bflo(u0)*w0; acc1 += bfhi(u0)*w0; ssum += w0;
      if (jj2 + 2 < nj){                      // uniform condition
        int sl1 = jj2 + 2 + hh;
        int s1 = __shfl(sE, sl1);
        float w1 = __shfl(wv, sl1);
        if (sl1 >= nj) w1 = 0.f;
        uint_t u1 = h2u[(long)s1*32 + lh];
        acc0 += bflo(u1)*w1; acc1 += bfhi(u1)*w1; ssum += w1;
      }
    }
  }
  acc0 += __shfl_xor(acc0, 32);
  acc1 += __shfl_xor(acc1, 32);
  ssum += __shfl_xor(ssum, 32);
  if (hh == 0){
    float inv = 1.f/(ssum + 1e-16f);
    float2 bb = *(const float2*)&b2[2*lh];
    float2 o;
    o.x = acc0*inv + bb.x;
    o.y = acc1*inv + bb.y;
    ((float2*)y2)[(long)i*32 + lh] = o;
  }
}

// ---------------- final: bn+relu, fused climber MLP, concat, 2-layer MLP ----------------
__global__ __launch_bounds__(256) void k_final(const float* __restrict__ y2,
    const float* __restrict__ ss2, const int* __restrict__ batch,
    const float* __restrict__ cl, const float* __restrict__ Wc, const float* __restrict__ bc,
    const float* __restrict__ Wcl1, const float* __restrict__ bcl1,
    const float* __restrict__ Wcl2, const float* __restrict__ bcl2,
    float* __restrict__ out){
  __shared__ float W1s[2*HID*HID];
  __shared__ float W2s[HID*D_OUT];
  __shared__ float Wcs[D_CL*HID];
  __shared__ float bcs[HID];
  __shared__ float zs[4][2*HID];
  int t = threadIdx.x;
  for (int idx = t; idx < 2*HID*HID; idx += 256) W1s[idx] = Wcl1[idx];
  if (t < HID*D_OUT) W2s[t] = Wcl2[t];
  for (int idx = t; idx < D_CL*HID; idx += 256) Wcs[idx] = Wc[idx];
  if (t < HID) bcs[t] = bc[t];
  __syncthreads();
  int lane = t & 63, wid = t >> 6;
  int i = blockIdx.x*4 + wid;
  if (i >= N_NODES) return;
  float h = y2[(long)i*HID + lane];
  h = fmaxf(h*ss2[lane] + ss2[HID+lane], 0.f);
  int g = batch[i];
  const float* cg = cl + (long)g*D_CL;
  float cvv = bcs[lane];
  #pragma unroll
  for (int k = 0; k < D_CL; ++k) cvv += cg[k]*Wcs[k*HID + lane];
  cvv = fmaxf(cvv, 0.f);
  zs[wid][lane] = h;
  zs[wid][HID+lane] = cvv;
  // intra-wave LDS write->read is in-order; per-wave buffer, no barrier needed
  float acc = bcl1[lane];
  #pragma unroll 8
  for (int k = 0; k < 2*HID; ++k) acc += zs[wid][k]*W1s[k*HID + lane];
  float z2 = fmaxf(acc, 0.f);
  float p0 = z2*W2s[lane*D_OUT+0];
  float p1 = z2*W2s[lane*D_OUT+1];
  float p2 = z2*W2s[lane*D_OUT+2];
  float p3 = z2*W2s[lane*D_OUT+3];
  #pragma unroll
  for (int o = 32; o >= 1; o >>= 1){
    p0 += __shfl_xor(p0,o); p1 += __shfl_xor(p1,o);
    p2 += __shfl_xor(p2,o); p3 += __shfl_xor(p3,o);
  }
  if (lane == 0){
    out[(long)i*D_OUT+0] = p0 + bcl2[0];
    out[(long)i*D_OUT+1] = p1 + bcl2[1];
    out[(long)i*D_OUT+2] = p2 + bcl2[2];
    out[(long)i*D_OUT+3] = p3 + bcl2[3];
  }
}

extern "C" void kernel_launch(void* const* d_in, const int* in_sizes, int n_in,
                              void* d_out, int out_size, void* d_ws, size_t ws_size,
                              hipStream_t stream){
  const float* x    = (const float*)d_in[0];
  const float* cl   = (const float*)d_in[1];
  const int*   ei   = (const int*)d_in[2];
  const int*   batch= (const int*)d_in[3];
  const float* W1   = (const float*)d_in[4];
  const float* a1s  = (const float*)d_in[5];
  const float* a1d  = (const float*)d_in[6];
  const float* b1   = (const float*)d_in[7];
  const float* g1   = (const float*)d_in[8];
  const float* be1  = (const float*)d_in[9];
  const float* W2   = (const float*)d_in[10];
  const float* a2s  = (const float*)d_in[11];
  const float* a2d  = (const float*)d_in[12];
  const float* b2   = (const float*)d_in[13];
  const float* g2   = (const float*)d_in[14];
  const float* be2  = (const float*)d_in[15];
  const float* Wc   = (const float*)d_in[16];
  const float* bc   = (const float*)d_in[17];
  const float* Wcl1 = (const float*)d_in[18];
  const float* bcl1 = (const float*)d_in[19];
  const float* Wcl2 = (const float*)d_in[20];
  const float* bcl2 = (const float*)d_in[21];
  const int* srcE = ei;
  const int* dstE = ei + N_EDGES;
  float* out = (float*)d_out;

  char* w = (char*)d_ws;
  auto take = [&](size_t bytes)->char*{ char* p = w; w += (bytes + 255) & ~(size_t)255; return p; };
  ushort_t* h1b = (ushort_t*)take((size_t)N_NODES*C1*2);   // 25.6 MB, dead after k_agg1
  ushort_t* y1b = (ushort_t*)take((size_t)N_NODES*C1*2);   // 25.6 MB bf16
  float* es1 = (float*)take((size_t)N_NODES*NH*4);
  float* ed1 = (float*)take((size_t)N_NODES*NH*4);
  float* es2 = (float*)take((size_t)N_NODES*4);
  float* ed2 = (float*)take((size_t)N_NODES*4);
  float* st  = (float*)take((2*C1 + 2*HID)*4);   // st1 | st2 contiguous -> one memset
  float* ss1 = (float*)take(2*C1*4);
  float* ss2 = (float*)take(2*HID*4);
  int* cnt  = (int*)take((size_t)CNT_PAD*4);
  int* off  = (int*)take((size_t)(CNT_PAD+16)*4);
  int* csr  = (int*)take((size_t)N_EDGES*4);
  float* st1 = st;
  float* st2 = st + 2*C1;
  // alias into dead h1b region after k_agg1: h2b (6.4 MB) at 0, y2 (12.8 MB) at +8 MB
  ushort_t* h2b = h1b;
  float* y2 = (float*)((char*)h1b + ((size_t)8 << 20));

  hipMemsetAsync(cnt, 0, (size_t)CNT_PAD*4, stream);
  hipMemsetAsync(st, 0, (2*C1 + 2*HID)*4, stream);

  k_node1<<<(N_NODES+15)/16, 256, 0, stream>>>(x, W1, a1s, a1d, h1b, es1, ed1);
  k_hist<<<(N_EDGES+255)/256, 256, 0, stream>>>(dstE, cnt);
  k_scan<<<1, 1024, 0, stream>>>(cnt, off);
  k_scatter<<<(N_EDGES+255)/256, 256, 0, stream>>>(srcE, dstE, off, cnt, csr);

  k_agg1<<<(N_NODES+3)/4, 256, 0, stream>>>(h1b, es1, ed1, off, csr, b1, y1b);
  k_colstats1<<<(N_NODES+127)/128, 256, 0, stream>>>(y1b, st1);
  k_prep<<<1, 256, 0, stream>>>(st1, g1, be1, ss1, C1);
  k_gemm2<<<(N_NODES+63)/64, 256, 0, stream>>>(y1b, W2, ss1, a2s, a2d, h2b, es2, ed2);
  k_agg2<<<(N_NODES+3)/4, 256, 0, stream>>>(h2b, es2, ed2, off, csr, b2, y2);
  k_colstats<HID,128><<<(N_NODES+127)/128, 256, 0, stream>>>(y2, st2);
  k_prep<<<1, 64, 0, stream>>>(st2, g2, be2, ss2, HID);
  k_final<<<(N_NODES+3)/4, 256, 0, stream>>>(y2, ss2, batch, cl, Wc, bc, Wcl1, bcl1, Wcl2, bcl2, out);
}

// Round 7
// 441.475 us; speedup vs baseline: 1.3153x; 1.0753x over previous
//
#include <hip/hip_runtime.h>

#define N_NODES   50000
#define N_EDGES   800000
#define G_GRAPHS  512
#define D_IN      10
#define D_CL      6
#define HID       64
#define NH        4
#define C1        256   // NH*HID
#define D_OUT     4
#define BN_EPS    1e-5f
#define CNT_PAD   53248  // 52*1024, padded count buffer for vectorized scan

typedef unsigned short ushort_t;
typedef unsigned int uint_t;

__device__ __forceinline__ float leaky(float x){ return x > 0.f ? x : 0.2f*x; }
__device__ __forceinline__ ushort_t f2bf(float f){
  unsigned u = __float_as_uint(f);
  return (ushort_t)((u + 0x7fffu + ((u >> 16) & 1u)) >> 16);
}
__device__ __forceinline__ float bflo(uint_t u){ return __uint_as_float(u << 16); }
__device__ __forceinline__ float bfhi(uint_t u){ return __uint_as_float(u & 0xffff0000u); }
__device__ __forceinline__ uint_t pack2(float a, float b){
  return (uint_t)f2bf(a) | ((uint_t)f2bf(b) << 16);
}

// ---------------- K1: h1 = x@W1 (bf16 out), e_src1/e_dst1 per node ----------------
__global__ __launch_bounds__(256) void k_node1(const float* __restrict__ x,
    const float* __restrict__ W1, const float* __restrict__ a1s, const float* __restrict__ a1d,
    ushort_t* __restrict__ h1b, float* __restrict__ es1, float* __restrict__ ed1){
  __shared__ float W1s[D_IN*C1];
  __shared__ float as_s[C1], ad_s[C1];
  int t = threadIdx.x;
  for (int idx = t; idx < D_IN*C1; idx += 256) W1s[idx] = W1[idx];
  as_s[t] = a1s[t]; ad_s[t] = a1d[t];
  __syncthreads();
  int lane = t & 63, wid = t >> 6;
  for (int nn = 0; nn < 16; ++nn){
    int i = blockIdx.x*16 + nn;
    if (i >= N_NODES) return;
    const float* xr = x + (long)i*D_IN;
    float acc = 0.f;
    #pragma unroll
    for (int k = 0; k < D_IN; ++k) acc += xr[k]*W1s[k*C1 + t];
    h1b[(long)i*C1 + t] = f2bf(acc);
    float ps = acc*as_s[t], pd = acc*ad_s[t];
    #pragma unroll
    for (int o = 32; o >= 1; o >>= 1){ ps += __shfl_xor(ps,o); pd += __shfl_xor(pd,o); }
    if (lane == 0){ es1[i*NH + wid] = ps; ed1[i*NH + wid] = pd; }
  }
}

// ---------------- CSR build ----------------
__global__ void k_hist(const int* __restrict__ dst, int* __restrict__ cnt){
  int e = blockIdx.x*blockDim.x + threadIdx.x;
  if (e < N_EDGES) atomicAdd(&cnt[dst[e]], 1);
}

// single-block vectorized scan; also re-zeroes cnt for use as scatter cursor
__global__ __launch_bounds__(1024) void k_scan(int* __restrict__ cnt, int* __restrict__ off){
  __shared__ int sh[1024];
  int t = threadIdx.x;
  int4 v[13];
  const int4* c4 = (const int4*)cnt;
  int base4 = t*13;
  int tsum = 0;
  #pragma unroll
  for (int k = 0; k < 13; ++k){
    v[k] = c4[base4 + k];
    tsum += v[k].x + v[k].y + v[k].z + v[k].w;
  }
  sh[t] = tsum;
  __syncthreads();
  for (int o = 1; o < 1024; o <<= 1){
    int xv = (t >= o) ? sh[t-o] : 0;
    __syncthreads();
    sh[t] += xv;
    __syncthreads();
  }
  int run = sh[t] - tsum;   // exclusive prefix of this thread's chunk
  int4* o4 = (int4*)off;
  int base = t*52;
  #pragma unroll
  for (int k = 0; k < 13; ++k){
    int i = base + k*4;
    int4 w_;
    w_.x = run; run += v[k].x;
    w_.y = run; run += v[k].y;
    w_.z = run; run += v[k].z;
    w_.w = run; run += v[k].w;
    if (i + 3 < N_NODES) o4[base4 + k] = w_;
    else {
      if (i+0 < N_NODES) off[i+0] = w_.x;
      if (i+1 < N_NODES) off[i+1] = w_.y;
      if (i+2 < N_NODES) off[i+2] = w_.z;
      if (i+3 < N_NODES) off[i+3] = w_.w;
    }
  }
  int4 z = make_int4(0,0,0,0);
  int4* cz = (int4*)cnt;
  #pragma unroll
  for (int k = 0; k < 13; ++k) cz[base4 + k] = z;
  if (t == 0) off[N_NODES] = N_EDGES;
}

__global__ void k_scatter(const int* __restrict__ src, const int* __restrict__ dst,
                          const int* __restrict__ off, int* __restrict__ cur, int* __restrict__ csr){
  int e = blockIdx.x*blockDim.x + threadIdx.x;
  if (e < N_EDGES){
    int d = dst[e];
    int r = atomicAdd(&cur[d], 1);
    csr[off[d] + r] = src[e];
  }
}

// ---------------- K3: layer-1 GAT aggregation, wave per dst ----------------
// No max-subtraction (logits bounded; softmax shift-invariant).
// Weight phase: lane e*4+h computes w(edge e, head h) for a 16-edge chunk;
// accumulate phase pulls weights via shuffle. ALL loops are wave-uniform.
// 8-deep gather unroll (8 row-loads in flight).
__global__ __launch_bounds__(256) void k_agg1(const ushort_t* __restrict__ h1b,
    const float* __restrict__ es1, const float* __restrict__ ed1,
    const int* __restrict__ off, const int* __restrict__ csr,
    const float* __restrict__ b1, ushort_t* __restrict__ y1b){
  int lane = threadIdx.x & 63, wid = threadIdx.x >> 6;
  int i = blockIdx.x*4 + wid;
  if (i >= N_NODES) return;
  int head = lane >> 4;           // my output head (channels 4*lane..4*lane+3)
  int h    = lane & 3;            // weight-phase head
  int e    = lane >> 2;           // weight-phase edge slot (0..15)
  float4 edv4 = *(const float4*)&ed1[i*NH];
  float4 esv4 = *(const float4*)&es1[i*NH];
  float edh   = (head==0)?edv4.x:(head==1)?edv4.y:(head==2)?edv4.z:edv4.w;
  float esS   = (head==0)?esv4.x:(head==1)?esv4.y:(head==2)?esv4.z:esv4.w;
  float edw   = (h==0)?edv4.x:(h==1)?edv4.y:(h==2)?edv4.z:edv4.w;
  int start = off[i], end = off[i+1];
  const uint2* h1v = (const uint2*)h1b;
  // self loop
  float wS = __expf(leaky(esS + edh));
  float ssum = wS;
  uint2 hv = h1v[(long)i*64 + lane];
  float ax = bflo(hv.x)*wS, ay = bfhi(hv.x)*wS, az = bflo(hv.y)*wS, aw = bfhi(hv.y)*wS;
  for (int j0 = start; j0 < end; j0 += 16){
    int nj = end - j0; if (nj > 16) nj = 16;
    int ce = (e < nj) ? e : nj - 1;
    int sE = csr[j0 + ce];
    float wv = (e < nj) ? __expf(leaky(es1[sE*NH + h] + edw)) : 0.f;
    int jj = 0;
    for (; jj + 7 < nj; jj += 8){
      int s0 = __shfl(sE, (jj+0)<<2);
      int s1 = __shfl(sE, (jj+1)<<2);
      int s2 = __shfl(sE, (jj+2)<<2);
      int s3 = __shfl(sE, (jj+3)<<2);
      int s4 = __shfl(sE, (jj+4)<<2);
      int s5 = __shfl(sE, (jj+5)<<2);
      int s6 = __shfl(sE, (jj+6)<<2);
      int s7 = __shfl(sE, (jj+7)<<2);
      uint2 r0 = h1v[(long)s0*64 + lane];
      uint2 r1 = h1v[(long)s1*64 + lane];
      uint2 r2 = h1v[(long)s2*64 + lane];
      uint2 r3 = h1v[(long)s3*64 + lane];
      uint2 r4 = h1v[(long)s4*64 + lane];
      uint2 r5 = h1v[(long)s5*64 + lane];
      uint2 r6 = h1v[(long)s6*64 + lane];
      uint2 r7 = h1v[(long)s7*64 + lane];
      float w0 = __shfl(wv, ((jj+0)<<2) | head);
      float w1 = __shfl(wv, ((jj+1)<<2) | head);
      float w2 = __shfl(wv, ((jj+2)<<2) | head);
      float w3 = __shfl(wv, ((jj+3)<<2) | head);
      float w4 = __shfl(wv, ((jj+4)<<2) | head);
      float w5 = __shfl(wv, ((jj+5)<<2) | head);
      float w6 = __shfl(wv, ((jj+6)<<2) | head);
      float w7 = __shfl(wv, ((jj+7)<<2) | head);
      ax += bflo(r0.x)*w0; ay += bfhi(r0.x)*w0; az += bflo(r0.y)*w0; aw += bfhi(r0.y)*w0;
      ax += bflo(r1.x)*w1; ay += bfhi(r1.x)*w1; az += bflo(r1.y)*w1; aw += bfhi(r1.y)*w1;
      ax += bflo(r2.x)*w2; ay += bfhi(r2.x)*w2; az += bflo(r2.y)*w2; aw += bfhi(r2.y)*w2;
      ax += bflo(r3.x)*w3; ay += bfhi(r3.x)*w3; az += bflo(r3.y)*w3; aw += bfhi(r3.y)*w3;
      ax += bflo(r4.x)*w4; ay += bfhi(r4.x)*w4; az += bflo(r4.y)*w4; aw += bfhi(r4.y)*w4;
      ax += bflo(r5.x)*w5; ay += bfhi(r5.x)*w5; az += bflo(r5.y)*w5; aw += bfhi(r5.y)*w5;
      ax += bflo(r6.x)*w6; ay += bfhi(r6.x)*w6; az += bflo(r6.y)*w6; aw += bfhi(r6.y)*w6;
      ax += bflo(r7.x)*w7; ay += bfhi(r7.x)*w7; az += bflo(r7.y)*w7; aw += bfhi(r7.y)*w7;
      ssum += w0 + w1 + w2 + w3 + w4 + w5 + w6 + w7;
    }
    for (; jj + 3 < nj; jj += 4){
      int s0 = __shfl(sE, (jj+0)<<2);
      int s1 = __shfl(sE, (jj+1)<<2);
      int s2 = __shfl(sE, (jj+2)<<2);
      int s3 = __shfl(sE, (jj+3)<<2);
      float w0 = __shfl(wv, ((jj+0)<<2) | head);
      float w1 = __shfl(wv, ((jj+1)<<2) | head);
      float w2 = __shfl(wv, ((jj+2)<<2) | head);
      float w3 = __shfl(wv, ((jj+3)<<2) | head);
      uint2 r0 = h1v[(long)s0*64 + lane];
      uint2 r1 = h1v[(long)s1*64 + lane];
      uint2 r2 = h1v[(long)s2*64 + lane];
      uint2 r3 = h1v[(long)s3*64 + lane];
      ax += bflo(r0.x)*w0; ay += bfhi(r0.x)*w0; az += bflo(r0.y)*w0; aw += bfhi(r0.y)*w0;
      ax += bflo(r1.x)*w1; ay += bfhi(r1.x)*w1; az += bflo(r1.y)*w1; aw += bfhi(r1.y)*w1;
      ax += bflo(r2.x)*w2; ay += bfhi(r2.x)*w2; az += bflo(r2.y)*w2; aw += bfhi(r2.y)*w2;
      ax += bflo(r3.x)*w3; ay += bfhi(r3.x)*w3; az += bflo(r3.y)*w3; aw += bfhi(r3.y)*w3;
      ssum += w0 + w1 + w2 + w3;
    }
    for (; jj < nj; ++jj){
      int s = __shfl(sE, jj<<2);
      float wj = __shfl(wv, (jj<<2) | head);
      uint2 r = h1v[(long)s*64 + lane];
      ax += bflo(r.x)*wj; ay += bfhi(r.x)*wj; az += bflo(r.y)*wj; aw += bfhi(r.y)*wj;
      ssum += wj;
    }
  }
  float inv = 1.f/(ssum + 1e-16f);
  float4 bb = *(const float4*)&b1[lane*4];
  uint2 o;
  o.x = pack2(ax*inv + bb.x, ay*inv + bb.y);
  o.y = pack2(az*inv + bb.z, aw*inv + bb.w);
  ((uint2*)y1b)[(long)i*64 + lane] = o;
}

// ---------------- BN column stats (bf16 input, C1 channels) ----------------
__global__ __launch_bounds__(256) void k_colstats1(const ushort_t* __restrict__ y, float* __restrict__ st){
  const uint_t* yu = (const uint_t*)y;
  int c2 = threadIdx.x & 127, half = threadIdx.x >> 7;
  long r0 = (long)blockIdx.x * 128;
  float s0=0,q0=0,s1=0,q1=0;
  for (int r = half; r < 128; r += 2){
    long rr = r0 + r;
    if (rr < N_NODES){
      uint_t u = yu[rr*128 + c2];
      float a = bflo(u), b = bfhi(u);
      s0 += a; q0 += a*a; s1 += b; q1 += b*b;
    }
  }
  int c = c2*2;
  atomicAdd(&st[c], s0);      atomicAdd(&st[C1 + c], q0);
  atomicAdd(&st[c+1], s1);    atomicAdd(&st[C1 + c+1], q1);
}

// ---------------- BN column stats (f32 input) ----------------
template<int C, int RPB>
__global__ __launch_bounds__(256) void k_colstats(const float* __restrict__ y, float* __restrict__ st){
  int c = threadIdx.x % C;
  int rl = threadIdx.x / C;
  const int rpb = 256 / C;
  long r0 = (long)blockIdx.x * RPB;
  float s = 0.f, q = 0.f;
  for (int r = rl; r < RPB; r += rpb){
    long rr = r0 + r;
    if (rr < N_NODES){ float v = y[rr*C + c]; s += v; q += v*v; }
  }
  atomicAdd(&st[c], s); atomicAdd(&st[C + c], q);
}

__global__ void k_prep(const float* __restrict__ st, const float* __restrict__ g, const float* __restrict__ be,
                       float* __restrict__ ss, int C){
  int c = blockIdx.x*blockDim.x + threadIdx.x;
  if (c < C){
    float mean = st[c] / (float)N_NODES;
    float var  = st[C + c] / (float)N_NODES - mean*mean;
    float sc = g[c] * rsqrtf(var + BN_EPS);
    ss[c] = sc;
    ss[C + c] = be[c] - mean*sc;
  }
}

// ---------------- K6: h2 = relu(bn(y1)) @ W2 (bf16 out) + fused es2/ed2 ----------------
__global__ __launch_bounds__(256) void k_gemm2(const ushort_t* __restrict__ y1b, const float* __restrict__ W2,
    const float* __restrict__ ss1, const float* __restrict__ a2s, const float* __restrict__ a2d,
    ushort_t* __restrict__ h2b, float* __restrict__ es2, float* __restrict__ ed2){
  __shared__ float As[64][68];
  __shared__ float Bs[64][64];
  __shared__ float as_s[HID], ad_s[HID];
  __shared__ float ss_s[2*C1];
  int t = threadIdx.x;
  if (t < HID){ as_s[t] = a2s[t]; ad_s[t] = a2d[t]; }
  for (int idx = t; idx < 2*C1; idx += 256) ss_s[idx] = ss1[idx];
  int tx = t & 15, ty = t >> 4;
  long i0 = (long)blockIdx.x * 64;
  float acc[4][4] = {};
  __syncthreads();
  for (int kc = 0; kc < C1; kc += 64){
    const uint_t* yu = (const uint_t*)y1b;
    for (int idx = t; idx < 64*32; idx += 256){
      int r = idx >> 5, k2 = idx & 31;
      long gi = i0 + r;
      int k = kc + k2*2;
      float v0 = 0.f, v1 = 0.f;
      if (gi < N_NODES){
        uint_t u = yu[gi*128 + (k >> 1)];
        v0 = fmaxf(bflo(u)*ss_s[k]   + ss_s[C1+k],   0.f);
        v1 = fmaxf(bfhi(u)*ss_s[k+1] + ss_s[C1+k+1], 0.f);
      }
      As[r][k2*2]   = v0;
      As[r][k2*2+1] = v1;
    }
    for (int idx = t; idx < 64*64; idx += 256){
      Bs[idx >> 6][idx & 63] = W2[(kc + (idx >> 6))*HID + (idx & 63)];
    }
    __syncthreads();
    #pragma unroll 8
    for (int kk = 0; kk < 64; ++kk){
      float a0 = As[4*ty+0][kk], a1 = As[4*ty+1][kk], a2 = As[4*ty+2][kk], a3 = As[4*ty+3][kk];
      float4 b = *(float4*)&Bs[kk][4*tx];
      acc[0][0] += a0*b.x; acc[0][1] += a0*b.y; acc[0][2] += a0*b.z; acc[0][3] += a0*b.w;
      acc[1][0] += a1*b.x; acc[1][1] += a1*b.y; acc[1][2] += a1*b.z; acc[1][3] += a1*b.w;
      acc[2][0] += a2*b.x; acc[2][1] += a2*b.y; acc[2][2] += a2*b.z; acc[2][3] += a2*b.w;
      acc[3][0] += a3*b.x; acc[3][1] += a3*b.y; acc[3][2] += a3*b.z; acc[3][3] += a3*b.w;
    }
    __syncthreads();
  }
  #pragma unroll
  for (int rr = 0; rr < 4; ++rr){
    long gi = i0 + 4*ty + rr;
    if (gi < N_NODES){
      uint_t p0 = pack2(acc[rr][0], acc[rr][1]);
      uint_t p1 = pack2(acc[rr][2], acc[rr][3]);
      *(uint2*)&h2b[gi*HID + 4*tx] = make_uint2(p0, p1);
      float ps = acc[rr][0]*as_s[4*tx+0] + acc[rr][1]*as_s[4*tx+1]
               + acc[rr][2]*as_s[4*tx+2] + acc[rr][3]*as_s[4*tx+3];
      float pd = acc[rr][0]*ad_s[4*tx+0] + acc[rr][1]*ad_s[4*tx+1]
               + acc[rr][2]*ad_s[4*tx+2] + acc[rr][3]*ad_s[4*tx+3];
      #pragma unroll
      for (int o = 8; o >= 1; o >>= 1){ ps += __shfl_xor(ps,o); pd += __shfl_xor(pd,o); }
      if (tx == 0){ es2[gi] = ps; ed2[gi] = pd; }
    }
  }
}

// ---------------- K7: layer-2 GAT aggregation (bf16 rows, no max) ----------------
// Exec-uniform inner loop; every __shfl executes with all 64 lanes active.
__global__ __launch_bounds__(256) void k_agg2(const ushort_t* __restrict__ h2b,
    const float* __restrict__ es2, const float* __restrict__ ed2,
    const int* __restrict__ off, const int* __restrict__ csr,
    const float* __restrict__ b2, float* __restrict__ y2){
  int lane = threadIdx.x & 63, wid = threadIdx.x >> 6;
  int i = blockIdx.x*4 + wid;
  if (i >= N_NODES) return;
  int lh = lane & 31, hh = lane >> 5;
  float edv = ed2[i];
  int start = off[i], end = off[i+1];
  const uint_t* h2u = (const uint_t*)h2b;   // row = 32 uints; half-wave per row
  float acc0 = 0.f, acc1 = 0.f, ssum = 0.f;
  {
    float wS = (hh == 0) ? __expf(leaky(es2[i] + edv)) : 0.f;
    uint_t uS = h2u[(long)i*32 + lh];
    acc0 = bflo(uS)*wS; acc1 = bfhi(uS)*wS; ssum = wS;
  }
  for (int j0 = start; j0 < end; j0 += 64){
    int nj = end - j0; if (nj > 64) nj = 64;
    int ce = (lane < nj) ? lane : nj - 1;
    int sE = csr[j0 + ce];
    float wv = (lane < nj) ? __expf(leaky(es2[sE] + edv)) : 0.f;
    for (int jj2 = 0; jj2 < nj; jj2 += 4){   // uniform trip count
      int sl0 = jj2 + hh;
      int s0 = __shfl(sE, sl0);
      float w0 = __shfl(wv, sl0);
      if (sl0 >= nj) w0 = 0.f;
      uint_t u0 = h2u[(long)s0*32 + lh];
      acc0 += bflo(u0)*w0; acc1 += bfhi(u0)*w0; ssum += w0;
      if (jj2 + 2 < nj){                      // uniform condition
        int sl1 = jj2 + 2 + hh;
        int s1 = __shfl(sE, sl1);
        float w1 = __shfl(wv, sl1);
        if (sl1 >= nj) w1 = 0.f;
        uint_t u1 = h2u[(long)s1*32 + lh];
        acc0 += bflo(u1)*w1; acc1 += bfhi(u1)*w1; ssum += w1;
      }
    }
  }
  acc0 += __shfl_xor(acc0, 32);
  acc1 += __shfl_xor(acc1, 32);
  ssum += __shfl_xor(ssum, 32);
  if (hh == 0){
    float inv = 1.f/(ssum + 1e-16f);
    float2 bb = *(const float2*)&b2[2*lh];
    float2 o;
    o.x = acc0*inv + bb.x;
    o.y = acc1*inv + bb.y;
    ((float2*)y2)[(long)i*32 + lh] = o;
  }
}

// ---------------- climber MLP: cv[g] = relu(climber@Wc + bc) ----------------
__global__ void k_climber(const float* __restrict__ cl, const float* __restrict__ Wc,
                          const float* __restrict__ bc, float* __restrict__ cv){
  int idx = blockIdx.x*blockDim.x + threadIdx.x;
  if (idx < G_GRAPHS*HID){
    int g = idx >> 6, j = idx & 63;
    float a = bc[j];
    #pragma unroll
    for (int k = 0; k < D_CL; ++k) a += cl[g*D_CL + k]*Wc[k*HID + j];
    cv[idx] = fmaxf(a, 0.f);
  }
}

// ---------------- final: tiled GEMM. 64 rows/block.
// As[64][132] = [bn_relu(y2) | cv[batch]], Bs[128][64] = Wcl1.
// acc = As@Bs (+bcl1, relu); out = acc@Wcl2 via register partials + 16-lane reduce.
__global__ __launch_bounds__(256) void k_final(const float* __restrict__ y2,
    const float* __restrict__ ss2, const int* __restrict__ batch, const float* __restrict__ cv,
    const float* __restrict__ Wcl1, const float* __restrict__ bcl1,
    const float* __restrict__ Wcl2, const float* __restrict__ bcl2,
    float* __restrict__ out){
  __shared__ float As[64][132];
  __shared__ float Bs[128][64];
  __shared__ float ss2s[2*HID];
  __shared__ float b1s[HID];
  __shared__ float W2s[HID*D_OUT];
  int t = threadIdx.x;
  long i0 = (long)blockIdx.x * 64;
  if (t < 2*HID) ss2s[t] = ss2[t];
  if (t >= 128 && t < 192) b1s[t-128] = bcl1[t-128];
  W2s[t] = Wcl2[t];
  __syncthreads();   // FIX: ss2s is consumed by the As staging below (all waves)
  // stage As left half: bn_relu(y2), float2 (64 rows x 32 float2)
  const float2* y2v = (const float2*)y2;
  #pragma unroll
  for (int ii = 0; ii < 8; ++ii){
    int idx = t + 256*ii;
    int r = idx >> 5, k2 = idx & 31;
    long gi = i0 + r;
    float2 v = make_float2(0.f, 0.f);
    if (gi < N_NODES) v = y2v[gi*32 + k2];
    int k = k2*2;
    As[r][k]   = fmaxf(v.x*ss2s[k]   + ss2s[HID+k],   0.f);
    As[r][k+1] = fmaxf(v.y*ss2s[k+1] + ss2s[HID+k+1], 0.f);
  }
  // stage As right half: cv[batch[gi]], float2
  const float2* cvv = (const float2*)cv;
  #pragma unroll
  for (int ii = 0; ii < 8; ++ii){
    int idx = t + 256*ii;
    int r = idx >> 5, k2 = idx & 31;
    long gi = i0 + r;
    float2 v = make_float2(0.f, 0.f);
    if (gi < N_NODES){ int g = batch[gi]; v = cvv[g*32 + k2]; }
    As[r][HID + k2*2]   = v.x;
    As[r][HID + k2*2+1] = v.y;
  }
  // stage Bs = Wcl1 [128][64], float4
  #pragma unroll
  for (int ii = 0; ii < 8; ++ii){
    int idx = t + 256*ii;
    int kk = idx >> 4, c4 = idx & 15;
    *(float4*)&Bs[kk][c4*4] = *(const float4*)&Wcl1[kk*64 + c4*4];
  }
  __syncthreads();
  int tx = t & 15, ty = t >> 4;
  float acc[4][4] = {};
  #pragma unroll 4
  for (int kk = 0; kk < 2*HID; kk += 4){
    float4 a0 = *(float4*)&As[4*ty+0][kk];
    float4 a1 = *(float4*)&As[4*ty+1][kk];
    float4 a2 = *(float4*)&As[4*ty+2][kk];
    float4 a3 = *(float4*)&As[4*ty+3][kk];
    float4 b0 = *(float4*)&Bs[kk+0][4*tx];
    float4 b1 = *(float4*)&Bs[kk+1][4*tx];
    float4 b2 = *(float4*)&Bs[kk+2][4*tx];
    float4 b3 = *(float4*)&Bs[kk+3][4*tx];
    acc[0][0] += a0.x*b0.x + a0.y*b1.x + a0.z*b2.x + a0.w*b3.x;
    acc[0][1] += a0.x*b0.y + a0.y*b1.y + a0.z*b2.y + a0.w*b3.y;
    acc[0][2] += a0.x*b0.z + a0.y*b1.z + a0.z*b2.z + a0.w*b3.z;
    acc[0][3] += a0.x*b0.w + a0.y*b1.w + a0.z*b2.w + a0.w*b3.w;
    acc[1][0] += a1.x*b0.x + a1.y*b1.x + a1.z*b2.x + a1.w*b3.x;
    acc[1][1] += a1.x*b0.y + a1.y*b1.y + a1.z*b2.y + a1.w*b3.y;
    acc[1][2] += a1.x*b0.z + a1.y*b1.z + a1.z*b2.z + a1.w*b3.z;
    acc[1][3] += a1.x*b0.w + a1.y*b1.w + a1.z*b2.w + a1.w*b3.w;
    acc[2][0] += a2.x*b0.x + a2.y*b1.x + a2.z*b2.x + a2.w*b3.x;
    acc[2][1] += a2.x*b0.y + a2.y*b1.y + a2.z*b2.y + a2.w*b3.y;
    acc[2][2] += a2.x*b0.z + a2.y*b1.z + a2.z*b2.z + a2.w*b3.z;
    acc[2][3] += a2.x*b0.w + a2.y*b1.w + a2.z*b2.w + a2.w*b3.w;
    acc[3][0] += a3.x*b0.x + a3.y*b1.x + a3.z*b2.x + a3.w*b3.x;
    acc[3][1] += a3.x*b0.y + a3.y*b1.y + a3.z*b2.y + a3.w*b3.y;
    acc[3][2] += a3.x*b0.z + a3.y*b1.z + a3.z*b2.z + a3.w*b3.z;
    acc[3][3] += a3.x*b0.w + a3.y*b1.w + a3.z*b2.w + a3.w*b3.w;
  }
  // bias + relu, then xWcl2 partials and 16-lane reduce
  float p[4][4];
  #pragma unroll
  for (int r = 0; r < 4; ++r){
    #pragma unroll
    for (int c = 0; c < 4; ++c)
      acc[r][c] = fmaxf(acc[r][c] + b1s[4*tx+c], 0.f);
    #pragma unroll
    for (int oc = 0; oc < 4; ++oc){
      p[r][oc] = acc[r][0]*W2s[(4*tx+0)*4+oc] + acc[r][1]*W2s[(4*tx+1)*4+oc]
               + acc[r][2]*W2s[(4*tx+2)*4+oc] + acc[r][3]*W2s[(4*tx+3)*4+oc];
    }
  }
  #pragma unroll
  for (int o = 8; o >= 1; o >>= 1){
    #pragma unroll
    for (int r = 0; r < 4; ++r){
      p[r][0] += __shfl_xor(p[r][0], o);
      p[r][1] += __shfl_xor(p[r][1], o);
      p[r][2] += __shfl_xor(p[r][2], o);
      p[r][3] += __shfl_xor(p[r][3], o);
    }
  }
  if (tx == 0){
    float4 bb = *(const float4*)bcl2;
    #pragma unroll
    for (int r = 0; r < 4; ++r){
      long gi = i0 + 4*ty + r;
      if (gi < N_NODES){
        float4 o;
        o.x = p[r][0] + bb.x; o.y = p[r][1] + bb.y;
        o.z = p[r][2] + bb.z; o.w = p[r][3] + bb.w;
        *(float4*)&out[gi*4] = o;
      }
    }
  }
}

extern "C" void kernel_launch(void* const* d_in, const int* in_sizes, int n_in,
                              void* d_out, int out_size, void* d_ws, size_t ws_size,
                              hipStream_t stream){
  const float* x    = (const float*)d_in[0];
  const float* cl   = (const float*)d_in[1];
  const int*   ei   = (const int*)d_in[2];
  const int*   batch= (const int*)d_in[3];
  const float* W1   = (const float*)d_in[4];
  const float* a1s  = (const float*)d_in[5];
  const float* a1d  = (const float*)d_in[6];
  const float* b1   = (const float*)d_in[7];
  const float* g1   = (const float*)d_in[8];
  const float* be1  = (const float*)d_in[9];
  const float* W2   = (const float*)d_in[10];
  const float* a2s  = (const float*)d_in[11];
  const float* a2d  = (const float*)d_in[12];
  const float* b2   = (const float*)d_in[13];
  const float* g2   = (const float*)d_in[14];
  const float* be2  = (const float*)d_in[15];
  const float* Wc   = (const float*)d_in[16];
  const float* bc   = (const float*)d_in[17];
  const float* Wcl1 = (const float*)d_in[18];
  const float* bcl1 = (const float*)d_in[19];
  const float* Wcl2 = (const float*)d_in[20];
  const float* bcl2 = (const float*)d_in[21];
  const int* srcE = ei;
  const int* dstE = ei + N_EDGES;
  float* out = (float*)d_out;

  char* w = (char*)d_ws;
  auto take = [&](size_t bytes)->char*{ char* p = w; w += (bytes + 255) & ~(size_t)255; return p; };
  ushort_t* h1b = (ushort_t*)take((size_t)N_NODES*C1*2);   // 25.6 MB, dead after k_agg1
  ushort_t* y1b = (ushort_t*)take((size_t)N_NODES*C1*2);   // 25.6 MB bf16
  float* es1 = (float*)take((size_t)N_NODES*NH*4);
  float* ed1 = (float*)take((size_t)N_NODES*NH*4);
  float* es2 = (float*)take((size_t)N_NODES*4);
  float* ed2 = (float*)take((size_t)N_NODES*4);
  float* cv  = (float*)take((size_t)G_GRAPHS*HID*4);
  float* st  = (float*)take((2*C1 + 2*HID)*4);   // st1 | st2 contiguous -> one memset
  float* ss1 = (float*)take(2*C1*4);
  float* ss2 = (float*)take(2*HID*4);
  int* cnt  = (int*)take((size_t)CNT_PAD*4);
  int* off  = (int*)take((size_t)(CNT_PAD+16)*4);
  int* csr  = (int*)take((size_t)N_EDGES*4);
  float* st1 = st;
  float* st2 = st + 2*C1;
  // alias into dead h1b region after k_agg1: h2b (6.4 MB) at 0, y2 (12.8 MB) at +8 MB
  ushort_t* h2b = h1b;
  float* y2 = (float*)((char*)h1b + ((size_t)8 << 20));

  hipMemsetAsync(cnt, 0, (size_t)CNT_PAD*4, stream);
  hipMemsetAsync(st, 0, (2*C1 + 2*HID)*4, stream);

  k_node1<<<(N_NODES+15)/16, 256, 0, stream>>>(x, W1, a1s, a1d, h1b, es1, ed1);
  k_hist<<<(N_EDGES+255)/256, 256, 0, stream>>>(dstE, cnt);
  k_scan<<<1, 1024, 0, stream>>>(cnt, off);
  k_scatter<<<(N_EDGES+255)/256, 256, 0, stream>>>(srcE, dstE, off, cnt, csr);

  k_agg1<<<(N_NODES+3)/4, 256, 0, stream>>>(h1b, es1, ed1, off, csr, b1, y1b);
  k_colstats1<<<(N_NODES+127)/128, 256, 0, stream>>>(y1b, st1);
  k_prep<<<1, 256, 0, stream>>>(st1, g1, be1, ss1, C1);
  k_gemm2<<<(N_NODES+63)/64, 256, 0, stream>>>(y1b, W2, ss1, a2s, a2d, h2b, es2, ed2);
  k_agg2<<<(N_NODES+3)/4, 256, 0, stream>>>(h2b, es2, ed2, off, csr, b2, y2);
  k_colstats<HID,128><<<(N_NODES+127)/128, 256, 0, stream>>>(y2, st2);
  k_prep<<<1, 64, 0, stream>>>(st2, g2, be2, ss2, HID);
  k_climber<<<(G_GRAPHS*HID+255)/256, 256, 0, stream>>>(cl, Wc, bc, cv);
  k_final<<<(N_NODES+63)/64, 256, 0, stream>>>(y2, ss2, batch, cv, Wcl1, bcl1, Wcl2, bcl2, out);
}

// Round 8
// 433.483 us; speedup vs baseline: 1.3396x; 1.0184x over previous
//
#include <hip/hip_runtime.h>

#define N_NODES   50000
#define N_EDGES   800000
#define G_GRAPHS  512
#define D_IN      10
#define D_CL      6
#define HID       64
#define NH        4
#define C1        256   // NH*HID
#define D_OUT     4
#define BN_EPS    1e-5f
#define CNT_PAD   53248  // 52*1024, padded count buffer for vectorized scan

typedef unsigned short ushort_t;
typedef unsigned int uint_t;

__device__ __forceinline__ float leaky(float x){ return x > 0.f ? x : 0.2f*x; }
__device__ __forceinline__ ushort_t f2bf(float f){
  unsigned u = __float_as_uint(f);
  return (ushort_t)((u + 0x7fffu + ((u >> 16) & 1u)) >> 16);
}
__device__ __forceinline__ float bflo(uint_t u){ return __uint_as_float(u << 16); }
__device__ __forceinline__ float bfhi(uint_t u){ return __uint_as_float(u & 0xffff0000u); }
__device__ __forceinline__ uint_t pack2(float a, float b){
  return (uint_t)f2bf(a) | ((uint_t)f2bf(b) << 16);
}

// ---------------- K1: h1 = x@W1 (bf16 out), e_src1/e_dst1 per node ----------------
__global__ __launch_bounds__(256) void k_node1(const float* __restrict__ x,
    const float* __restrict__ W1, const float* __restrict__ a1s, const float* __restrict__ a1d,
    ushort_t* __restrict__ h1b, float* __restrict__ es1, float* __restrict__ ed1){
  __shared__ float W1s[D_IN*C1];
  __shared__ float as_s[C1], ad_s[C1];
  int t = threadIdx.x;
  for (int idx = t; idx < D_IN*C1; idx += 256) W1s[idx] = W1[idx];
  as_s[t] = a1s[t]; ad_s[t] = a1d[t];
  __syncthreads();
  int lane = t & 63, wid = t >> 6;
  for (int nn = 0; nn < 16; ++nn){
    int i = blockIdx.x*16 + nn;
    if (i >= N_NODES) return;
    const float* xr = x + (long)i*D_IN;
    float acc = 0.f;
    #pragma unroll
    for (int k = 0; k < D_IN; ++k) acc += xr[k]*W1s[k*C1 + t];
    h1b[(long)i*C1 + t] = f2bf(acc);
    float ps = acc*as_s[t], pd = acc*ad_s[t];
    #pragma unroll
    for (int o = 32; o >= 1; o >>= 1){ ps += __shfl_xor(ps,o); pd += __shfl_xor(pd,o); }
    if (lane == 0){ es1[i*NH + wid] = ps; ed1[i*NH + wid] = pd; }
  }
}

// ---------------- CSR build ----------------
__global__ void k_hist(const int* __restrict__ dst, int* __restrict__ cnt){
  int e = blockIdx.x*blockDim.x + threadIdx.x;
  if (e < N_EDGES) atomicAdd(&cnt[dst[e]], 1);
}

// single-block vectorized scan; also re-zeroes cnt for use as scatter cursor
__global__ __launch_bounds__(1024) void k_scan(int* __restrict__ cnt, int* __restrict__ off){
  __shared__ int sh[1024];
  int t = threadIdx.x;
  int4 v[13];
  const int4* c4 = (const int4*)cnt;
  int base4 = t*13;
  int tsum = 0;
  #pragma unroll
  for (int k = 0; k < 13; ++k){
    v[k] = c4[base4 + k];
    tsum += v[k].x + v[k].y + v[k].z + v[k].w;
  }
  sh[t] = tsum;
  __syncthreads();
  for (int o = 1; o < 1024; o <<= 1){
    int xv = (t >= o) ? sh[t-o] : 0;
    __syncthreads();
    sh[t] += xv;
    __syncthreads();
  }
  int run = sh[t] - tsum;   // exclusive prefix of this thread's chunk
  int4* o4 = (int4*)off;
  int base = t*52;
  #pragma unroll
  for (int k = 0; k < 13; ++k){
    int i = base + k*4;
    int4 w_;
    w_.x = run; run += v[k].x;
    w_.y = run; run += v[k].y;
    w_.z = run; run += v[k].z;
    w_.w = run; run += v[k].w;
    if (i + 3 < N_NODES) o4[base4 + k] = w_;
    else {
      if (i+0 < N_NODES) off[i+0] = w_.x;
      if (i+1 < N_NODES) off[i+1] = w_.y;
      if (i+2 < N_NODES) off[i+2] = w_.z;
      if (i+3 < N_NODES) off[i+3] = w_.w;
    }
  }
  int4 z = make_int4(0,0,0,0);
  int4* cz = (int4*)cnt;
  #pragma unroll
  for (int k = 0; k < 13; ++k) cz[base4 + k] = z;
  if (t == 0) off[N_NODES] = N_EDGES;
}

__global__ void k_scatter(const int* __restrict__ src, const int* __restrict__ dst,
                          const int* __restrict__ off, int* __restrict__ cur, int* __restrict__ csr){
  int e = blockIdx.x*blockDim.x + threadIdx.x;
  if (e < N_EDGES){
    int d = dst[e];
    int r = atomicAdd(&cur[d], 1);
    csr[off[d] + r] = src[e];
  }
}

// ---------------- K3: layer-1 GAT aggregation, wave per dst ----------------
// 32-lane x uint4 accumulate: lanes lh=0..31 each hold 8 channels (uint4 = 8 bf16),
// halves hf=0/1 process edges (jj+2k+hf). Full 8-edge blocks are mask-free;
// exec-uniform step-2 tail with clamped shfl sources. Weight phase unchanged:
// lane e*4+h computes w(edge e, head h) for a 16-edge chunk.
__global__ __launch_bounds__(256) void k_agg1(const ushort_t* __restrict__ h1b,
    const float* __restrict__ es1, const float* __restrict__ ed1,
    const int* __restrict__ off, const int* __restrict__ csr,
    const float* __restrict__ b1, ushort_t* __restrict__ y1b){
  int lane = threadIdx.x & 63, wid = threadIdx.x >> 6;
  int i = blockIdx.x*4 + wid;
  if (i >= N_NODES) return;
  int lh = lane & 31, hf = lane >> 5;
  int headO = lh >> 3;            // output head (my channels 8*lh..8*lh+7)
  int h    = lane & 3;            // weight-phase head
  int e    = lane >> 2;           // weight-phase edge slot (0..15)
  float4 edv4 = *(const float4*)&ed1[i*NH];
  float4 esv4 = *(const float4*)&es1[i*NH];
  float edh = (headO==0)?edv4.x:(headO==1)?edv4.y:(headO==2)?edv4.z:edv4.w;
  float esS = (headO==0)?esv4.x:(headO==1)?esv4.y:(headO==2)?esv4.z:esv4.w;
  float edw = (h==0)?edv4.x:(h==1)?edv4.y:(h==2)?edv4.z:edv4.w;
  int start = off[i], end = off[i+1];
  const uint4* h1v4 = (const uint4*)h1b;    // row = 32 x uint4 (8 bf16/lane)
  // self loop (only half 0 contributes; row load harmless for half 1)
  float wS = (hf == 0) ? __expf(leaky(esS + edh)) : 0.f;
  float ssum = wS;
  uint4 hv = h1v4[(long)i*32 + lh];
  float a0 = bflo(hv.x)*wS, a1 = bfhi(hv.x)*wS, a2 = bflo(hv.y)*wS, a3 = bfhi(hv.y)*wS;
  float a4 = bflo(hv.z)*wS, a5 = bfhi(hv.z)*wS, a6 = bflo(hv.w)*wS, a7 = bfhi(hv.w)*wS;
  for (int j0 = start; j0 < end; j0 += 16){
    int nj = end - j0; if (nj > 16) nj = 16;
    int ce = (e < nj) ? e : nj - 1;
    int sE = csr[j0 + ce];
    float wv = (e < nj) ? __expf(leaky(es1[sE*NH + h] + edw)) : 0.f;
    int jj = 0;
    for (; jj + 8 <= nj; jj += 8){         // full block: slots jj..jj+7 all valid
      int c0 = (jj+0+hf)<<2, c1 = (jj+2+hf)<<2, c2 = (jj+4+hf)<<2, c3 = (jj+6+hf)<<2;
      int s0 = __shfl(sE, c0);
      int s1 = __shfl(sE, c1);
      int s2 = __shfl(sE, c2);
      int s3 = __shfl(sE, c3);
      uint4 r0 = h1v4[(long)s0*32 + lh];
      uint4 r1 = h1v4[(long)s1*32 + lh];
      uint4 r2 = h1v4[(long)s2*32 + lh];
      uint4 r3 = h1v4[(long)s3*32 + lh];
      float w0 = __shfl(wv, c0 | headO);
      float w1 = __shfl(wv, c1 | headO);
      float w2 = __shfl(wv, c2 | headO);
      float w3 = __shfl(wv, c3 | headO);
      a0 += bflo(r0.x)*w0; a1 += bfhi(r0.x)*w0; a2 += bflo(r0.y)*w0; a3 += bfhi(r0.y)*w0;
      a4 += bflo(r0.z)*w0; a5 += bfhi(r0.z)*w0; a6 += bflo(r0.w)*w0; a7 += bfhi(r0.w)*w0;
      a0 += bflo(r1.x)*w1; a1 += bfhi(r1.x)*w1; a2 += bflo(r1.y)*w1; a3 += bfhi(r1.y)*w1;
      a4 += bflo(r1.z)*w1; a5 += bfhi(r1.z)*w1; a6 += bflo(r1.w)*w1; a7 += bfhi(r1.w)*w1;
      a0 += bflo(r2.x)*w2; a1 += bfhi(r2.x)*w2; a2 += bflo(r2.y)*w2; a3 += bfhi(r2.y)*w2;
      a4 += bflo(r2.z)*w2; a5 += bfhi(r2.z)*w2; a6 += bflo(r2.w)*w2; a7 += bfhi(r2.w)*w2;
      a0 += bflo(r3.x)*w3; a1 += bfhi(r3.x)*w3; a2 += bflo(r3.y)*w3; a3 += bfhi(r3.y)*w3;
      a4 += bflo(r3.z)*w3; a5 += bfhi(r3.z)*w3; a6 += bflo(r3.w)*w3; a7 += bfhi(r3.w)*w3;
      ssum += w0 + w1 + w2 + w3;
    }
    for (; jj < nj; jj += 2){              // uniform tail, ≤4 iters; slot may be ==nj for hf=1
      int slot = jj + hf;
      int slc = (slot < nj) ? slot : nj - 1;   // clamp: shfl source stays in range
      int cc = slc << 2;
      int s = __shfl(sE, cc);
      float w = __shfl(wv, cc | headO);
      if (slot >= nj) w = 0.f;
      uint4 r = h1v4[(long)s*32 + lh];
      a0 += bflo(r.x)*w; a1 += bfhi(r.x)*w; a2 += bflo(r.y)*w; a3 += bfhi(r.y)*w;
      a4 += bflo(r.z)*w; a5 += bfhi(r.z)*w; a6 += bflo(r.w)*w; a7 += bfhi(r.w)*w;
      ssum += w;
    }
  }
  // combine halves
  a0 += __shfl_xor(a0,32); a1 += __shfl_xor(a1,32); a2 += __shfl_xor(a2,32); a3 += __shfl_xor(a3,32);
  a4 += __shfl_xor(a4,32); a5 += __shfl_xor(a5,32); a6 += __shfl_xor(a6,32); a7 += __shfl_xor(a7,32);
  ssum += __shfl_xor(ssum,32);
  if (hf == 0){
    float inv = 1.f/(ssum + 1e-16f);
    float4 bb0 = *(const float4*)&b1[8*lh];
    float4 bb1 = *(const float4*)&b1[8*lh+4];
    uint4 o;
    o.x = pack2(a0*inv + bb0.x, a1*inv + bb0.y);
    o.y = pack2(a2*inv + bb0.z, a3*inv + bb0.w);
    o.z = pack2(a4*inv + bb1.x, a5*inv + bb1.y);
    o.w = pack2(a6*inv + bb1.z, a7*inv + bb1.w);
    ((uint4*)y1b)[(long)i*32 + lh] = o;
  }
}

// ---------------- BN column stats (bf16 input, C1 channels) ----------------
__global__ __launch_bounds__(256) void k_colstats1(const ushort_t* __restrict__ y, float* __restrict__ st){
  const uint_t* yu = (const uint_t*)y;
  int c2 = threadIdx.x & 127, half = threadIdx.x >> 7;
  long r0 = (long)blockIdx.x * 128;
  float s0=0,q0=0,s1=0,q1=0;
  for (int r = half; r < 128; r += 2){
    long rr = r0 + r;
    if (rr < N_NODES){
      uint_t u = yu[rr*128 + c2];
      float a = bflo(u), b = bfhi(u);
      s0 += a; q0 += a*a; s1 += b; q1 += b*b;
    }
  }
  int c = c2*2;
  atomicAdd(&st[c], s0);      atomicAdd(&st[C1 + c], q0);
  atomicAdd(&st[c+1], s1);    atomicAdd(&st[C1 + c+1], q1);
}

// ---------------- BN column stats (f32 input) ----------------
template<int C, int RPB>
__global__ __launch_bounds__(256) void k_colstats(const float* __restrict__ y, float* __restrict__ st){
  int c = threadIdx.x % C;
  int rl = threadIdx.x / C;
  const int rpb = 256 / C;
  long r0 = (long)blockIdx.x * RPB;
  float s = 0.f, q = 0.f;
  for (int r = rl; r < RPB; r += rpb){
    long rr = r0 + r;
    if (rr < N_NODES){ float v = y[rr*C + c]; s += v; q += v*v; }
  }
  atomicAdd(&st[c], s); atomicAdd(&st[C + c], q);
}

__global__ void k_prep(const float* __restrict__ st, const float* __restrict__ g, const float* __restrict__ be,
                       float* __restrict__ ss, int C){
  int c = blockIdx.x*blockDim.x + threadIdx.x;
  if (c < C){
    float mean = st[c] / (float)N_NODES;
    float var  = st[C + c] / (float)N_NODES - mean*mean;
    float sc = g[c] * rsqrtf(var + BN_EPS);
    ss[c] = sc;
    ss[C + c] = be[c] - mean*sc;
  }
}

// ---------------- K6: h2 = relu(bn(y1)) @ W2 (bf16 out) + fused es2/ed2 ----------------
__global__ __launch_bounds__(256) void k_gemm2(const ushort_t* __restrict__ y1b, const float* __restrict__ W2,
    const float* __restrict__ ss1, const float* __restrict__ a2s, const float* __restrict__ a2d,
    ushort_t* __restrict__ h2b, float* __restrict__ es2, float* __restrict__ ed2){
  __shared__ float As[64][68];
  __shared__ float Bs[64][64];
  __shared__ float as_s[HID], ad_s[HID];
  __shared__ float ss_s[2*C1];
  int t = threadIdx.x;
  if (t < HID){ as_s[t] = a2s[t]; ad_s[t] = a2d[t]; }
  for (int idx = t; idx < 2*C1; idx += 256) ss_s[idx] = ss1[idx];
  int tx = t & 15, ty = t >> 4;
  long i0 = (long)blockIdx.x * 64;
  float acc[4][4] = {};
  __syncthreads();
  for (int kc = 0; kc < C1; kc += 64){
    const uint_t* yu = (const uint_t*)y1b;
    for (int idx = t; idx < 64*32; idx += 256){
      int r = idx >> 5, k2 = idx & 31;
      long gi = i0 + r;
      int k = kc + k2*2;
      float v0 = 0.f, v1 = 0.f;
      if (gi < N_NODES){
        uint_t u = yu[gi*128 + (k >> 1)];
        v0 = fmaxf(bflo(u)*ss_s[k]   + ss_s[C1+k],   0.f);
        v1 = fmaxf(bfhi(u)*ss_s[k+1] + ss_s[C1+k+1], 0.f);
      }
      As[r][k2*2]   = v0;
      As[r][k2*2+1] = v1;
    }
    for (int idx = t; idx < 64*64; idx += 256){
      Bs[idx >> 6][idx & 63] = W2[(kc + (idx >> 6))*HID + (idx & 63)];
    }
    __syncthreads();
    #pragma unroll 4
    for (int kk = 0; kk < 64; kk += 4){
      float4 va0 = *(float4*)&As[4*ty+0][kk];
      float4 va1 = *(float4*)&As[4*ty+1][kk];
      float4 va2 = *(float4*)&As[4*ty+2][kk];
      float4 va3 = *(float4*)&As[4*ty+3][kk];
      float4 vb0 = *(float4*)&Bs[kk+0][4*tx];
      float4 vb1 = *(float4*)&Bs[kk+1][4*tx];
      float4 vb2 = *(float4*)&Bs[kk+2][4*tx];
      float4 vb3 = *(float4*)&Bs[kk+3][4*tx];
      acc[0][0] += va0.x*vb0.x + va0.y*vb1.x + va0.z*vb2.x + va0.w*vb3.x;
      acc[0][1] += va0.x*vb0.y + va0.y*vb1.y + va0.z*vb2.y + va0.w*vb3.y;
      acc[0][2] += va0.x*vb0.z + va0.y*vb1.z + va0.z*vb2.z + va0.w*vb3.z;
      acc[0][3] += va0.x*vb0.w + va0.y*vb1.w + va0.z*vb2.w + va0.w*vb3.w;
      acc[1][0] += va1.x*vb0.x + va1.y*vb1.x + va1.z*vb2.x + va1.w*vb3.x;
      acc[1][1] += va1.x*vb0.y + va1.y*vb1.y + va1.z*vb2.y + va1.w*vb3.y;
      acc[1][2] += va1.x*vb0.z + va1.y*vb1.z + va1.z*vb2.z + va1.w*vb3.z;
      acc[1][3] += va1.x*vb0.w + va1.y*vb1.w + va1.z*vb2.w + va1.w*vb3.w;
      acc[2][0] += va2.x*vb0.x + va2.y*vb1.x + va2.z*vb2.x + va2.w*vb3.x;
      acc[2][1] += va2.x*vb0.y + va2.y*vb1.y + va2.z*vb2.y + va2.w*vb3.y;
      acc[2][2] += va2.x*vb0.z + va2.y*vb1.z + va2.z*vb2.z + va2.w*vb3.z;
      acc[2][3] += va2.x*vb0.w + va2.y*vb1.w + va2.z*vb2.w + va2.w*vb3.w;
      acc[3][0] += va3.x*vb0.x + va3.y*vb1.x + va3.z*vb2.x + va3.w*vb3.x;
      acc[3][1] += va3.x*vb0.y + va3.y*vb1.y + va3.z*vb2.y + va3.w*vb3.y;
      acc[3][2] += va3.x*vb0.z + va3.y*vb1.z + va3.z*vb2.z + va3.w*vb3.z;
      acc[3][3] += va3.x*vb0.w + va3.y*vb1.w + va3.z*vb2.w + va3.w*vb3.w;
    }
    __syncthreads();
  }
  #pragma unroll
  for (int rr = 0; rr < 4; ++rr){
    long gi = i0 + 4*ty + rr;
    if (gi < N_NODES){
      uint_t p0 = pack2(acc[rr][0], acc[rr][1]);
      uint_t p1 = pack2(acc[rr][2], acc[rr][3]);
      *(uint2*)&h2b[gi*HID + 4*tx] = make_uint2(p0, p1);
      float ps = acc[rr][0]*as_s[4*tx+0] + acc[rr][1]*as_s[4*tx+1]
               + acc[rr][2]*as_s[4*tx+2] + acc[rr][3]*as_s[4*tx+3];
      float pd = acc[rr][0]*ad_s[4*tx+0] + acc[rr][1]*ad_s[4*tx+1]
               + acc[rr][2]*ad_s[4*tx+2] + acc[rr][3]*ad_s[4*tx+3];
      #pragma unroll
      for (int o = 8; o >= 1; o >>= 1){ ps += __shfl_xor(ps,o); pd += __shfl_xor(pd,o); }
      if (tx == 0){ es2[gi] = ps; ed2[gi] = pd; }
    }
  }
}

// ---------------- K7: layer-2 GAT aggregation, quarter-wave rows ----------------
// Lanes lq=0..15 hold 4 channels each (uint2 = 4 bf16); quarters q=0..3 process
// edges (jj+4k+q). Full 16-edge blocks mask-free; uniform step-4 tail with
// clamped shfl sources (wv=0 lanes auto-mask invalid slots' weights).
__global__ __launch_bounds__(256) void k_agg2(const ushort_t* __restrict__ h2b,
    const float* __restrict__ es2, const float* __restrict__ ed2,
    const int* __restrict__ off, const int* __restrict__ csr,
    const float* __restrict__ b2, float* __restrict__ y2){
  int lane = threadIdx.x & 63, wid = threadIdx.x >> 6;
  int i = blockIdx.x*4 + wid;
  if (i >= N_NODES) return;
  int lq = lane & 15, q = lane >> 4;
  float edv = ed2[i];
  int start = off[i], end = off[i+1];
  const uint2* h2u2 = (const uint2*)h2b;   // row = 16 x uint2 (4 bf16/lane)
  float a0, a1, a2, a3, ssum;
  {
    float wS = (q == 0) ? __expf(leaky(es2[i] + edv)) : 0.f;
    uint2 uS = h2u2[(long)i*16 + lq];
    a0 = bflo(uS.x)*wS; a1 = bfhi(uS.x)*wS; a2 = bflo(uS.y)*wS; a3 = bfhi(uS.y)*wS;
    ssum = wS;
  }
  for (int j0 = start; j0 < end; j0 += 64){
    int nj = end - j0; if (nj > 64) nj = 64;
    int ce = (lane < nj) ? lane : nj - 1;
    int sE = csr[j0 + ce];
    float wv = (lane < nj) ? __expf(leaky(es2[sE] + edv)) : 0.f;
    int jj = 0;
    for (; jj + 16 <= nj; jj += 16){       // full block: slots jj..jj+15 all valid
      int c0 = jj + q, c1 = jj + 4 + q, c2 = jj + 8 + q, c3 = jj + 12 + q;
      int s0 = __shfl(sE, c0);
      int s1 = __shfl(sE, c1);
      int s2 = __shfl(sE, c2);
      int s3 = __shfl(sE, c3);
      uint2 r0 = h2u2[(long)s0*16 + lq];
      uint2 r1 = h2u2[(long)s1*16 + lq];
      uint2 r2 = h2u2[(long)s2*16 + lq];
      uint2 r3 = h2u2[(long)s3*16 + lq];
      float w0 = __shfl(wv, c0);
      float w1 = __shfl(wv, c1);
      float w2 = __shfl(wv, c2);
      float w3 = __shfl(wv, c3);
      a0 += bflo(r0.x)*w0; a1 += bfhi(r0.x)*w0; a2 += bflo(r0.y)*w0; a3 += bfhi(r0.y)*w0;
      a0 += bflo(r1.x)*w1; a1 += bfhi(r1.x)*w1; a2 += bflo(r1.y)*w1; a3 += bfhi(r1.y)*w1;
      a0 += bflo(r2.x)*w2; a1 += bfhi(r2.x)*w2; a2 += bflo(r2.y)*w2; a3 += bfhi(r2.y)*w2;
      a0 += bflo(r3.x)*w3; a1 += bfhi(r3.x)*w3; a2 += bflo(r3.y)*w3; a3 += bfhi(r3.y)*w3;
      ssum += w0 + w1 + w2 + w3;
    }
    for (; jj < nj; jj += 4){              // uniform tail, ≤4 iters
      int slot = jj + q;                    // may be >= nj (up to nj+3)
      int slc = (slot < nj) ? slot : nj - 1;
      int s = __shfl(sE, slc);
      float w = __shfl(wv, slc);
      if (slot >= nj) w = 0.f;
      uint2 r = h2u2[(long)s*16 + lq];
      a0 += bflo(r.x)*w; a1 += bfhi(r.x)*w; a2 += bflo(r.y)*w; a3 += bfhi(r.y)*w;
      ssum += w;
    }
  }
  // reduce across quarters
  a0 += __shfl_xor(a0,16); a1 += __shfl_xor(a1,16); a2 += __shfl_xor(a2,16); a3 += __shfl_xor(a3,16);
  ssum += __shfl_xor(ssum,16);
  a0 += __shfl_xor(a0,32); a1 += __shfl_xor(a1,32); a2 += __shfl_xor(a2,32); a3 += __shfl_xor(a3,32);
  ssum += __shfl_xor(ssum,32);
  if (q == 0){
    float inv = 1.f/(ssum + 1e-16f);
    float4 bb = *(const float4*)&b2[4*lq];
    float4 o;
    o.x = a0*inv + bb.x; o.y = a1*inv + bb.y;
    o.z = a2*inv + bb.z; o.w = a3*inv + bb.w;
    ((float4*)y2)[(long)i*16 + lq] = o;
  }
}

// ---------------- climber MLP: cv[g] = relu(climber@Wc + bc) ----------------
__global__ void k_climber(const float* __restrict__ cl, const float* __restrict__ Wc,
                          const float* __restrict__ bc, float* __restrict__ cv){
  int idx = blockIdx.x*blockDim.x + threadIdx.x;
  if (idx < G_GRAPHS*HID){
    int g = idx >> 6, j = idx & 63;
    float a = bc[j];
    #pragma unroll
    for (int k = 0; k < D_CL; ++k) a += cl[g*D_CL + k]*Wc[k*HID + j];
    cv[idx] = fmaxf(a, 0.f);
  }
}

// ---------------- final: tiled GEMM. 64 rows/block.
__global__ __launch_bounds__(256) void k_final(const float* __restrict__ y2,
    const float* __restrict__ ss2, const int* __restrict__ batch, const float* __restrict__ cv,
    const float* __restrict__ Wcl1, const float* __restrict__ bcl1,
    const float* __restrict__ Wcl2, const float* __restrict__ bcl2,
    float* __restrict__ out){
  __shared__ float As[64][132];
  __shared__ float Bs[128][64];
  __shared__ float ss2s[2*HID];
  __shared__ float b1s[HID];
  __shared__ float W2s[HID*D_OUT];
  int t = threadIdx.x;
  long i0 = (long)blockIdx.x * 64;
  if (t < 2*HID) ss2s[t] = ss2[t];
  if (t >= 128 && t < 192) b1s[t-128] = bcl1[t-128];
  W2s[t] = Wcl2[t];
  __syncthreads();   // ss2s consumed by the As staging below (all waves)
  const float2* y2v = (const float2*)y2;
  #pragma unroll
  for (int ii = 0; ii < 8; ++ii){
    int idx = t + 256*ii;
    int r = idx >> 5, k2 = idx & 31;
    long gi = i0 + r;
    float2 v = make_float2(0.f, 0.f);
    if (gi < N_NODES) v = y2v[gi*32 + k2];
    int k = k2*2;
    As[r][k]   = fmaxf(v.x*ss2s[k]   + ss2s[HID+k],   0.f);
    As[r][k+1] = fmaxf(v.y*ss2s[k+1] + ss2s[HID+k+1], 0.f);
  }
  const float2* cvv = (const float2*)cv;
  #pragma unroll
  for (int ii = 0; ii < 8; ++ii){
    int idx = t + 256*ii;
    int r = idx >> 5, k2 = idx & 31;
    long gi = i0 + r;
    float2 v = make_float2(0.f, 0.f);
    if (gi < N_NODES){ int g = batch[gi]; v = cvv[g*32 + k2]; }
    As[r][HID + k2*2]   = v.x;
    As[r][HID + k2*2+1] = v.y;
  }
  #pragma unroll
  for (int ii = 0; ii < 8; ++ii){
    int idx = t + 256*ii;
    int kk = idx >> 4, c4 = idx & 15;
    *(float4*)&Bs[kk][c4*4] = *(const float4*)&Wcl1[kk*64 + c4*4];
  }
  __syncthreads();
  int tx = t & 15, ty = t >> 4;
  float acc[4][4] = {};
  #pragma unroll 4
  for (int kk = 0; kk < 2*HID; kk += 4){
    float4 a0 = *(float4*)&As[4*ty+0][kk];
    float4 a1 = *(float4*)&As[4*ty+1][kk];
    float4 a2 = *(float4*)&As[4*ty+2][kk];
    float4 a3 = *(float4*)&As[4*ty+3][kk];
    float4 b0 = *(float4*)&Bs[kk+0][4*tx];
    float4 b1 = *(float4*)&Bs[kk+1][4*tx];
    float4 b2 = *(float4*)&Bs[kk+2][4*tx];
    float4 b3 = *(float4*)&Bs[kk+3][4*tx];
    acc[0][0] += a0.x*b0.x + a0.y*b1.x + a0.z*b2.x + a0.w*b3.x;
    acc[0][1] += a0.x*b0.y + a0.y*b1.y + a0.z*b2.y + a0.w*b3.y;
    acc[0][2] += a0.x*b0.z + a0.y*b1.z + a0.z*b2.z + a0.w*b3.z;
    acc[0][3] += a0.x*b0.w + a0.y*b1.w + a0.z*b2.w + a0.w*b3.w;
    acc[1][0] += a1.x*b0.x + a1.y*b1.x + a1.z*b2.x + a1.w*b3.x;
    acc[1][1] += a1.x*b0.y + a1.y*b1.y + a1.z*b2.y + a1.w*b3.y;
    acc[1][2] += a1.x*b0.z + a1.y*b1.z + a1.z*b2.z + a1.w*b3.z;
    acc[1][3] += a1.x*b0.w + a1.y*b1.w + a1.z*b2.w + a1.w*b3.w;
    acc[2][0] += a2.x*b0.x + a2.y*b1.x + a2.z*b2.x + a2.w*b3.x;
    acc[2][1] += a2.x*b0.y + a2.y*b1.y + a2.z*b2.y + a2.w*b3.y;
    acc[2][2] += a2.x*b0.z + a2.y*b1.z + a2.z*b2.z + a2.w*b3.z;
    acc[2][3] += a2.x*b0.w + a2.y*b1.w + a2.z*b2.w + a2.w*b3.w;
    acc[3][0] += a3.x*b0.x + a3.y*b1.x + a3.z*b2.x + a3.w*b3.x;
    acc[3][1] += a3.x*b0.y + a3.y*b1.y + a3.z*b2.y + a3.w*b3.y;
    acc[3][2] += a3.x*b0.z + a3.y*b1.z + a3.z*b2.z + a3.w*b3.z;
    acc[3][3] += a3.x*b0.w + a3.y*b1.w + a3.z*b2.w + a3.w*b3.w;
  }
  float p[4][4];
  #pragma unroll
  for (int r = 0; r < 4; ++r){
    #pragma unroll
    for (int c = 0; c < 4; ++c)
      acc[r][c] = fmaxf(acc[r][c] + b1s[4*tx+c], 0.f);
    #pragma unroll
    for (int oc = 0; oc < 4; ++oc){
      p[r][oc] = acc[r][0]*W2s[(4*tx+0)*4+oc] + acc[r][1]*W2s[(4*tx+1)*4+oc]
               + acc[r][2]*W2s[(4*tx+2)*4+oc] + acc[r][3]*W2s[(4*tx+3)*4+oc];
    }
  }
  #pragma unroll
  for (int o = 8; o >= 1; o >>= 1){
    #pragma unroll
    for (int r = 0; r < 4; ++r){
      p[r][0] += __shfl_xor(p[r][0], o);
      p[r][1] += __shfl_xor(p[r][1], o);
      p[r][2] += __shfl_xor(p[r][2], o);
      p[r][3] += __shfl_xor(p[r][3], o);
    }
  }
  if (tx == 0){
    float4 bb = *(const float4*)bcl2;
    #pragma unroll
    for (int r = 0; r < 4; ++r){
      long gi = i0 + 4*ty + r;
      if (gi < N_NODES){
        float4 o;
        o.x = p[r][0] + bb.x; o.y = p[r][1] + bb.y;
        o.z = p[r][2] + bb.z; o.w = p[r][3] + bb.w;
        *(float4*)&out[gi*4] = o;
      }
    }
  }
}

extern "C" void kernel_launch(void* const* d_in, const int* in_sizes, int n_in,
                              void* d_out, int out_size, void* d_ws, size_t ws_size,
                              hipStream_t stream){
  const float* x    = (const float*)d_in[0];
  const float* cl   = (const float*)d_in[1];
  const int*   ei   = (const int*)d_in[2];
  const int*   batch= (const int*)d_in[3];
  const float* W1   = (const float*)d_in[4];
  const float* a1s  = (const float*)d_in[5];
  const float* a1d  = (const float*)d_in[6];
  const float* b1   = (const float*)d_in[7];
  const float* g1   = (const float*)d_in[8];
  const float* be1  = (const float*)d_in[9];
  const float* W2   = (const float*)d_in[10];
  const float* a2s  = (const float*)d_in[11];
  const float* a2d  = (const float*)d_in[12];
  const float* b2   = (const float*)d_in[13];
  const float* g2   = (const float*)d_in[14];
  const float* be2  = (const float*)d_in[15];
  const float* Wc   = (const float*)d_in[16];
  const float* bc   = (const float*)d_in[17];
  const float* Wcl1 = (const float*)d_in[18];
  const float* bcl1 = (const float*)d_in[19];
  const float* Wcl2 = (const float*)d_in[20];
  const float* bcl2 = (const float*)d_in[21];
  const int* srcE = ei;
  const int* dstE = ei + N_EDGES;
  float* out = (float*)d_out;

  char* w = (char*)d_ws;
  auto take = [&](size_t bytes)->char*{ char* p = w; w += (bytes + 255) & ~(size_t)255; return p; };
  ushort_t* h1b = (ushort_t*)take((size_t)N_NODES*C1*2);   // 25.6 MB, dead after k_agg1
  ushort_t* y1b = (ushort_t*)take((size_t)N_NODES*C1*2);   // 25.6 MB bf16
  float* es1 = (float*)take((size_t)N_NODES*NH*4);
  float* ed1 = (float*)take((size_t)N_NODES*NH*4);
  float* es2 = (float*)take((size_t)N_NODES*4);
  float* ed2 = (float*)take((size_t)N_NODES*4);
  float* cv  = (float*)take((size_t)G_GRAPHS*HID*4);
  float* st  = (float*)take((2*C1 + 2*HID)*4);   // st1 | st2 contiguous -> one memset
  float* ss1 = (float*)take(2*C1*4);
  float* ss2 = (float*)take(2*HID*4);
  int* cnt  = (int*)take((size_t)CNT_PAD*4);
  int* off  = (int*)take((size_t)(CNT_PAD+16)*4);
  int* csr  = (int*)take((size_t)N_EDGES*4);
  float* st1 = st;
  float* st2 = st + 2*C1;
  // alias into dead h1b region after k_agg1: h2b (6.4 MB) at 0, y2 (12.8 MB) at +8 MB
  ushort_t* h2b = h1b;
  float* y2 = (float*)((char*)h1b + ((size_t)8 << 20));

  hipMemsetAsync(cnt, 0, (size_t)CNT_PAD*4, stream);
  hipMemsetAsync(st, 0, (2*C1 + 2*HID)*4, stream);

  k_node1<<<(N_NODES+15)/16, 256, 0, stream>>>(x, W1, a1s, a1d, h1b, es1, ed1);
  k_hist<<<(N_EDGES+255)/256, 256, 0, stream>>>(dstE, cnt);
  k_scan<<<1, 1024, 0, stream>>>(cnt, off);
  k_scatter<<<(N_EDGES+255)/256, 256, 0, stream>>>(srcE, dstE, off, cnt, csr);

  k_agg1<<<(N_NODES+3)/4, 256, 0, stream>>>(h1b, es1, ed1, off, csr, b1, y1b);
  k_colstats1<<<(N_NODES+127)/128, 256, 0, stream>>>(y1b, st1);
  k_prep<<<1, 256, 0, stream>>>(st1, g1, be1, ss1, C1);
  k_gemm2<<<(N_NODES+63)/64, 256, 0, stream>>>(y1b, W2, ss1, a2s, a2d, h2b, es2, ed2);
  k_agg2<<<(N_NODES+3)/4, 256, 0, stream>>>(h2b, es2, ed2, off, csr, b2, y2);
  k_colstats<HID,128><<<(N_NODES+127)/128, 256, 0, stream>>>(y2, st2);
  k_prep<<<1, 64, 0, stream>>>(st2, g2, be2, ss2, HID);
  k_climber<<<(G_GRAPHS*HID+255)/256, 256, 0, stream>>>(cl, Wc, bc, cv);
  k_final<<<(N_NODES+63)/64, 256, 0, stream>>>(y2, ss2, batch, cv, Wcl1, bcl1, Wcl2, bcl2, out);
}

// Round 9
// 390.275 us; speedup vs baseline: 1.4879x; 1.1107x over previous
//
#include <hip/hip_runtime.h>

#define N_NODES   50000
#define N_EDGES   800000
#define G_GRAPHS  512
#define D_IN      10
#define D_CL      6
#define HID       64
#define NH        4
#define C1        256   // NH*HID
#define D_OUT     4
#define BN_EPS    1e-5f
#define CNT_PAD   53248  // 52*1024, padded count buffer for vectorized scan
#define NB_N1     3125   // node1 sub-grid blocks in fused k_pre
#define NB_HIST   3125   // hist sub-grid blocks (3125*256 = 800000 exactly)

typedef unsigned short ushort_t;
typedef unsigned int uint_t;

__device__ __forceinline__ float leaky(float x){ return x > 0.f ? x : 0.2f*x; }
__device__ __forceinline__ ushort_t f2bf(float f){
  unsigned u = __float_as_uint(f);
  return (ushort_t)((u + 0x7fffu + ((u >> 16) & 1u)) >> 16);
}
__device__ __forceinline__ float bflo(uint_t u){ return __uint_as_float(u << 16); }
__device__ __forceinline__ float bfhi(uint_t u){ return __uint_as_float(u & 0xffff0000u); }
__device__ __forceinline__ uint_t pack2(float a, float b){
  return (uint_t)f2bf(a) | ((uint_t)f2bf(b) << 16);
}

// ---------------- K_pre: grid-fused {h1 = x@W1 + attention logits} || {degree hist + edge rank} ----------------
__global__ __launch_bounds__(256) void k_pre(const float* __restrict__ x,
    const float* __restrict__ W1, const float* __restrict__ a1s, const float* __restrict__ a1d,
    ushort_t* __restrict__ h1b, float* __restrict__ es1, float* __restrict__ ed1,
    const int* __restrict__ dstE, int* __restrict__ cnt, int* __restrict__ rank){
  if (blockIdx.x >= NB_N1){
    // hist half: count in-degree AND capture each edge's rank within its dst bucket
    int e = (blockIdx.x - NB_N1)*256 + threadIdx.x;
    if (e < N_EDGES){
      int r = atomicAdd(&cnt[dstE[e]], 1);
      rank[e] = r;
    }
    return;
  }
  __shared__ float W1s[D_IN*C1];
  __shared__ float as_s[C1], ad_s[C1];
  int t = threadIdx.x;
  for (int idx = t; idx < D_IN*C1; idx += 256) W1s[idx] = W1[idx];
  as_s[t] = a1s[t]; ad_s[t] = a1d[t];
  __syncthreads();
  int lane = t & 63, wid = t >> 6;
  for (int nn = 0; nn < 16; ++nn){
    int i = blockIdx.x*16 + nn;
    if (i >= N_NODES) return;
    const float* xr = x + (long)i*D_IN;
    float acc = 0.f;
    #pragma unroll
    for (int k = 0; k < D_IN; ++k) acc += xr[k]*W1s[k*C1 + t];
    h1b[(long)i*C1 + t] = f2bf(acc);
    float ps = acc*as_s[t], pd = acc*ad_s[t];
    #pragma unroll
    for (int o = 32; o >= 1; o >>= 1){ ps += __shfl_xor(ps,o); pd += __shfl_xor(pd,o); }
    if (lane == 0){ es1[i*NH + wid] = ps; ed1[i*NH + wid] = pd; }
  }
}

// single-block vectorized exclusive scan of cnt -> off
__global__ __launch_bounds__(1024) void k_scan(const int* __restrict__ cnt, int* __restrict__ off){
  __shared__ int sh[1024];
  int t = threadIdx.x;
  int4 v[13];
  const int4* c4 = (const int4*)cnt;
  int base4 = t*13;
  int tsum = 0;
  #pragma unroll
  for (int k = 0; k < 13; ++k){
    v[k] = c4[base4 + k];
    tsum += v[k].x + v[k].y + v[k].z + v[k].w;
  }
  sh[t] = tsum;
  __syncthreads();
  for (int o = 1; o < 1024; o <<= 1){
    int xv = (t >= o) ? sh[t-o] : 0;
    __syncthreads();
    sh[t] += xv;
    __syncthreads();
  }
  int run = sh[t] - tsum;   // exclusive prefix of this thread's chunk
  int4* o4 = (int4*)off;
  #pragma unroll
  for (int k = 0; k < 13; ++k){
    int i = t*52 + k*4;
    int4 w_;
    w_.x = run; run += v[k].x;
    w_.y = run; run += v[k].y;
    w_.z = run; run += v[k].z;
    w_.w = run; run += v[k].w;
    if (i + 3 < N_NODES) o4[base4 + k] = w_;
    else {
      if (i+0 < N_NODES) off[i+0] = w_.x;
      if (i+1 < N_NODES) off[i+1] = w_.y;
      if (i+2 < N_NODES) off[i+2] = w_.z;
      if (i+3 < N_NODES) off[i+3] = w_.w;
    }
  }
  if (t == 0) off[N_NODES] = N_EDGES;
}

// atomic-free scatter: rank precomputed in k_pre
__global__ void k_scatter(const int* __restrict__ src, const int* __restrict__ dst,
                          const int* __restrict__ rank, const int* __restrict__ off,
                          int* __restrict__ csr){
  int e = blockIdx.x*blockDim.x + threadIdx.x;
  if (e < N_EDGES) csr[off[dst[e]] + rank[e]] = src[e];
}

// ---------------- K3: layer-1 GAT aggregation (unchanged from R8) ----------------
__global__ __launch_bounds__(256) void k_agg1(const ushort_t* __restrict__ h1b,
    const float* __restrict__ es1, const float* __restrict__ ed1,
    const int* __restrict__ off, const int* __restrict__ csr,
    const float* __restrict__ b1, ushort_t* __restrict__ y1b){
  int lane = threadIdx.x & 63, wid = threadIdx.x >> 6;
  int i = blockIdx.x*4 + wid;
  if (i >= N_NODES) return;
  int lh = lane & 31, hf = lane >> 5;
  int headO = lh >> 3;
  int h    = lane & 3;
  int e    = lane >> 2;
  float4 edv4 = *(const float4*)&ed1[i*NH];
  float4 esv4 = *(const float4*)&es1[i*NH];
  float edh = (headO==0)?edv4.x:(headO==1)?edv4.y:(headO==2)?edv4.z:edv4.w;
  float esS = (headO==0)?esv4.x:(headO==1)?esv4.y:(headO==2)?esv4.z:esv4.w;
  float edw = (h==0)?edv4.x:(h==1)?edv4.y:(h==2)?edv4.z:edv4.w;
  int start = off[i], end = off[i+1];
  const uint4* h1v4 = (const uint4*)h1b;
  float wS = (hf == 0) ? __expf(leaky(esS + edh)) : 0.f;
  float ssum = wS;
  uint4 hv = h1v4[(long)i*32 + lh];
  float a0 = bflo(hv.x)*wS, a1 = bfhi(hv.x)*wS, a2 = bflo(hv.y)*wS, a3 = bfhi(hv.y)*wS;
  float a4 = bflo(hv.z)*wS, a5 = bfhi(hv.z)*wS, a6 = bflo(hv.w)*wS, a7 = bfhi(hv.w)*wS;
  for (int j0 = start; j0 < end; j0 += 16){
    int nj = end - j0; if (nj > 16) nj = 16;
    int ce = (e < nj) ? e : nj - 1;
    int sE = csr[j0 + ce];
    float wv = (e < nj) ? __expf(leaky(es1[sE*NH + h] + edw)) : 0.f;
    int jj = 0;
    for (; jj + 8 <= nj; jj += 8){
      int c0 = (jj+0+hf)<<2, c1 = (jj+2+hf)<<2, c2 = (jj+4+hf)<<2, c3 = (jj+6+hf)<<2;
      int s0 = __shfl(sE, c0);
      int s1 = __shfl(sE, c1);
      int s2 = __shfl(sE, c2);
      int s3 = __shfl(sE, c3);
      uint4 r0 = h1v4[(long)s0*32 + lh];
      uint4 r1 = h1v4[(long)s1*32 + lh];
      uint4 r2 = h1v4[(long)s2*32 + lh];
      uint4 r3 = h1v4[(long)s3*32 + lh];
      float w0 = __shfl(wv, c0 | headO);
      float w1 = __shfl(wv, c1 | headO);
      float w2 = __shfl(wv, c2 | headO);
      float w3 = __shfl(wv, c3 | headO);
      a0 += bflo(r0.x)*w0; a1 += bfhi(r0.x)*w0; a2 += bflo(r0.y)*w0; a3 += bfhi(r0.y)*w0;
      a4 += bflo(r0.z)*w0; a5 += bfhi(r0.z)*w0; a6 += bflo(r0.w)*w0; a7 += bfhi(r0.w)*w0;
      a0 += bflo(r1.x)*w1; a1 += bfhi(r1.x)*w1; a2 += bflo(r1.y)*w1; a3 += bfhi(r1.y)*w1;
      a4 += bflo(r1.z)*w1; a5 += bfhi(r1.z)*w1; a6 += bflo(r1.w)*w1; a7 += bfhi(r1.w)*w1;
      a0 += bflo(r2.x)*w2; a1 += bfhi(r2.x)*w2; a2 += bflo(r2.y)*w2; a3 += bfhi(r2.y)*w2;
      a4 += bflo(r2.z)*w2; a5 += bfhi(r2.z)*w2; a6 += bflo(r2.w)*w2; a7 += bfhi(r2.w)*w2;
      a0 += bflo(r3.x)*w3; a1 += bfhi(r3.x)*w3; a2 += bflo(r3.y)*w3; a3 += bfhi(r3.y)*w3;
      a4 += bflo(r3.z)*w3; a5 += bfhi(r3.z)*w3; a6 += bflo(r3.w)*w3; a7 += bfhi(r3.w)*w3;
      ssum += w0 + w1 + w2 + w3;
    }
    for (; jj < nj; jj += 2){
      int slot = jj + hf;
      int slc = (slot < nj) ? slot : nj - 1;
      int cc = slc << 2;
      int s = __shfl(sE, cc);
      float w = __shfl(wv, cc | headO);
      if (slot >= nj) w = 0.f;
      uint4 r = h1v4[(long)s*32 + lh];
      a0 += bflo(r.x)*w; a1 += bfhi(r.x)*w; a2 += bflo(r.y)*w; a3 += bfhi(r.y)*w;
      a4 += bflo(r.z)*w; a5 += bfhi(r.z)*w; a6 += bflo(r.w)*w; a7 += bfhi(r.w)*w;
      ssum += w;
    }
  }
  a0 += __shfl_xor(a0,32); a1 += __shfl_xor(a1,32); a2 += __shfl_xor(a2,32); a3 += __shfl_xor(a3,32);
  a4 += __shfl_xor(a4,32); a5 += __shfl_xor(a5,32); a6 += __shfl_xor(a6,32); a7 += __shfl_xor(a7,32);
  ssum += __shfl_xor(ssum,32);
  if (hf == 0){
    float inv = 1.f/(ssum + 1e-16f);
    float4 bb0 = *(const float4*)&b1[8*lh];
    float4 bb1 = *(const float4*)&b1[8*lh+4];
    uint4 o;
    o.x = pack2(a0*inv + bb0.x, a1*inv + bb0.y);
    o.y = pack2(a2*inv + bb0.z, a3*inv + bb0.w);
    o.z = pack2(a4*inv + bb1.x, a5*inv + bb1.y);
    o.w = pack2(a6*inv + bb1.z, a7*inv + bb1.w);
    ((uint4*)y1b)[(long)i*32 + lh] = o;
  }
}

// ---------------- BN column stats (bf16 input, C1 channels) ----------------
__global__ __launch_bounds__(256) void k_colstats1(const ushort_t* __restrict__ y, float* __restrict__ st){
  const uint_t* yu = (const uint_t*)y;
  int c2 = threadIdx.x & 127, half = threadIdx.x >> 7;
  long r0 = (long)blockIdx.x * 128;
  float s0=0,q0=0,s1=0,q1=0;
  for (int r = half; r < 128; r += 2){
    long rr = r0 + r;
    if (rr < N_NODES){
      uint_t u = yu[rr*128 + c2];
      float a = bflo(u), b = bfhi(u);
      s0 += a; q0 += a*a; s1 += b; q1 += b*b;
    }
  }
  int c = c2*2;
  atomicAdd(&st[c], s0);      atomicAdd(&st[C1 + c], q0);
  atomicAdd(&st[c+1], s1);    atomicAdd(&st[C1 + c+1], q1);
}

// ---------------- BN column stats (f32 input) ----------------
template<int C, int RPB>
__global__ __launch_bounds__(256) void k_colstats(const float* __restrict__ y, float* __restrict__ st){
  int c = threadIdx.x % C;
  int rl = threadIdx.x / C;
  const int rpb = 256 / C;
  long r0 = (long)blockIdx.x * RPB;
  float s = 0.f, q = 0.f;
  for (int r = rl; r < RPB; r += rpb){
    long rr = r0 + r;
    if (rr < N_NODES){ float v = y[rr*C + c]; s += v; q += v*v; }
  }
  atomicAdd(&st[c], s); atomicAdd(&st[C + c], q);
}

// ---------------- K6: h2 = relu(bn(y1)) @ W2 (bf16 out) + fused es2/ed2; BN prep inlined ----------------
__global__ __launch_bounds__(256) void k_gemm2(const ushort_t* __restrict__ y1b, const float* __restrict__ W2,
    const float* __restrict__ st1, const float* __restrict__ g1, const float* __restrict__ be1,
    const float* __restrict__ a2s, const float* __restrict__ a2d,
    ushort_t* __restrict__ h2b, float* __restrict__ es2, float* __restrict__ ed2){
  __shared__ float As[64][68];
  __shared__ float Bs[64][64];
  __shared__ float as_s[HID], ad_s[HID];
  __shared__ float ss_s[2*C1];
  int t = threadIdx.x;
  if (t < HID){ as_s[t] = a2s[t]; ad_s[t] = a2d[t]; }
  {
    // inline BN prep: one channel per thread (C1 == blockDim)
    float mean = st1[t] / (float)N_NODES;
    float var  = st1[C1 + t] / (float)N_NODES - mean*mean;
    float sc = g1[t] * rsqrtf(var + BN_EPS);
    ss_s[t] = sc;
    ss_s[C1 + t] = be1[t] - mean*sc;
  }
  int tx = t & 15, ty = t >> 4;
  long i0 = (long)blockIdx.x * 64;
  float acc[4][4] = {};
  __syncthreads();
  for (int kc = 0; kc < C1; kc += 64){
    const uint_t* yu = (const uint_t*)y1b;
    for (int idx = t; idx < 64*32; idx += 256){
      int r = idx >> 5, k2 = idx & 31;
      long gi = i0 + r;
      int k = kc + k2*2;
      float v0 = 0.f, v1 = 0.f;
      if (gi < N_NODES){
        uint_t u = yu[gi*128 + (k >> 1)];
        v0 = fmaxf(bflo(u)*ss_s[k]   + ss_s[C1+k],   0.f);
        v1 = fmaxf(bfhi(u)*ss_s[k+1] + ss_s[C1+k+1], 0.f);
      }
      As[r][k2*2]   = v0;
      As[r][k2*2+1] = v1;
    }
    for (int idx = t; idx < 64*64; idx += 256){
      Bs[idx >> 6][idx & 63] = W2[(kc + (idx >> 6))*HID + (idx & 63)];
    }
    __syncthreads();
    #pragma unroll 4
    for (int kk = 0; kk < 64; kk += 4){
      float4 va0 = *(float4*)&As[4*ty+0][kk];
      float4 va1 = *(float4*)&As[4*ty+1][kk];
      float4 va2 = *(float4*)&As[4*ty+2][kk];
      float4 va3 = *(float4*)&As[4*ty+3][kk];
      float4 vb0 = *(float4*)&Bs[kk+0][4*tx];
      float4 vb1 = *(float4*)&Bs[kk+1][4*tx];
      float4 vb2 = *(float4*)&Bs[kk+2][4*tx];
      float4 vb3 = *(float4*)&Bs[kk+3][4*tx];
      acc[0][0] += va0.x*vb0.x + va0.y*vb1.x + va0.z*vb2.x + va0.w*vb3.x;
      acc[0][1] += va0.x*vb0.y + va0.y*vb1.y + va0.z*vb2.y + va0.w*vb3.y;
      acc[0][2] += va0.x*vb0.z + va0.y*vb1.z + va0.z*vb2.z + va0.w*vb3.z;
      acc[0][3] += va0.x*vb0.w + va0.y*vb1.w + va0.z*vb2.w + va0.w*vb3.w;
      acc[1][0] += va1.x*vb0.x + va1.y*vb1.x + va1.z*vb2.x + va1.w*vb3.x;
      acc[1][1] += va1.x*vb0.y + va1.y*vb1.y + va1.z*vb2.y + va1.w*vb3.y;
      acc[1][2] += va1.x*vb0.z + va1.y*vb1.z + va1.z*vb2.z + va1.w*vb3.z;
      acc[1][3] += va1.x*vb0.w + va1.y*vb1.w + va1.z*vb2.w + va1.w*vb3.w;
      acc[2][0] += va2.x*vb0.x + va2.y*vb1.x + va2.z*vb2.x + va2.w*vb3.x;
      acc[2][1] += va2.x*vb0.y + va2.y*vb1.y + va2.z*vb2.y + va2.w*vb3.y;
      acc[2][2] += va2.x*vb0.z + va2.y*vb1.z + va2.z*vb2.z + va2.w*vb3.z;
      acc[2][3] += va2.x*vb0.w + va2.y*vb1.w + va2.z*vb2.w + va2.w*vb3.w;
      acc[3][0] += va3.x*vb0.x + va3.y*vb1.x + va3.z*vb2.x + va3.w*vb3.x;
      acc[3][1] += va3.x*vb0.y + va3.y*vb1.y + va3.z*vb2.y + va3.w*vb3.y;
      acc[3][2] += va3.x*vb0.z + va3.y*vb1.z + va3.z*vb2.z + va3.w*vb3.z;
      acc[3][3] += va3.x*vb0.w + va3.y*vb1.w + va3.z*vb2.w + va3.w*vb3.w;
    }
    __syncthreads();
  }
  #pragma unroll
  for (int rr = 0; rr < 4; ++rr){
    long gi = i0 + 4*ty + rr;
    if (gi < N_NODES){
      uint_t p0 = pack2(acc[rr][0], acc[rr][1]);
      uint_t p1 = pack2(acc[rr][2], acc[rr][3]);
      *(uint2*)&h2b[gi*HID + 4*tx] = make_uint2(p0, p1);
      float ps = acc[rr][0]*as_s[4*tx+0] + acc[rr][1]*as_s[4*tx+1]
               + acc[rr][2]*as_s[4*tx+2] + acc[rr][3]*as_s[4*tx+3];
      float pd = acc[rr][0]*ad_s[4*tx+0] + acc[rr][1]*ad_s[4*tx+1]
               + acc[rr][2]*ad_s[4*tx+2] + acc[rr][3]*ad_s[4*tx+3];
      #pragma unroll
      for (int o = 8; o >= 1; o >>= 1){ ps += __shfl_xor(ps,o); pd += __shfl_xor(pd,o); }
      if (tx == 0){ es2[gi] = ps; ed2[gi] = pd; }
    }
  }
}

// ---------------- K7: layer-2 GAT aggregation (unchanged from R8) ----------------
__global__ __launch_bounds__(256) void k_agg2(const ushort_t* __restrict__ h2b,
    const float* __restrict__ es2, const float* __restrict__ ed2,
    const int* __restrict__ off, const int* __restrict__ csr,
    const float* __restrict__ b2, float* __restrict__ y2){
  int lane = threadIdx.x & 63, wid = threadIdx.x >> 6;
  int i = blockIdx.x*4 + wid;
  if (i >= N_NODES) return;
  int lq = lane & 15, q = lane >> 4;
  float edv = ed2[i];
  int start = off[i], end = off[i+1];
  const uint2* h2u2 = (const uint2*)h2b;
  float a0, a1, a2, a3, ssum;
  {
    float wS = (q == 0) ? __expf(leaky(es2[i] + edv)) : 0.f;
    uint2 uS = h2u2[(long)i*16 + lq];
    a0 = bflo(uS.x)*wS; a1 = bfhi(uS.x)*wS; a2 = bflo(uS.y)*wS; a3 = bfhi(uS.y)*wS;
    ssum = wS;
  }
  for (int j0 = start; j0 < end; j0 += 64){
    int nj = end - j0; if (nj > 64) nj = 64;
    int ce = (lane < nj) ? lane : nj - 1;
    int sE = csr[j0 + ce];
    float wv = (lane < nj) ? __expf(leaky(es2[sE] + edv)) : 0.f;
    int jj = 0;
    for (; jj + 16 <= nj; jj += 16){
      int c0 = jj + q, c1 = jj + 4 + q, c2 = jj + 8 + q, c3 = jj + 12 + q;
      int s0 = __shfl(sE, c0);
      int s1 = __shfl(sE, c1);
      int s2 = __shfl(sE, c2);
      int s3 = __shfl(sE, c3);
      uint2 r0 = h2u2[(long)s0*16 + lq];
      uint2 r1 = h2u2[(long)s1*16 + lq];
      uint2 r2 = h2u2[(long)s2*16 + lq];
      uint2 r3 = h2u2[(long)s3*16 + lq];
      float w0 = __shfl(wv, c0);
      float w1 = __shfl(wv, c1);
      float w2 = __shfl(wv, c2);
      float w3 = __shfl(wv, c3);
      a0 += bflo(r0.x)*w0; a1 += bfhi(r0.x)*w0; a2 += bflo(r0.y)*w0; a3 += bfhi(r0.y)*w0;
      a0 += bflo(r1.x)*w1; a1 += bfhi(r1.x)*w1; a2 += bflo(r1.y)*w1; a3 += bfhi(r1.y)*w1;
      a0 += bflo(r2.x)*w2; a1 += bfhi(r2.x)*w2; a2 += bflo(r2.y)*w2; a3 += bfhi(r2.y)*w2;
      a0 += bflo(r3.x)*w3; a1 += bfhi(r3.x)*w3; a2 += bflo(r3.y)*w3; a3 += bfhi(r3.y)*w3;
      ssum += w0 + w1 + w2 + w3;
    }
    for (; jj < nj; jj += 4){
      int slot = jj + q;
      int slc = (slot < nj) ? slot : nj - 1;
      int s = __shfl(sE, slc);
      float w = __shfl(wv, slc);
      if (slot >= nj) w = 0.f;
      uint2 r = h2u2[(long)s*16 + lq];
      a0 += bflo(r.x)*w; a1 += bfhi(r.x)*w; a2 += bflo(r.y)*w; a3 += bfhi(r.y)*w;
      ssum += w;
    }
  }
  a0 += __shfl_xor(a0,16); a1 += __shfl_xor(a1,16); a2 += __shfl_xor(a2,16); a3 += __shfl_xor(a3,16);
  ssum += __shfl_xor(ssum,16);
  a0 += __shfl_xor(a0,32); a1 += __shfl_xor(a1,32); a2 += __shfl_xor(a2,32); a3 += __shfl_xor(a3,32);
  ssum += __shfl_xor(ssum,32);
  if (q == 0){
    float inv = 1.f/(ssum + 1e-16f);
    float4 bb = *(const float4*)&b2[4*lq];
    float4 o;
    o.x = a0*inv + bb.x; o.y = a1*inv + bb.y;
    o.z = a2*inv + bb.z; o.w = a3*inv + bb.w;
    ((float4*)y2)[(long)i*16 + lq] = o;
  }
}

// ---------------- final: tiled GEMM, BN2 prep + climber MLP inlined ----------------
__global__ __launch_bounds__(256) void k_final(const float* __restrict__ y2,
    const float* __restrict__ st2, const float* __restrict__ g2, const float* __restrict__ be2,
    const int* __restrict__ batch,
    const float* __restrict__ cl, const float* __restrict__ Wc, const float* __restrict__ bc,
    const float* __restrict__ Wcl1, const float* __restrict__ bcl1,
    const float* __restrict__ Wcl2, const float* __restrict__ bcl2,
    float* __restrict__ out){
  __shared__ float As[64][132];
  __shared__ float Bs[128][64];
  __shared__ float ss2s[2*HID];
  __shared__ float b1s[HID];
  __shared__ float W2s[HID*D_OUT];
  __shared__ float Wcs[D_CL*HID];
  __shared__ float bcs[HID];
  int t = threadIdx.x;
  long i0 = (long)blockIdx.x * 64;
  if (t < HID){
    // inline BN2 prep
    float mean = st2[t] / (float)N_NODES;
    float var  = st2[HID + t] / (float)N_NODES - mean*mean;
    float sc = g2[t] * rsqrtf(var + BN_EPS);
    ss2s[t] = sc;
    ss2s[HID + t] = be2[t] - mean*sc;
  }
  if (t >= 64 && t < 128) bcs[t-64] = bc[t-64];
  if (t >= 128 && t < 192) b1s[t-128] = bcl1[t-128];
  W2s[t] = Wcl2[t];
  for (int idx = t; idx < D_CL*HID; idx += 256) Wcs[idx] = Wc[idx];
  __syncthreads();   // ss2s/Wcs/bcs consumed by the As staging below (all waves)
  const float2* y2v = (const float2*)y2;
  #pragma unroll
  for (int ii = 0; ii < 8; ++ii){
    int idx = t + 256*ii;
    int r = idx >> 5, k2 = idx & 31;
    long gi = i0 + r;
    float2 v = make_float2(0.f, 0.f);
    if (gi < N_NODES) v = y2v[gi*32 + k2];
    int k = k2*2;
    As[r][k]   = fmaxf(v.x*ss2s[k]   + ss2s[HID+k],   0.f);
    As[r][k+1] = fmaxf(v.y*ss2s[k+1] + ss2s[HID+k+1], 0.f);
  }
  // As right half: climber MLP computed inline (dropout=identity in eval)
  #pragma unroll
  for (int ii = 0; ii < 8; ++ii){
    int idx = t + 256*ii;
    int r = idx >> 5, k2 = idx & 31;
    long gi = i0 + r;
    int k = k2*2;
    float c0 = 0.f, c1 = 0.f;
    if (gi < N_NODES){
      int g = batch[gi];
      const float* cg = cl + (long)g*D_CL;
      c0 = bcs[k]; c1 = bcs[k+1];
      #pragma unroll
      for (int kk = 0; kk < D_CL; ++kk){
        float clv = cg[kk];
        c0 += clv*Wcs[kk*HID + k];
        c1 += clv*Wcs[kk*HID + k+1];
      }
      c0 = fmaxf(c0, 0.f); c1 = fmaxf(c1, 0.f);
    }
    As[r][HID + k]   = c0;
    As[r][HID + k+1] = c1;
  }
  #pragma unroll
  for (int ii = 0; ii < 8; ++ii){
    int idx = t + 256*ii;
    int kk = idx >> 4, c4 = idx & 15;
    *(float4*)&Bs[kk][c4*4] = *(const float4*)&Wcl1[kk*64 + c4*4];
  }
  __syncthreads();
  int tx = t & 15, ty = t >> 4;
  float acc[4][4] = {};
  #pragma unroll 4
  for (int kk = 0; kk < 2*HID; kk += 4){
    float4 a0 = *(float4*)&As[4*ty+0][kk];
    float4 a1 = *(float4*)&As[4*ty+1][kk];
    float4 a2 = *(float4*)&As[4*ty+2][kk];
    float4 a3 = *(float4*)&As[4*ty+3][kk];
    float4 b0 = *(float4*)&Bs[kk+0][4*tx];
    float4 b1 = *(float4*)&Bs[kk+1][4*tx];
    float4 b2 = *(float4*)&Bs[kk+2][4*tx];
    float4 b3 = *(float4*)&Bs[kk+3][4*tx];
    acc[0][0] += a0.x*b0.x + a0.y*b1.x + a0.z*b2.x + a0.w*b3.x;
    acc[0][1] += a0.x*b0.y + a0.y*b1.y + a0.z*b2.y + a0.w*b3.y;
    acc[0][2] += a0.x*b0.z + a0.y*b1.z + a0.z*b2.z + a0.w*b3.z;
    acc[0][3] += a0.x*b0.w + a0.y*b1.w + a0.z*b2.w + a0.w*b3.w;
    acc[1][0] += a1.x*b0.x + a1.y*b1.x + a1.z*b2.x + a1.w*b3.x;
    acc[1][1] += a1.x*b0.y + a1.y*b1.y + a1.z*b2.y + a1.w*b3.y;
    acc[1][2] += a1.x*b0.z + a1.y*b1.z + a1.z*b2.z + a1.w*b3.z;
    acc[1][3] += a1.x*b0.w + a1.y*b1.w + a1.z*b2.w + a1.w*b3.w;
    acc[2][0] += a2.x*b0.x + a2.y*b1.x + a2.z*b2.x + a2.w*b3.x;
    acc[2][1] += a2.x*b0.y + a2.y*b1.y + a2.z*b2.y + a2.w*b3.y;
    acc[2][2] += a2.x*b0.z + a2.y*b1.z + a2.z*b2.z + a2.w*b3.z;
    acc[2][3] += a2.x*b0.w + a2.y*b1.w + a2.z*b2.w + a2.w*b3.w;
    acc[3][0] += a3.x*b0.x + a3.y*b1.x + a3.z*b2.x + a3.w*b3.x;
    acc[3][1] += a3.x*b0.y + a3.y*b1.y + a3.z*b2.y + a3.w*b3.y;
    acc[3][2] += a3.x*b0.z + a3.y*b1.z + a3.z*b2.z + a3.w*b3.z;
    acc[3][3] += a3.x*b0.w + a3.y*b1.w + a3.z*b2.w + a3.w*b3.w;
  }
  float p[4][4];
  #pragma unroll
  for (int r = 0; r < 4; ++r){
    #pragma unroll
    for (int c = 0; c < 4; ++c)
      acc[r][c] = fmaxf(acc[r][c] + b1s[4*tx+c], 0.f);
    #pragma unroll
    for (int oc = 0; oc < 4; ++oc){
      p[r][oc] = acc[r][0]*W2s[(4*tx+0)*4+oc] + acc[r][1]*W2s[(4*tx+1)*4+oc]
               + acc[r][2]*W2s[(4*tx+2)*4+oc] + acc[r][3]*W2s[(4*tx+3)*4+oc];
    }
  }
  #pragma unroll
  for (int o = 8; o >= 1; o >>= 1){
    #pragma unroll
    for (int r = 0; r < 4; ++r){
      p[r][0] += __shfl_xor(p[r][0], o);
      p[r][1] += __shfl_xor(p[r][1], o);
      p[r][2] += __shfl_xor(p[r][2], o);
      p[r][3] += __shfl_xor(p[r][3], o);
    }
  }
  if (tx == 0){
    float4 bb = *(const float4*)bcl2;
    #pragma unroll
    for (int r = 0; r < 4; ++r){
      long gi = i0 + 4*ty + r;
      if (gi < N_NODES){
        float4 o;
        o.x = p[r][0] + bb.x; o.y = p[r][1] + bb.y;
        o.z = p[r][2] + bb.z; o.w = p[r][3] + bb.w;
        *(float4*)&out[gi*4] = o;
      }
    }
  }
}

extern "C" void kernel_launch(void* const* d_in, const int* in_sizes, int n_in,
                              void* d_out, int out_size, void* d_ws, size_t ws_size,
                              hipStream_t stream){
  const float* x    = (const float*)d_in[0];
  const float* cl   = (const float*)d_in[1];
  const int*   ei   = (const int*)d_in[2];
  const int*   batch= (const int*)d_in[3];
  const float* W1   = (const float*)d_in[4];
  const float* a1s  = (const float*)d_in[5];
  const float* a1d  = (const float*)d_in[6];
  const float* b1   = (const float*)d_in[7];
  const float* g1   = (const float*)d_in[8];
  const float* be1  = (const float*)d_in[9];
  const float* W2   = (const float*)d_in[10];
  const float* a2s  = (const float*)d_in[11];
  const float* a2d  = (const float*)d_in[12];
  const float* b2   = (const float*)d_in[13];
  const float* g2   = (const float*)d_in[14];
  const float* be2  = (const float*)d_in[15];
  const float* Wc   = (const float*)d_in[16];
  const float* bc   = (const float*)d_in[17];
  const float* Wcl1 = (const float*)d_in[18];
  const float* bcl1 = (const float*)d_in[19];
  const float* Wcl2 = (const float*)d_in[20];
  const float* bcl2 = (const float*)d_in[21];
  const int* srcE = ei;
  const int* dstE = ei + N_EDGES;
  float* out = (float*)d_out;

  char* w = (char*)d_ws;
  auto take = [&](size_t bytes)->char*{ char* p = w; w += (bytes + 255) & ~(size_t)255; return p; };
  ushort_t* h1b = (ushort_t*)take((size_t)N_NODES*C1*2);   // 25.6 MB, dead after k_agg1
  ushort_t* y1b = (ushort_t*)take((size_t)N_NODES*C1*2);   // 25.6 MB bf16
  float* es1 = (float*)take((size_t)N_NODES*NH*4);
  float* ed1 = (float*)take((size_t)N_NODES*NH*4);
  float* es2 = (float*)take((size_t)N_NODES*4);
  float* ed2 = (float*)take((size_t)N_NODES*4);
  float* st  = (float*)take((2*C1 + 2*HID)*4);   // st1 | st2 contiguous -> one memset
  int* cnt  = (int*)take((size_t)CNT_PAD*4);
  int* off  = (int*)take((size_t)(CNT_PAD+16)*4);
  int* csr  = (int*)take((size_t)N_EDGES*4);
  int* rank = (int*)take((size_t)N_EDGES*4);
  float* st1 = st;
  float* st2 = st + 2*C1;
  // alias into dead h1b region after k_agg1: h2b (6.4 MB) at 0, y2 (12.8 MB) at +8 MB
  ushort_t* h2b = h1b;
  float* y2 = (float*)((char*)h1b + ((size_t)8 << 20));

  hipMemsetAsync(cnt, 0, (size_t)CNT_PAD*4, stream);
  hipMemsetAsync(st, 0, (2*C1 + 2*HID)*4, stream);

  k_pre<<<NB_N1 + NB_HIST, 256, 0, stream>>>(x, W1, a1s, a1d, h1b, es1, ed1, dstE, cnt, rank);
  k_scan<<<1, 1024, 0, stream>>>(cnt, off);
  k_scatter<<<(N_EDGES+255)/256, 256, 0, stream>>>(srcE, dstE, rank, off, csr);

  k_agg1<<<(N_NODES+3)/4, 256, 0, stream>>>(h1b, es1, ed1, off, csr, b1, y1b);
  k_colstats1<<<(N_NODES+127)/128, 256, 0, stream>>>(y1b, st1);
  k_gemm2<<<(N_NODES+63)/64, 256, 0, stream>>>(y1b, W2, st1, g1, be1, a2s, a2d, h2b, es2, ed2);
  k_agg2<<<(N_NODES+3)/4, 256, 0, stream>>>(h2b, es2, ed2, off, csr, b2, y2);
  k_colstats<HID,128><<<(N_NODES+127)/128, 256, 0, stream>>>(y2, st2);
  k_final<<<(N_NODES+63)/64, 256, 0, stream>>>(y2, st2, g2, be2, batch, cl, Wc, bc, Wcl1, bcl1, Wcl2, bcl2, out);
}

// Round 10
// 385.870 us; speedup vs baseline: 1.5048x; 1.0114x over previous
//
#include <hip/hip_runtime.h>

#define N_NODES   50000
#define N_EDGES   800000
#define G_GRAPHS  512
#define D_IN      10
#define D_CL      6
#define HID       64
#define NH        4
#define C1        256   // NH*HID
#define D_OUT     4
#define BN_EPS    1e-5f
#define CNT_PAD   53248  // 52*1024, padded count buffer for vectorized scan
#define NB_N1     3125   // node1 sub-grid blocks in fused k_pre (3125*16 = 50000 exactly)
#define NB_HIST   3125   // hist sub-grid blocks (3125*256 = 800000 exactly)

typedef unsigned short ushort_t;
typedef unsigned int uint_t;

__device__ __forceinline__ float leaky(float x){ return x > 0.f ? x : 0.2f*x; }
__device__ __forceinline__ ushort_t f2bf(float f){
  unsigned u = __float_as_uint(f);
  return (ushort_t)((u + 0x7fffu + ((u >> 16) & 1u)) >> 16);
}
__device__ __forceinline__ float bflo(uint_t u){ return __uint_as_float(u << 16); }
__device__ __forceinline__ float bfhi(uint_t u){ return __uint_as_float(u & 0xffff0000u); }
__device__ __forceinline__ uint_t pack2(float a, float b){
  return (uint_t)f2bf(a) | ((uint_t)f2bf(b) << 16);
}

// ---------------- K_pre: grid-fused {h1 = x@W1 + analytic logits} || {degree hist + edge rank} ----------------
// es1[i][h] = x[i] . ahat_s[:,h] with ahat_s[k][h] = sum_d W1[k][h*64+d]*a1s[h][d]
// -> no per-node shuffle reduction chains (R9's latency bottleneck).
__global__ __launch_bounds__(256) void k_pre(const float* __restrict__ x,
    const float* __restrict__ W1, const float* __restrict__ a1s, const float* __restrict__ a1d,
    ushort_t* __restrict__ h1b, float* __restrict__ es1, float* __restrict__ ed1,
    const int* __restrict__ dstE, int* __restrict__ cnt, int* __restrict__ rank){
  if (blockIdx.x >= NB_N1){
    // hist half: count in-degree AND capture each edge's rank within its dst bucket
    int e = (blockIdx.x - NB_N1)*256 + threadIdx.x;
    if (e < N_EDGES){
      int r = atomicAdd(&cnt[dstE[e]], 1);
      rank[e] = r;
    }
    return;
  }
  __shared__ float W1s[D_IN*C1];
  __shared__ float as_s[C1], ad_s[C1];
  __shared__ float ahat[2][D_IN][NH];
  int t = threadIdx.x;
  for (int idx = t; idx < D_IN*C1; idx += 256) W1s[idx] = W1[idx];
  as_s[t] = a1s[t]; ad_s[t] = a1d[t];
  __syncthreads();
  if (t < 2*D_IN*NH){            // 80 threads compute ahat once per block
    int which = (t >= D_IN*NH) ? 1 : 0;
    int r = which ? t - D_IN*NH : t;
    int k = r >> 2, h = r & 3;
    const float* av = which ? ad_s : as_s;
    float s = 0.f;
    #pragma unroll
    for (int d = 0; d < 64; ++d) s += W1s[k*C1 + h*64 + d]*av[h*64 + d];
    ahat[which][k][h] = s;
  }
  // h1 compute: 8 iterations x 2 nodes; thread handles channel pair c,c+1 of node (pair,half)
  int half = t >> 7;             // which node of the pair
  int c = (t & 127) * 2;         // channel pair
  uint_t* h1u = (uint_t*)h1b;
  #pragma unroll 2
  for (int nn2 = 0; nn2 < 8; ++nn2){
    int i = blockIdx.x*16 + nn2*2 + half;        // always < 50000
    const float* xr = x + (long)i*D_IN;
    float acc0 = 0.f, acc1 = 0.f;
    #pragma unroll
    for (int k = 0; k < D_IN; ++k){
      float xv = xr[k];
      acc0 += xv*W1s[k*C1 + c];
      acc1 += xv*W1s[k*C1 + c + 1];
    }
    h1u[(long)i*128 + (c >> 1)] = pack2(acc0, acc1);
  }
  __syncthreads();               // ahat visible to all
  if (t < 128){                  // es (t<64) / ed (t>=64): 4 threads per node, 10 FMAs, no reduction
    int which = (t >= 64) ? 1 : 0;
    int r = t & 63;
    int nn = r >> 2, h = r & 3;
    int i = blockIdx.x*16 + nn;
    const float* xr = x + (long)i*D_IN;
    float s = 0.f;
    #pragma unroll
    for (int k = 0; k < D_IN; ++k) s += xr[k]*ahat[which][k][h];
    if (which) ed1[i*NH + h] = s; else es1[i*NH + h] = s;
  }
}

// single-block vectorized exclusive scan of cnt -> off
__global__ __launch_bounds__(1024) void k_scan(const int* __restrict__ cnt, int* __restrict__ off){
  __shared__ int sh[1024];
  int t = threadIdx.x;
  int4 v[13];
  const int4* c4 = (const int4*)cnt;
  int base4 = t*13;
  int tsum = 0;
  #pragma unroll
  for (int k = 0; k < 13; ++k){
    v[k] = c4[base4 + k];
    tsum += v[k].x + v[k].y + v[k].z + v[k].w;
  }
  sh[t] = tsum;
  __syncthreads();
  for (int o = 1; o < 1024; o <<= 1){
    int xv = (t >= o) ? sh[t-o] : 0;
    __syncthreads();
    sh[t] += xv;
    __syncthreads();
  }
  int run = sh[t] - tsum;   // exclusive prefix of this thread's chunk
  int4* o4 = (int4*)off;
  #pragma unroll
  for (int k = 0; k < 13; ++k){
    int i = t*52 + k*4;
    int4 w_;
    w_.x = run; run += v[k].x;
    w_.y = run; run += v[k].y;
    w_.z = run; run += v[k].z;
    w_.w = run; run += v[k].w;
    if (i + 3 < N_NODES) o4[base4 + k] = w_;
    else {
      if (i+0 < N_NODES) off[i+0] = w_.x;
      if (i+1 < N_NODES) off[i+1] = w_.y;
      if (i+2 < N_NODES) off[i+2] = w_.z;
      if (i+3 < N_NODES) off[i+3] = w_.w;
    }
  }
  if (t == 0) off[N_NODES] = N_EDGES;
}

// atomic-free scatter: rank precomputed in k_pre
__global__ void k_scatter(const int* __restrict__ src, const int* __restrict__ dst,
                          const int* __restrict__ rank, const int* __restrict__ off,
                          int* __restrict__ csr){
  int e = blockIdx.x*blockDim.x + threadIdx.x;
  if (e < N_EDGES) csr[off[dst[e]] + rank[e]] = src[e];
}

// ---------------- K3: layer-1 GAT aggregation (unchanged) ----------------
__global__ __launch_bounds__(256) void k_agg1(const ushort_t* __restrict__ h1b,
    const float* __restrict__ es1, const float* __restrict__ ed1,
    const int* __restrict__ off, const int* __restrict__ csr,
    const float* __restrict__ b1, ushort_t* __restrict__ y1b){
  int lane = threadIdx.x & 63, wid = threadIdx.x >> 6;
  int i = blockIdx.x*4 + wid;
  if (i >= N_NODES) return;
  int lh = lane & 31, hf = lane >> 5;
  int headO = lh >> 3;
  int h    = lane & 3;
  int e    = lane >> 2;
  float4 edv4 = *(const float4*)&ed1[i*NH];
  float4 esv4 = *(const float4*)&es1[i*NH];
  float edh = (headO==0)?edv4.x:(headO==1)?edv4.y:(headO==2)?edv4.z:edv4.w;
  float esS = (headO==0)?esv4.x:(headO==1)?esv4.y:(headO==2)?esv4.z:esv4.w;
  float edw = (h==0)?edv4.x:(h==1)?edv4.y:(h==2)?edv4.z:edv4.w;
  int start = off[i], end = off[i+1];
  const uint4* h1v4 = (const uint4*)h1b;
  float wS = (hf == 0) ? __expf(leaky(esS + edh)) : 0.f;
  float ssum = wS;
  uint4 hv = h1v4[(long)i*32 + lh];
  float a0 = bflo(hv.x)*wS, a1 = bfhi(hv.x)*wS, a2 = bflo(hv.y)*wS, a3 = bfhi(hv.y)*wS;
  float a4 = bflo(hv.z)*wS, a5 = bfhi(hv.z)*wS, a6 = bflo(hv.w)*wS, a7 = bfhi(hv.w)*wS;
  for (int j0 = start; j0 < end; j0 += 16){
    int nj = end - j0; if (nj > 16) nj = 16;
    int ce = (e < nj) ? e : nj - 1;
    int sE = csr[j0 + ce];
    float wv = (e < nj) ? __expf(leaky(es1[sE*NH + h] + edw)) : 0.f;
    int jj = 0;
    for (; jj + 8 <= nj; jj += 8){
      int c0 = (jj+0+hf)<<2, c1 = (jj+2+hf)<<2, c2 = (jj+4+hf)<<2, c3 = (jj+6+hf)<<2;
      int s0 = __shfl(sE, c0);
      int s1 = __shfl(sE, c1);
      int s2 = __shfl(sE, c2);
      int s3 = __shfl(sE, c3);
      uint4 r0 = h1v4[(long)s0*32 + lh];
      uint4 r1 = h1v4[(long)s1*32 + lh];
      uint4 r2 = h1v4[(long)s2*32 + lh];
      uint4 r3 = h1v4[(long)s3*32 + lh];
      float w0 = __shfl(wv, c0 | headO);
      float w1 = __shfl(wv, c1 | headO);
      float w2 = __shfl(wv, c2 | headO);
      float w3 = __shfl(wv, c3 | headO);
      a0 += bflo(r0.x)*w0; a1 += bfhi(r0.x)*w0; a2 += bflo(r0.y)*w0; a3 += bfhi(r0.y)*w0;
      a4 += bflo(r0.z)*w0; a5 += bfhi(r0.z)*w0; a6 += bflo(r0.w)*w0; a7 += bfhi(r0.w)*w0;
      a0 += bflo(r1.x)*w1; a1 += bfhi(r1.x)*w1; a2 += bflo(r1.y)*w1; a3 += bfhi(r1.y)*w1;
      a4 += bflo(r1.z)*w1; a5 += bfhi(r1.z)*w1; a6 += bflo(r1.w)*w1; a7 += bfhi(r1.w)*w1;
      a0 += bflo(r2.x)*w2; a1 += bfhi(r2.x)*w2; a2 += bflo(r2.y)*w2; a3 += bfhi(r2.y)*w2;
      a4 += bflo(r2.z)*w2; a5 += bfhi(r2.z)*w2; a6 += bflo(r2.w)*w2; a7 += bfhi(r2.w)*w2;
      a0 += bflo(r3.x)*w3; a1 += bfhi(r3.x)*w3; a2 += bflo(r3.y)*w3; a3 += bfhi(r3.y)*w3;
      a4 += bflo(r3.z)*w3; a5 += bfhi(r3.z)*w3; a6 += bflo(r3.w)*w3; a7 += bfhi(r3.w)*w3;
      ssum += w0 + w1 + w2 + w3;
    }
    for (; jj < nj; jj += 2){
      int slot = jj + hf;
      int slc = (slot < nj) ? slot : nj - 1;
      int cc = slc << 2;
      int s = __shfl(sE, cc);
      float w = __shfl(wv, cc | headO);
      if (slot >= nj) w = 0.f;
      uint4 r = h1v4[(long)s*32 + lh];
      a0 += bflo(r.x)*w; a1 += bfhi(r.x)*w; a2 += bflo(r.y)*w; a3 += bfhi(r.y)*w;
      a4 += bflo(r.z)*w; a5 += bfhi(r.z)*w; a6 += bflo(r.w)*w; a7 += bfhi(r.w)*w;
      ssum += w;
    }
  }
  a0 += __shfl_xor(a0,32); a1 += __shfl_xor(a1,32); a2 += __shfl_xor(a2,32); a3 += __shfl_xor(a3,32);
  a4 += __shfl_xor(a4,32); a5 += __shfl_xor(a5,32); a6 += __shfl_xor(a6,32); a7 += __shfl_xor(a7,32);
  ssum += __shfl_xor(ssum,32);
  if (hf == 0){
    float inv = 1.f/(ssum + 1e-16f);
    float4 bb0 = *(const float4*)&b1[8*lh];
    float4 bb1 = *(const float4*)&b1[8*lh+4];
    uint4 o;
    o.x = pack2(a0*inv + bb0.x, a1*inv + bb0.y);
    o.y = pack2(a2*inv + bb0.z, a3*inv + bb0.w);
    o.z = pack2(a4*inv + bb1.x, a5*inv + bb1.y);
    o.w = pack2(a6*inv + bb1.z, a7*inv + bb1.w);
    ((uint4*)y1b)[(long)i*32 + lh] = o;
  }
}

// ---------------- BN column stats (bf16 input, C1 channels) ----------------
__global__ __launch_bounds__(256) void k_colstats1(const ushort_t* __restrict__ y, float* __restrict__ st){
  const uint_t* yu = (const uint_t*)y;
  int c2 = threadIdx.x & 127, half = threadIdx.x >> 7;
  long r0 = (long)blockIdx.x * 128;
  float s0=0,q0=0,s1=0,q1=0;
  for (int r = half; r < 128; r += 2){
    long rr = r0 + r;
    if (rr < N_NODES){
      uint_t u = yu[rr*128 + c2];
      float a = bflo(u), b = bfhi(u);
      s0 += a; q0 += a*a; s1 += b; q1 += b*b;
    }
  }
  int c = c2*2;
  atomicAdd(&st[c], s0);      atomicAdd(&st[C1 + c], q0);
  atomicAdd(&st[c+1], s1);    atomicAdd(&st[C1 + c+1], q1);
}

// ---------------- BN column stats (f32 input) ----------------
template<int C, int RPB>
__global__ __launch_bounds__(256) void k_colstats(const float* __restrict__ y, float* __restrict__ st){
  int c = threadIdx.x % C;
  int rl = threadIdx.x / C;
  const int rpb = 256 / C;
  long r0 = (long)blockIdx.x * RPB;
  float s = 0.f, q = 0.f;
  for (int r = rl; r < RPB; r += rpb){
    long rr = r0 + r;
    if (rr < N_NODES){ float v = y[rr*C + c]; s += v; q += v*v; }
  }
  atomicAdd(&st[c], s); atomicAdd(&st[C + c], q);
}

// ---------------- K6: h2 = relu(bn(y1)) @ W2 (bf16 out) + fused es2/ed2; BN prep inlined ----------------
__global__ __launch_bounds__(256) void k_gemm2(const ushort_t* __restrict__ y1b, const float* __restrict__ W2,
    const float* __restrict__ st1, const float* __restrict__ g1, const float* __restrict__ be1,
    const float* __restrict__ a2s, const float* __restrict__ a2d,
    ushort_t* __restrict__ h2b, float* __restrict__ es2, float* __restrict__ ed2){
  __shared__ float As[64][68];
  __shared__ float Bs[64][64];
  __shared__ float as_s[HID], ad_s[HID];
  __shared__ float ss_s[2*C1];
  int t = threadIdx.x;
  if (t < HID){ as_s[t] = a2s[t]; ad_s[t] = a2d[t]; }
  {
    float mean = st1[t] / (float)N_NODES;
    float var  = st1[C1 + t] / (float)N_NODES - mean*mean;
    float sc = g1[t] * rsqrtf(var + BN_EPS);
    ss_s[t] = sc;
    ss_s[C1 + t] = be1[t] - mean*sc;
  }
  int tx = t & 15, ty = t >> 4;
  long i0 = (long)blockIdx.x * 64;
  float acc[4][4] = {};
  __syncthreads();
  for (int kc = 0; kc < C1; kc += 64){
    const uint_t* yu = (const uint_t*)y1b;
    for (int idx = t; idx < 64*32; idx += 256){
      int r = idx >> 5, k2 = idx & 31;
      long gi = i0 + r;
      int k = kc + k2*2;
      float v0 = 0.f, v1 = 0.f;
      if (gi < N_NODES){
        uint_t u = yu[gi*128 + (k >> 1)];
        v0 = fmaxf(bflo(u)*ss_s[k]   + ss_s[C1+k],   0.f);
        v1 = fmaxf(bfhi(u)*ss_s[k+1] + ss_s[C1+k+1], 0.f);
      }
      As[r][k2*2]   = v0;
      As[r][k2*2+1] = v1;
    }
    for (int idx = t; idx < 64*64; idx += 256){
      Bs[idx >> 6][idx & 63] = W2[(kc + (idx >> 6))*HID + (idx & 63)];
    }
    __syncthreads();
    #pragma unroll 4
    for (int kk = 0; kk < 64; kk += 4){
      float4 va0 = *(float4*)&As[4*ty+0][kk];
      float4 va1 = *(float4*)&As[4*ty+1][kk];
      float4 va2 = *(float4*)&As[4*ty+2][kk];
      float4 va3 = *(float4*)&As[4*ty+3][kk];
      float4 vb0 = *(float4*)&Bs[kk+0][4*tx];
      float4 vb1 = *(float4*)&Bs[kk+1][4*tx];
      float4 vb2 = *(float4*)&Bs[kk+2][4*tx];
      float4 vb3 = *(float4*)&Bs[kk+3][4*tx];
      acc[0][0] += va0.x*vb0.x + va0.y*vb1.x + va0.z*vb2.x + va0.w*vb3.x;
      acc[0][1] += va0.x*vb0.y + va0.y*vb1.y + va0.z*vb2.y + va0.w*vb3.y;
      acc[0][2] += va0.x*vb0.z + va0.y*vb1.z + va0.z*vb2.z + va0.w*vb3.z;
      acc[0][3] += va0.x*vb0.w + va0.y*vb1.w + va0.z*vb2.w + va0.w*vb3.w;
      acc[1][0] += va1.x*vb0.x + va1.y*vb1.x + va1.z*vb2.x + va1.w*vb3.x;
      acc[1][1] += va1.x*vb0.y + va1.y*vb1.y + va1.z*vb2.y + va1.w*vb3.y;
      acc[1][2] += va1.x*vb0.z + va1.y*vb1.z + va1.z*vb2.z + va1.w*vb3.z;
      acc[1][3] += va1.x*vb0.w + va1.y*vb1.w + va1.z*vb2.w + va1.w*vb3.w;
      acc[2][0] += va2.x*vb0.x + va2.y*vb1.x + va2.z*vb2.x + va2.w*vb3.x;
      acc[2][1] += va2.x*vb0.y + va2.y*vb1.y + va2.z*vb2.y + va2.w*vb3.y;
      acc[2][2] += va2.x*vb0.z + va2.y*vb1.z + va2.z*vb2.z + va2.w*vb3.z;
      acc[2][3] += va2.x*vb0.w + va2.y*vb1.w + va2.z*vb2.w + va2.w*vb3.w;
      acc[3][0] += va3.x*vb0.x + va3.y*vb1.x + va3.z*vb2.x + va3.w*vb3.x;
      acc[3][1] += va3.x*vb0.y + va3.y*vb1.y + va3.z*vb2.y + va3.w*vb3.y;
      acc[3][2] += va3.x*vb0.z + va3.y*vb1.z + va3.z*vb2.z + va3.w*vb3.z;
      acc[3][3] += va3.x*vb0.w + va3.y*vb1.w + va3.z*vb2.w + va3.w*vb3.w;
    }
    __syncthreads();
  }
  #pragma unroll
  for (int rr = 0; rr < 4; ++rr){
    long gi = i0 + 4*ty + rr;
    if (gi < N_NODES){
      uint_t p0 = pack2(acc[rr][0], acc[rr][1]);
      uint_t p1 = pack2(acc[rr][2], acc[rr][3]);
      *(uint2*)&h2b[gi*HID + 4*tx] = make_uint2(p0, p1);
      float ps = acc[rr][0]*as_s[4*tx+0] + acc[rr][1]*as_s[4*tx+1]
               + acc[rr][2]*as_s[4*tx+2] + acc[rr][3]*as_s[4*tx+3];
      float pd = acc[rr][0]*ad_s[4*tx+0] + acc[rr][1]*ad_s[4*tx+1]
               + acc[rr][2]*ad_s[4*tx+2] + acc[rr][3]*ad_s[4*tx+3];
      #pragma unroll
      for (int o = 8; o >= 1; o >>= 1){ ps += __shfl_xor(ps,o); pd += __shfl_xor(pd,o); }
      if (tx == 0){ es2[gi] = ps; ed2[gi] = pd; }
    }
  }
}

// ---------------- K7: layer-2 GAT aggregation (unchanged) ----------------
__global__ __launch_bounds__(256) void k_agg2(const ushort_t* __restrict__ h2b,
    const float* __restrict__ es2, const float* __restrict__ ed2,
    const int* __restrict__ off, const int* __restrict__ csr,
    const float* __restrict__ b2, float* __restrict__ y2){
  int lane = threadIdx.x & 63, wid = threadIdx.x >> 6;
  int i = blockIdx.x*4 + wid;
  if (i >= N_NODES) return;
  int lq = lane & 15, q = lane >> 4;
  float edv = ed2[i];
  int start = off[i], end = off[i+1];
  const uint2* h2u2 = (const uint2*)h2b;
  float a0, a1, a2, a3, ssum;
  {
    float wS = (q == 0) ? __expf(leaky(es2[i] + edv)) : 0.f;
    uint2 uS = h2u2[(long)i*16 + lq];
    a0 = bflo(uS.x)*wS; a1 = bfhi(uS.x)*wS; a2 = bflo(uS.y)*wS; a3 = bfhi(uS.y)*wS;
    ssum = wS;
  }
  for (int j0 = start; j0 < end; j0 += 64){
    int nj = end - j0; if (nj > 64) nj = 64;
    int ce = (lane < nj) ? lane : nj - 1;
    int sE = csr[j0 + ce];
    float wv = (lane < nj) ? __expf(leaky(es2[sE] + edv)) : 0.f;
    int jj = 0;
    for (; jj + 16 <= nj; jj += 16){
      int c0 = jj + q, c1 = jj + 4 + q, c2 = jj + 8 + q, c3 = jj + 12 + q;
      int s0 = __shfl(sE, c0);
      int s1 = __shfl(sE, c1);
      int s2 = __shfl(sE, c2);
      int s3 = __shfl(sE, c3);
      uint2 r0 = h2u2[(long)s0*16 + lq];
      uint2 r1 = h2u2[(long)s1*16 + lq];
      uint2 r2 = h2u2[(long)s2*16 + lq];
      uint2 r3 = h2u2[(long)s3*16 + lq];
      float w0 = __shfl(wv, c0);
      float w1 = __shfl(wv, c1);
      float w2 = __shfl(wv, c2);
      float w3 = __shfl(wv, c3);
      a0 += bflo(r0.x)*w0; a1 += bfhi(r0.x)*w0; a2 += bflo(r0.y)*w0; a3 += bfhi(r0.y)*w0;
      a0 += bflo(r1.x)*w1; a1 += bfhi(r1.x)*w1; a2 += bflo(r1.y)*w1; a3 += bfhi(r1.y)*w1;
      a0 += bflo(r2.x)*w2; a1 += bfhi(r2.x)*w2; a2 += bflo(r2.y)*w2; a3 += bfhi(r2.y)*w2;
      a0 += bflo(r3.x)*w3; a1 += bfhi(r3.x)*w3; a2 += bflo(r3.y)*w3; a3 += bfhi(r3.y)*w3;
      ssum += w0 + w1 + w2 + w3;
    }
    for (; jj < nj; jj += 4){
      int slot = jj + q;
      int slc = (slot < nj) ? slot : nj - 1;
      int s = __shfl(sE, slc);
      float w = __shfl(wv, slc);
      if (slot >= nj) w = 0.f;
      uint2 r = h2u2[(long)s*16 + lq];
      a0 += bflo(r.x)*w; a1 += bfhi(r.x)*w; a2 += bflo(r.y)*w; a3 += bfhi(r.y)*w;
      ssum += w;
    }
  }
  a0 += __shfl_xor(a0,16); a1 += __shfl_xor(a1,16); a2 += __shfl_xor(a2,16); a3 += __shfl_xor(a3,16);
  ssum += __shfl_xor(ssum,16);
  a0 += __shfl_xor(a0,32); a1 += __shfl_xor(a1,32); a2 += __shfl_xor(a2,32); a3 += __shfl_xor(a3,32);
  ssum += __shfl_xor(ssum,32);
  if (q == 0){
    float inv = 1.f/(ssum + 1e-16f);
    float4 bb = *(const float4*)&b2[4*lq];
    float4 o;
    o.x = a0*inv + bb.x; o.y = a1*inv + bb.y;
    o.z = a2*inv + bb.z; o.w = a3*inv + bb.w;
    ((float4*)y2)[(long)i*16 + lq] = o;
  }
}

// ---------------- final: tiled GEMM, BN2 prep + climber MLP inlined ----------------
__global__ __launch_bounds__(256) void k_final(const float* __restrict__ y2,
    const float* __restrict__ st2, const float* __restrict__ g2, const float* __restrict__ be2,
    const int* __restrict__ batch,
    const float* __restrict__ cl, const float* __restrict__ Wc, const float* __restrict__ bc,
    const float* __restrict__ Wcl1, const float* __restrict__ bcl1,
    const float* __restrict__ Wcl2, const float* __restrict__ bcl2,
    float* __restrict__ out){
  __shared__ float As[64][132];
  __shared__ float Bs[128][64];
  __shared__ float ss2s[2*HID];
  __shared__ float b1s[HID];
  __shared__ float W2s[HID*D_OUT];
  __shared__ float Wcs[D_CL*HID];
  __shared__ float bcs[HID];
  int t = threadIdx.x;
  long i0 = (long)blockIdx.x * 64;
  if (t < HID){
    float mean = st2[t] / (float)N_NODES;
    float var  = st2[HID + t] / (float)N_NODES - mean*mean;
    float sc = g2[t] * rsqrtf(var + BN_EPS);
    ss2s[t] = sc;
    ss2s[HID + t] = be2[t] - mean*sc;
  }
  if (t >= 64 && t < 128) bcs[t-64] = bc[t-64];
  if (t >= 128 && t < 192) b1s[t-128] = bcl1[t-128];
  W2s[t] = Wcl2[t];
  for (int idx = t; idx < D_CL*HID; idx += 256) Wcs[idx] = Wc[idx];
  __syncthreads();
  const float2* y2v = (const float2*)y2;
  #pragma unroll
  for (int ii = 0; ii < 8; ++ii){
    int idx = t + 256*ii;
    int r = idx >> 5, k2 = idx & 31;
    long gi = i0 + r;
    float2 v = make_float2(0.f, 0.f);
    if (gi < N_NODES) v = y2v[gi*32 + k2];
    int k = k2*2;
    As[r][k]   = fmaxf(v.x*ss2s[k]   + ss2s[HID+k],   0.f);
    As[r][k+1] = fmaxf(v.y*ss2s[k+1] + ss2s[HID+k+1], 0.f);
  }
  #pragma unroll
  for (int ii = 0; ii < 8; ++ii){
    int idx = t + 256*ii;
    int r = idx >> 5, k2 = idx & 31;
    long gi = i0 + r;
    int k = k2*2;
    float c0 = 0.f, c1 = 0.f;
    if (gi < N_NODES){
      int g = batch[gi];
      const float* cg = cl + (long)g*D_CL;
      c0 = bcs[k]; c1 = bcs[k+1];
      #pragma unroll
      for (int kk = 0; kk < D_CL; ++kk){
        float clv = cg[kk];
        c0 += clv*Wcs[kk*HID + k];
        c1 += clv*Wcs[kk*HID + k+1];
      }
      c0 = fmaxf(c0, 0.f); c1 = fmaxf(c1, 0.f);
    }
    As[r][HID + k]   = c0;
    As[r][HID + k+1] = c1;
  }
  #pragma unroll
  for (int ii = 0; ii < 8; ++ii){
    int idx = t + 256*ii;
    int kk = idx >> 4, c4 = idx & 15;
    *(float4*)&Bs[kk][c4*4] = *(const float4*)&Wcl1[kk*64 + c4*4];
  }
  __syncthreads();
  int tx = t & 15, ty = t >> 4;
  float acc[4][4] = {};
  #pragma unroll 4
  for (int kk = 0; kk < 2*HID; kk += 4){
    float4 a0 = *(float4*)&As[4*ty+0][kk];
    float4 a1 = *(float4*)&As[4*ty+1][kk];
    float4 a2 = *(float4*)&As[4*ty+2][kk];
    float4 a3 = *(float4*)&As[4*ty+3][kk];
    float4 b0 = *(float4*)&Bs[kk+0][4*tx];
    float4 b1 = *(float4*)&Bs[kk+1][4*tx];
    float4 b2 = *(float4*)&Bs[kk+2][4*tx];
    float4 b3 = *(float4*)&Bs[kk+3][4*tx];
    acc[0][0] += a0.x*b0.x + a0.y*b1.x + a0.z*b2.x + a0.w*b3.x;
    acc[0][1] += a0.x*b0.y + a0.y*b1.y + a0.z*b2.y + a0.w*b3.y;
    acc[0][2] += a0.x*b0.z + a0.y*b1.z + a0.z*b2.z + a0.w*b3.z;
    acc[0][3] += a0.x*b0.w + a0.y*b1.w + a0.z*b2.w + a0.w*b3.w;
    acc[1][0] += a1.x*b0.x + a1.y*b1.x + a1.z*b2.x + a1.w*b3.x;
    acc[1][1] += a1.x*b0.y + a1.y*b1.y + a1.z*b2.y + a1.w*b3.y;
    acc[1][2] += a1.x*b0.z + a1.y*b1.z + a1.z*b2.z + a1.w*b3.z;
    acc[1][3] += a1.x*b0.w + a1.y*b1.w + a1.z*b2.w + a1.w*b3.w;
    acc[2][0] += a2.x*b0.x + a2.y*b1.x + a2.z*b2.x + a2.w*b3.x;
    acc[2][1] += a2.x*b0.y + a2.y*b1.y + a2.z*b2.y + a2.w*b3.y;
    acc[2][2] += a2.x*b0.z + a2.y*b1.z + a2.z*b2.z + a2.w*b3.z;
    acc[2][3] += a2.x*b0.w + a2.y*b1.w + a2.z*b2.w + a2.w*b3.w;
    acc[3][0] += a3.x*b0.x + a3.y*b1.x + a3.z*b2.x + a3.w*b3.x;
    acc[3][1] += a3.x*b0.y + a3.y*b1.y + a3.z*b2.y + a3.w*b3.y;
    acc[3][2] += a3.x*b0.z + a3.y*b1.z + a3.z*b2.z + a3.w*b3.z;
    acc[3][3] += a3.x*b0.w + a3.y*b1.w + a3.z*b2.w + a3.w*b3.w;
  }
  float p[4][4];
  #pragma unroll
  for (int r = 0; r < 4; ++r){
    #pragma unroll
    for (int c = 0; c < 4; ++c)
      acc[r][c] = fmaxf(acc[r][c] + b1s[4*tx+c], 0.f);
    #pragma unroll
    for (int oc = 0; oc < 4; ++oc){
      p[r][oc] = acc[r][0]*W2s[(4*tx+0)*4+oc] + acc[r][1]*W2s[(4*tx+1)*4+oc]
               + acc[r][2]*W2s[(4*tx+2)*4+oc] + acc[r][3]*W2s[(4*tx+3)*4+oc];
    }
  }
  #pragma unroll
  for (int o = 8; o >= 1; o >>= 1){
    #pragma unroll
    for (int r = 0; r < 4; ++r){
      p[r][0] += __shfl_xor(p[r][0], o);
      p[r][1] += __shfl_xor(p[r][1], o);
      p[r][2] += __shfl_xor(p[r][2], o);
      p[r][3] += __shfl_xor(p[r][3], o);
    }
  }
  if (tx == 0){
    float4 bb = *(const float4*)bcl2;
    #pragma unroll
    for (int r = 0; r < 4; ++r){
      long gi = i0 + 4*ty + r;
      if (gi < N_NODES){
        float4 o;
        o.x = p[r][0] + bb.x; o.y = p[r][1] + bb.y;
        o.z = p[r][2] + bb.z; o.w = p[r][3] + bb.w;
        *(float4*)&out[gi*4] = o;
      }
    }
  }
}

extern "C" void kernel_launch(void* const* d_in, const int* in_sizes, int n_in,
                              void* d_out, int out_size, void* d_ws, size_t ws_size,
                              hipStream_t stream){
  const float* x    = (const float*)d_in[0];
  const float* cl   = (const float*)d_in[1];
  const int*   ei   = (const int*)d_in[2];
  const int*   batch= (const int*)d_in[3];
  const float* W1   = (const float*)d_in[4];
  const float* a1s  = (const float*)d_in[5];
  const float* a1d  = (const float*)d_in[6];
  const float* b1   = (const float*)d_in[7];
  const float* g1   = (const float*)d_in[8];
  const float* be1  = (const float*)d_in[9];
  const float* W2   = (const float*)d_in[10];
  const float* a2s  = (const float*)d_in[11];
  const float* a2d  = (const float*)d_in[12];
  const float* b2   = (const float*)d_in[13];
  const float* g2   = (const float*)d_in[14];
  const float* be2  = (const float*)d_in[15];
  const float* Wc   = (const float*)d_in[16];
  const float* bc   = (const float*)d_in[17];
  const float* Wcl1 = (const float*)d_in[18];
  const float* bcl1 = (const float*)d_in[19];
  const float* Wcl2 = (const float*)d_in[20];
  const float* bcl2 = (const float*)d_in[21];
  const int* srcE = ei;
  const int* dstE = ei + N_EDGES;
  float* out = (float*)d_out;

  char* w = (char*)d_ws;
  auto take = [&](size_t bytes)->char*{ char* p = w; w += (bytes + 255) & ~(size_t)255; return p; };
  ushort_t* h1b = (ushort_t*)take((size_t)N_NODES*C1*2);   // 25.6 MB, dead after k_agg1
  ushort_t* y1b = (ushort_t*)take((size_t)N_NODES*C1*2);   // 25.6 MB bf16
  float* es1 = (float*)take((size_t)N_NODES*NH*4);
  float* ed1 = (float*)take((size_t)N_NODES*NH*4);
  float* es2 = (float*)take((size_t)N_NODES*4);
  float* ed2 = (float*)take((size_t)N_NODES*4);
  float* st  = (float*)take((2*C1 + 2*HID)*4);   // st1 | st2 contiguous -> one memset
  int* cnt  = (int*)take((size_t)CNT_PAD*4);
  int* off  = (int*)take((size_t)(CNT_PAD+16)*4);
  int* csr  = (int*)take((size_t)N_EDGES*4);
  int* rank = (int*)take((size_t)N_EDGES*4);
  float* st1 = st;
  float* st2 = st + 2*C1;
  // alias into dead h1b region after k_agg1: h2b (6.4 MB) at 0, y2 (12.8 MB) at +8 MB
  ushort_t* h2b = h1b;
  float* y2 = (float*)((char*)h1b + ((size_t)8 << 20));

  hipMemsetAsync(cnt, 0, (size_t)CNT_PAD*4, stream);
  hipMemsetAsync(st, 0, (2*C1 + 2*HID)*4, stream);

  k_pre<<<NB_N1 + NB_HIST, 256, 0, stream>>>(x, W1, a1s, a1d, h1b, es1, ed1, dstE, cnt, rank);
  k_scan<<<1, 1024, 0, stream>>>(cnt, off);
  k_scatter<<<(N_EDGES+255)/256, 256, 0, stream>>>(srcE, dstE, rank, off, csr);

  k_agg1<<<(N_NODES+3)/4, 256, 0, stream>>>(h1b, es1, ed1, off, csr, b1, y1b);
  k_colstats1<<<(N_NODES+127)/128, 256, 0, stream>>>(y1b, st1);
  k_gemm2<<<(N_NODES+63)/64, 256, 0, stream>>>(y1b, W2, st1, g1, be1, a2s, a2d, h2b, es2, ed2);
  k_agg2<<<(N_NODES+3)/4, 256, 0, stream>>>(h2b, es2, ed2, off, csr, b2, y2);
  k_colstats<HID,128><<<(N_NODES+127)/128, 256, 0, stream>>>(y2, st2);
  k_final<<<(N_NODES+63)/64, 256, 0, stream>>>(y2, st2, g2, be2, batch, cl, Wc, bc, Wcl1, bcl1, Wcl2, bcl2, out);
}

// Round 11
// 358.467 us; speedup vs baseline: 1.6199x; 1.0764x over previous
//
#include <hip/hip_runtime.h>

#define N_NODES   50000
#define N_EDGES   800000
#define G_GRAPHS  512
#define D_IN      10
#define D_CL      6
#define HID       64
#define NH        4
#define C1        256   // NH*HID
#define D_OUT     4
#define BN_EPS    1e-5f
#define CNT_PAD   53248  // 52*1024, padded count buffer for vectorized scan
#define NB_N1     782    // node1 sub-grid: 782*64 = 50048 >= 50000
#define NB_HIST   782    // hist sub-grid: 782*1024 = 800768 >= 800000 (4 edges/thread)

typedef unsigned short ushort_t;
typedef unsigned int uint_t;

__device__ __forceinline__ float leaky(float x){ return x > 0.f ? x : 0.2f*x; }
__device__ __forceinline__ ushort_t f2bf(float f){
  unsigned u = __float_as_uint(f);
  return (ushort_t)((u + 0x7fffu + ((u >> 16) & 1u)) >> 16);
}
__device__ __forceinline__ float bflo(uint_t u){ return __uint_as_float(u << 16); }
__device__ __forceinline__ float bfhi(uint_t u){ return __uint_as_float(u & 0xffff0000u); }
__device__ __forceinline__ uint_t pack2(float a, float b){
  return (uint_t)f2bf(a) | ((uint_t)f2bf(b) << 16);
}

// ---------------- K_pre: grid-fused {h1 = x@W1 + analytic logits} || {4-edge/thread hist+rank} ----------------
// node1 half: 64 nodes/block; W1 columns in registers (no LDS reads in hot loop);
// ahat from GLOBAL W1 (kills R10's 32-way LDS bank conflicts).
// hist half: 4 independent atomics in flight per thread (latency hiding).
__global__ __launch_bounds__(256) void k_pre(const float* __restrict__ x,
    const float* __restrict__ W1, const float* __restrict__ a1s, const float* __restrict__ a1d,
    ushort_t* __restrict__ h1b, float* __restrict__ es1, float* __restrict__ ed1,
    const int* __restrict__ dstE, int* __restrict__ cnt, int* __restrict__ rank){
  if (blockIdx.x >= NB_N1){
    int base = (blockIdx.x - NB_N1)*1024 + threadIdx.x;
    #pragma unroll
    for (int u = 0; u < 4; ++u){
      int e = base + u*256;
      if (e < N_EDGES){
        int r = atomicAdd(&cnt[dstE[e]], 1);
        rank[e] = r;
      }
    }
    return;
  }
  __shared__ float As[64][12];          // x tile, pad 10->12
  __shared__ float ahat[2][D_IN][NH];
  int t = threadIdx.x;
  long i0 = (long)blockIdx.x * 64;
  // stage x tile (coalesced scalar; 640 floats)
  for (int idx = t; idx < 64*D_IN; idx += 256){
    int r = idx / D_IN, k = idx - r*D_IN;
    long gi = i0 + r;
    As[r][k] = (gi < N_NODES) ? x[gi*D_IN + k] : 0.f;
  }
  // W1 columns 2cp, 2cp+1 into registers (coalesced float2 global loads)
  int cp = t & 127, half = t >> 7;
  float w1r0[D_IN], w1r1[D_IN];
  #pragma unroll
  for (int k = 0; k < D_IN; ++k){
    float2 v = *(const float2*)&W1[k*C1 + 2*cp];
    w1r0[k] = v.x; w1r1[k] = v.y;
  }
  // ahat[which][k][h] = sum_d W1[k][h*64+d]*a[h][d] from GLOBAL memory (no LDS conflicts)
  if (t < 2*D_IN*NH){                  // 80 threads
    int which = (t >= D_IN*NH) ? 1 : 0;
    int r = which ? t - D_IN*NH : t;
    int k = r >> 2, h = r & 3;
    const float* av = which ? a1d : a1s;
    const float* wrow = &W1[k*C1 + h*64];
    const float* arow = &av[h*64];
    float s = 0.f;
    #pragma unroll
    for (int d = 0; d < 64; d += 4){
      float4 wv = *(const float4*)&wrow[d];
      float4 avv = *(const float4*)&arow[d];
      s += wv.x*avv.x + wv.y*avv.y + wv.z*avv.z + wv.w*avv.w;
    }
    ahat[which][k][h] = s;
  }
  __syncthreads();
  // h1: thread computes channels 2cp,2cp+1 for 32 nodes (r = half, half+2, ...)
  uint_t* h1u = (uint_t*)h1b;
  for (int r = half; r < 64; r += 2){
    long gi = i0 + r;                  // uniform per iteration
    if (gi >= N_NODES) break;
    float acc0 = 0.f, acc1 = 0.f;
    #pragma unroll
    for (int k = 0; k < D_IN; ++k){
      float xv = As[r][k];             // broadcast read (conflict-free)
      acc0 += xv*w1r0[k];
      acc1 += xv*w1r1[k];
    }
    h1u[gi*128 + cp] = pack2(acc0, acc1);
  }
  // es/ed: thread (nn = t>>2, h = t&3) computes both logits; 20 FMAs, no reductions
  {
    int nn = t >> 2, h = t & 3;
    long gi = i0 + nn;
    if (gi < N_NODES){
      float s = 0.f, d_ = 0.f;
      #pragma unroll
      for (int k = 0; k < D_IN; ++k){
        float xv = As[nn][k];
        s  += xv*ahat[0][k][h];
        d_ += xv*ahat[1][k][h];
      }
      es1[gi*NH + h] = s;
      ed1[gi*NH + h] = d_;
    }
  }
}

// single-block vectorized exclusive scan of cnt -> off
__global__ __launch_bounds__(1024) void k_scan(const int* __restrict__ cnt, int* __restrict__ off){
  __shared__ int sh[1024];
  int t = threadIdx.x;
  int4 v[13];
  const int4* c4 = (const int4*)cnt;
  int base4 = t*13;
  int tsum = 0;
  #pragma unroll
  for (int k = 0; k < 13; ++k){
    v[k] = c4[base4 + k];
    tsum += v[k].x + v[k].y + v[k].z + v[k].w;
  }
  sh[t] = tsum;
  __syncthreads();
  for (int o = 1; o < 1024; o <<= 1){
    int xv = (t >= o) ? sh[t-o] : 0;
    __syncthreads();
    sh[t] += xv;
    __syncthreads();
  }
  int run = sh[t] - tsum;   // exclusive prefix of this thread's chunk
  int4* o4 = (int4*)off;
  #pragma unroll
  for (int k = 0; k < 13; ++k){
    int i = t*52 + k*4;
    int4 w_;
    w_.x = run; run += v[k].x;
    w_.y = run; run += v[k].y;
    w_.z = run; run += v[k].z;
    w_.w = run; run += v[k].w;
    if (i + 3 < N_NODES) o4[base4 + k] = w_;
    else {
      if (i+0 < N_NODES) off[i+0] = w_.x;
      if (i+1 < N_NODES) off[i+1] = w_.y;
      if (i+2 < N_NODES) off[i+2] = w_.z;
      if (i+3 < N_NODES) off[i+3] = w_.w;
    }
  }
  if (t == 0) off[N_NODES] = N_EDGES;
}

// atomic-free scatter: rank precomputed in k_pre
__global__ void k_scatter(const int* __restrict__ src, const int* __restrict__ dst,
                          const int* __restrict__ rank, const int* __restrict__ off,
                          int* __restrict__ csr){
  int e = blockIdx.x*blockDim.x + threadIdx.x;
  if (e < N_EDGES) csr[off[dst[e]] + rank[e]] = src[e];
}

// ---------------- K3: layer-1 GAT aggregation (unchanged) ----------------
__global__ __launch_bounds__(256) void k_agg1(const ushort_t* __restrict__ h1b,
    const float* __restrict__ es1, const float* __restrict__ ed1,
    const int* __restrict__ off, const int* __restrict__ csr,
    const float* __restrict__ b1, ushort_t* __restrict__ y1b){
  int lane = threadIdx.x & 63, wid = threadIdx.x >> 6;
  int i = blockIdx.x*4 + wid;
  if (i >= N_NODES) return;
  int lh = lane & 31, hf = lane >> 5;
  int headO = lh >> 3;
  int h    = lane & 3;
  int e    = lane >> 2;
  float4 edv4 = *(const float4*)&ed1[i*NH];
  float4 esv4 = *(const float4*)&es1[i*NH];
  float edh = (headO==0)?edv4.x:(headO==1)?edv4.y:(headO==2)?edv4.z:edv4.w;
  float esS = (headO==0)?esv4.x:(headO==1)?esv4.y:(headO==2)?esv4.z:esv4.w;
  float edw = (h==0)?edv4.x:(h==1)?edv4.y:(h==2)?edv4.z:edv4.w;
  int start = off[i], end = off[i+1];
  const uint4* h1v4 = (const uint4*)h1b;
  float wS = (hf == 0) ? __expf(leaky(esS + edh)) : 0.f;
  float ssum = wS;
  uint4 hv = h1v4[(long)i*32 + lh];
  float a0 = bflo(hv.x)*wS, a1 = bfhi(hv.x)*wS, a2 = bflo(hv.y)*wS, a3 = bfhi(hv.y)*wS;
  float a4 = bflo(hv.z)*wS, a5 = bfhi(hv.z)*wS, a6 = bflo(hv.w)*wS, a7 = bfhi(hv.w)*wS;
  for (int j0 = start; j0 < end; j0 += 16){
    int nj = end - j0; if (nj > 16) nj = 16;
    int ce = (e < nj) ? e : nj - 1;
    int sE = csr[j0 + ce];
    float wv = (e < nj) ? __expf(leaky(es1[sE*NH + h] + edw)) : 0.f;
    int jj = 0;
    for (; jj + 8 <= nj; jj += 8){
      int c0 = (jj+0+hf)<<2, c1 = (jj+2+hf)<<2, c2 = (jj+4+hf)<<2, c3 = (jj+6+hf)<<2;
      int s0 = __shfl(sE, c0);
      int s1 = __shfl(sE, c1);
      int s2 = __shfl(sE, c2);
      int s3 = __shfl(sE, c3);
      uint4 r0 = h1v4[(long)s0*32 + lh];
      uint4 r1 = h1v4[(long)s1*32 + lh];
      uint4 r2 = h1v4[(long)s2*32 + lh];
      uint4 r3 = h1v4[(long)s3*32 + lh];
      float w0 = __shfl(wv, c0 | headO);
      float w1 = __shfl(wv, c1 | headO);
      float w2 = __shfl(wv, c2 | headO);
      float w3 = __shfl(wv, c3 | headO);
      a0 += bflo(r0.x)*w0; a1 += bfhi(r0.x)*w0; a2 += bflo(r0.y)*w0; a3 += bfhi(r0.y)*w0;
      a4 += bflo(r0.z)*w0; a5 += bfhi(r0.z)*w0; a6 += bflo(r0.w)*w0; a7 += bfhi(r0.w)*w0;
      a0 += bflo(r1.x)*w1; a1 += bfhi(r1.x)*w1; a2 += bflo(r1.y)*w1; a3 += bfhi(r1.y)*w1;
      a4 += bflo(r1.z)*w1; a5 += bfhi(r1.z)*w1; a6 += bflo(r1.w)*w1; a7 += bfhi(r1.w)*w1;
      a0 += bflo(r2.x)*w2; a1 += bfhi(r2.x)*w2; a2 += bflo(r2.y)*w2; a3 += bfhi(r2.y)*w2;
      a4 += bflo(r2.z)*w2; a5 += bfhi(r2.z)*w2; a6 += bflo(r2.w)*w2; a7 += bfhi(r2.w)*w2;
      a0 += bflo(r3.x)*w3; a1 += bfhi(r3.x)*w3; a2 += bflo(r3.y)*w3; a3 += bfhi(r3.y)*w3;
      a4 += bflo(r3.z)*w3; a5 += bfhi(r3.z)*w3; a6 += bflo(r3.w)*w3; a7 += bfhi(r3.w)*w3;
      ssum += w0 + w1 + w2 + w3;
    }
    for (; jj < nj; jj += 2){
      int slot = jj + hf;
      int slc = (slot < nj) ? slot : nj - 1;
      int cc = slc << 2;
      int s = __shfl(sE, cc);
      float w = __shfl(wv, cc | headO);
      if (slot >= nj) w = 0.f;
      uint4 r = h1v4[(long)s*32 + lh];
      a0 += bflo(r.x)*w; a1 += bfhi(r.x)*w; a2 += bflo(r.y)*w; a3 += bfhi(r.y)*w;
      a4 += bflo(r.z)*w; a5 += bfhi(r.z)*w; a6 += bflo(r.w)*w; a7 += bfhi(r.w)*w;
      ssum += w;
    }
  }
  a0 += __shfl_xor(a0,32); a1 += __shfl_xor(a1,32); a2 += __shfl_xor(a2,32); a3 += __shfl_xor(a3,32);
  a4 += __shfl_xor(a4,32); a5 += __shfl_xor(a5,32); a6 += __shfl_xor(a6,32); a7 += __shfl_xor(a7,32);
  ssum += __shfl_xor(ssum,32);
  if (hf == 0){
    float inv = 1.f/(ssum + 1e-16f);
    float4 bb0 = *(const float4*)&b1[8*lh];
    float4 bb1 = *(const float4*)&b1[8*lh+4];
    uint4 o;
    o.x = pack2(a0*inv + bb0.x, a1*inv + bb0.y);
    o.y = pack2(a2*inv + bb0.z, a3*inv + bb0.w);
    o.z = pack2(a4*inv + bb1.x, a5*inv + bb1.y);
    o.w = pack2(a6*inv + bb1.z, a7*inv + bb1.w);
    ((uint4*)y1b)[(long)i*32 + lh] = o;
  }
}

// ---------------- BN column stats (bf16 input, C1 channels) ----------------
__global__ __launch_bounds__(256) void k_colstats1(const ushort_t* __restrict__ y, float* __restrict__ st){
  const uint_t* yu = (const uint_t*)y;
  int c2 = threadIdx.x & 127, half = threadIdx.x >> 7;
  long r0 = (long)blockIdx.x * 128;
  float s0=0,q0=0,s1=0,q1=0;
  for (int r = half; r < 128; r += 2){
    long rr = r0 + r;
    if (rr < N_NODES){
      uint_t u = yu[rr*128 + c2];
      float a = bflo(u), b = bfhi(u);
      s0 += a; q0 += a*a; s1 += b; q1 += b*b;
    }
  }
  int c = c2*2;
  atomicAdd(&st[c], s0);      atomicAdd(&st[C1 + c], q0);
  atomicAdd(&st[c+1], s1);    atomicAdd(&st[C1 + c+1], q1);
}

// ---------------- BN column stats (f32 input) ----------------
template<int C, int RPB>
__global__ __launch_bounds__(256) void k_colstats(const float* __restrict__ y, float* __restrict__ st){
  int c = threadIdx.x % C;
  int rl = threadIdx.x / C;
  const int rpb = 256 / C;
  long r0 = (long)blockIdx.x * RPB;
  float s = 0.f, q = 0.f;
  for (int r = rl; r < RPB; r += rpb){
    long rr = r0 + r;
    if (rr < N_NODES){ float v = y[rr*C + c]; s += v; q += v*v; }
  }
  atomicAdd(&st[c], s); atomicAdd(&st[C + c], q);
}

// ---------------- K6: h2 = relu(bn(y1)) @ W2 (bf16 out) + fused es2/ed2; BN prep inlined ----------------
__global__ __launch_bounds__(256) void k_gemm2(const ushort_t* __restrict__ y1b, const float* __restrict__ W2,
    const float* __restrict__ st1, const float* __restrict__ g1, const float* __restrict__ be1,
    const float* __restrict__ a2s, const float* __restrict__ a2d,
    ushort_t* __restrict__ h2b, float* __restrict__ es2, float* __restrict__ ed2){
  __shared__ float As[64][68];
  __shared__ float Bs[64][64];
  __shared__ float as_s[HID], ad_s[HID];
  __shared__ float ss_s[2*C1];
  int t = threadIdx.x;
  if (t < HID){ as_s[t] = a2s[t]; ad_s[t] = a2d[t]; }
  {
    float mean = st1[t] / (float)N_NODES;
    float var  = st1[C1 + t] / (float)N_NODES - mean*mean;
    float sc = g1[t] * rsqrtf(var + BN_EPS);
    ss_s[t] = sc;
    ss_s[C1 + t] = be1[t] - mean*sc;
  }
  int tx = t & 15, ty = t >> 4;
  long i0 = (long)blockIdx.x * 64;
  float acc[4][4] = {};
  __syncthreads();
  for (int kc = 0; kc < C1; kc += 64){
    const uint_t* yu = (const uint_t*)y1b;
    for (int idx = t; idx < 64*32; idx += 256){
      int r = idx >> 5, k2 = idx & 31;
      long gi = i0 + r;
      int k = kc + k2*2;
      float v0 = 0.f, v1 = 0.f;
      if (gi < N_NODES){
        uint_t u = yu[gi*128 + (k >> 1)];
        v0 = fmaxf(bflo(u)*ss_s[k]   + ss_s[C1+k],   0.f);
        v1 = fmaxf(bfhi(u)*ss_s[k+1] + ss_s[C1+k+1], 0.f);
      }
      As[r][k2*2]   = v0;
      As[r][k2*2+1] = v1;
    }
    for (int idx = t; idx < 64*64; idx += 256){
      Bs[idx >> 6][idx & 63] = W2[(kc + (idx >> 6))*HID + (idx & 63)];
    }
    __syncthreads();
    #pragma unroll 4
    for (int kk = 0; kk < 64; kk += 4){
      float4 va0 = *(float4*)&As[4*ty+0][kk];
      float4 va1 = *(float4*)&As[4*ty+1][kk];
      float4 va2 = *(float4*)&As[4*ty+2][kk];
      float4 va3 = *(float4*)&As[4*ty+3][kk];
      float4 vb0 = *(float4*)&Bs[kk+0][4*tx];
      float4 vb1 = *(float4*)&Bs[kk+1][4*tx];
      float4 vb2 = *(float4*)&Bs[kk+2][4*tx];
      float4 vb3 = *(float4*)&Bs[kk+3][4*tx];
      acc[0][0] += va0.x*vb0.x + va0.y*vb1.x + va0.z*vb2.x + va0.w*vb3.x;
      acc[0][1] += va0.x*vb0.y + va0.y*vb1.y + va0.z*vb2.y + va0.w*vb3.y;
      acc[0][2] += va0.x*vb0.z + va0.y*vb1.z + va0.z*vb2.z + va0.w*vb3.z;
      acc[0][3] += va0.x*vb0.w + va0.y*vb1.w + va0.z*vb2.w + va0.w*vb3.w;
      acc[1][0] += va1.x*vb0.x + va1.y*vb1.x + va1.z*vb2.x + va1.w*vb3.x;
      acc[1][1] += va1.x*vb0.y + va1.y*vb1.y + va1.z*vb2.y + va1.w*vb3.y;
      acc[1][2] += va1.x*vb0.z + va1.y*vb1.z + va1.z*vb2.z + va1.w*vb3.z;
      acc[1][3] += va1.x*vb0.w + va1.y*vb1.w + va1.z*vb2.w + va1.w*vb3.w;
      acc[2][0] += va2.x*vb0.x + va2.y*vb1.x + va2.z*vb2.x + va2.w*vb3.x;
      acc[2][1] += va2.x*vb0.y + va2.y*vb1.y + va2.z*vb2.y + va2.w*vb3.y;
      acc[2][2] += va2.x*vb0.z + va2.y*vb1.z + va2.z*vb2.z + va2.w*vb3.z;
      acc[2][3] += va2.x*vb0.w + va2.y*vb1.w + va2.z*vb2.w + va2.w*vb3.w;
      acc[3][0] += va3.x*vb0.x + va3.y*vb1.x + va3.z*vb2.x + va3.w*vb3.x;
      acc[3][1] += va3.x*vb0.y + va3.y*vb1.y + va3.z*vb2.y + va3.w*vb3.y;
      acc[3][2] += va3.x*vb0.z + va3.y*vb1.z + va3.z*vb2.z + va3.w*vb3.z;
      acc[3][3] += va3.x*vb0.w + va3.y*vb1.w + va3.z*vb2.w + va3.w*vb3.w;
    }
    __syncthreads();
  }
  #pragma unroll
  for (int rr = 0; rr < 4; ++rr){
    long gi = i0 + 4*ty + rr;
    if (gi < N_NODES){
      uint_t p0 = pack2(acc[rr][0], acc[rr][1]);
      uint_t p1 = pack2(acc[rr][2], acc[rr][3]);
      *(uint2*)&h2b[gi*HID + 4*tx] = make_uint2(p0, p1);
      float ps = acc[rr][0]*as_s[4*tx+0] + acc[rr][1]*as_s[4*tx+1]
               + acc[rr][2]*as_s[4*tx+2] + acc[rr][3]*as_s[4*tx+3];
      float pd = acc[rr][0]*ad_s[4*tx+0] + acc[rr][1]*ad_s[4*tx+1]
               + acc[rr][2]*ad_s[4*tx+2] + acc[rr][3]*ad_s[4*tx+3];
      #pragma unroll
      for (int o = 8; o >= 1; o >>= 1){ ps += __shfl_xor(ps,o); pd += __shfl_xor(pd,o); }
      if (tx == 0){ es2[gi] = ps; ed2[gi] = pd; }
    }
  }
}

// ---------------- K7: layer-2 GAT aggregation (unchanged) ----------------
__global__ __launch_bounds__(256) void k_agg2(const ushort_t* __restrict__ h2b,
    const float* __restrict__ es2, const float* __restrict__ ed2,
    const int* __restrict__ off, const int* __restrict__ csr,
    const float* __restrict__ b2, float* __restrict__ y2){
  int lane = threadIdx.x & 63, wid = threadIdx.x >> 6;
  int i = blockIdx.x*4 + wid;
  if (i >= N_NODES) return;
  int lq = lane & 15, q = lane >> 4;
  float edv = ed2[i];
  int start = off[i], end = off[i+1];
  const uint2* h2u2 = (const uint2*)h2b;
  float a0, a1, a2, a3, ssum;
  {
    float wS = (q == 0) ? __expf(leaky(es2[i] + edv)) : 0.f;
    uint2 uS = h2u2[(long)i*16 + lq];
    a0 = bflo(uS.x)*wS; a1 = bfhi(uS.x)*wS; a2 = bflo(uS.y)*wS; a3 = bfhi(uS.y)*wS;
    ssum = wS;
  }
  for (int j0 = start; j0 < end; j0 += 64){
    int nj = end - j0; if (nj > 64) nj = 64;
    int ce = (lane < nj) ? lane : nj - 1;
    int sE = csr[j0 + ce];
    float wv = (lane < nj) ? __expf(leaky(es2[sE] + edv)) : 0.f;
    int jj = 0;
    for (; jj + 16 <= nj; jj += 16){
      int c0 = jj + q, c1 = jj + 4 + q, c2 = jj + 8 + q, c3 = jj + 12 + q;
      int s0 = __shfl(sE, c0);
      int s1 = __shfl(sE, c1);
      int s2 = __shfl(sE, c2);
      int s3 = __shfl(sE, c3);
      uint2 r0 = h2u2[(long)s0*16 + lq];
      uint2 r1 = h2u2[(long)s1*16 + lq];
      uint2 r2 = h2u2[(long)s2*16 + lq];
      uint2 r3 = h2u2[(long)s3*16 + lq];
      float w0 = __shfl(wv, c0);
      float w1 = __shfl(wv, c1);
      float w2 = __shfl(wv, c2);
      float w3 = __shfl(wv, c3);
      a0 += bflo(r0.x)*w0; a1 += bfhi(r0.x)*w0; a2 += bflo(r0.y)*w0; a3 += bfhi(r0.y)*w0;
      a0 += bflo(r1.x)*w1; a1 += bfhi(r1.x)*w1; a2 += bflo(r1.y)*w1; a3 += bfhi(r1.y)*w1;
      a0 += bflo(r2.x)*w2; a1 += bfhi(r2.x)*w2; a2 += bflo(r2.y)*w2; a3 += bfhi(r2.y)*w2;
      a0 += bflo(r3.x)*w3; a1 += bfhi(r3.x)*w3; a2 += bflo(r3.y)*w3; a3 += bfhi(r3.y)*w3;
      ssum += w0 + w1 + w2 + w3;
    }
    for (; jj < nj; jj += 4){
      int slot = jj + q;
      int slc = (slot < nj) ? slot : nj - 1;
      int s = __shfl(sE, slc);
      float w = __shfl(wv, slc);
      if (slot >= nj) w = 0.f;
      uint2 r = h2u2[(long)s*16 + lq];
      a0 += bflo(r.x)*w; a1 += bfhi(r.x)*w; a2 += bflo(r.y)*w; a3 += bfhi(r.y)*w;
      ssum += w;
    }
  }
  a0 += __shfl_xor(a0,16); a1 += __shfl_xor(a1,16); a2 += __shfl_xor(a2,16); a3 += __shfl_xor(a3,16);
  ssum += __shfl_xor(ssum,16);
  a0 += __shfl_xor(a0,32); a1 += __shfl_xor(a1,32); a2 += __shfl_xor(a2,32); a3 += __shfl_xor(a3,32);
  ssum += __shfl_xor(ssum,32);
  if (q == 0){
    float inv = 1.f/(ssum + 1e-16f);
    float4 bb = *(const float4*)&b2[4*lq];
    float4 o;
    o.x = a0*inv + bb.x; o.y = a1*inv + bb.y;
    o.z = a2*inv + bb.z; o.w = a3*inv + bb.w;
    ((float4*)y2)[(long)i*16 + lq] = o;
  }
}

// ---------------- final: tiled GEMM, BN2 prep + climber MLP inlined ----------------
__global__ __launch_bounds__(256) void k_final(const float* __restrict__ y2,
    const float* __restrict__ st2, const float* __restrict__ g2, const float* __restrict__ be2,
    const int* __restrict__ batch,
    const float* __restrict__ cl, const float* __restrict__ Wc, const float* __restrict__ bc,
    const float* __restrict__ Wcl1, const float* __restrict__ bcl1,
    const float* __restrict__ Wcl2, const float* __restrict__ bcl2,
    float* __restrict__ out){
  __shared__ float As[64][132];
  __shared__ float Bs[128][64];
  __shared__ float ss2s[2*HID];
  __shared__ float b1s[HID];
  __shared__ float W2s[HID*D_OUT];
  __shared__ float Wcs[D_CL*HID];
  __shared__ float bcs[HID];
  int t = threadIdx.x;
  long i0 = (long)blockIdx.x * 64;
  if (t < HID){
    float mean = st2[t] / (float)N_NODES;
    float var  = st2[HID + t] / (float)N_NODES - mean*mean;
    float sc = g2[t] * rsqrtf(var + BN_EPS);
    ss2s[t] = sc;
    ss2s[HID + t] = be2[t] - mean*sc;
  }
  if (t >= 64 && t < 128) bcs[t-64] = bc[t-64];
  if (t >= 128 && t < 192) b1s[t-128] = bcl1[t-128];
  W2s[t] = Wcl2[t];
  for (int idx = t; idx < D_CL*HID; idx += 256) Wcs[idx] = Wc[idx];
  __syncthreads();
  const float2* y2v = (const float2*)y2;
  #pragma unroll
  for (int ii = 0; ii < 8; ++ii){
    int idx = t + 256*ii;
    int r = idx >> 5, k2 = idx & 31;
    long gi = i0 + r;
    float2 v = make_float2(0.f, 0.f);
    if (gi < N_NODES) v = y2v[gi*32 + k2];
    int k = k2*2;
    As[r][k]   = fmaxf(v.x*ss2s[k]   + ss2s[HID+k],   0.f);
    As[r][k+1] = fmaxf(v.y*ss2s[k+1] + ss2s[HID+k+1], 0.f);
  }
  #pragma unroll
  for (int ii = 0; ii < 8; ++ii){
    int idx = t + 256*ii;
    int r = idx >> 5, k2 = idx & 31;
    long gi = i0 + r;
    int k = k2*2;
    float c0 = 0.f, c1 = 0.f;
    if (gi < N_NODES){
      int g = batch[gi];
      const float* cg = cl + (long)g*D_CL;
      c0 = bcs[k]; c1 = bcs[k+1];
      #pragma unroll
      for (int kk = 0; kk < D_CL; ++kk){
        float clv = cg[kk];
        c0 += clv*Wcs[kk*HID + k];
        c1 += clv*Wcs[kk*HID + k+1];
      }
      c0 = fmaxf(c0, 0.f); c1 = fmaxf(c1, 0.f);
    }
    As[r][HID + k]   = c0;
    As[r][HID + k+1] = c1;
  }
  #pragma unroll
  for (int ii = 0; ii < 8; ++ii){
    int idx = t + 256*ii;
    int kk = idx >> 4, c4 = idx & 15;
    *(float4*)&Bs[kk][c4*4] = *(const float4*)&Wcl1[kk*64 + c4*4];
  }
  __syncthreads();
  int tx = t & 15, ty = t >> 4;
  float acc[4][4] = {};
  #pragma unroll 4
  for (int kk = 0; kk < 2*HID; kk += 4){
    float4 a0 = *(float4*)&As[4*ty+0][kk];
    float4 a1 = *(float4*)&As[4*ty+1][kk];
    float4 a2 = *(float4*)&As[4*ty+2][kk];
    float4 a3 = *(float4*)&As[4*ty+3][kk];
    float4 b0 = *(float4*)&Bs[kk+0][4*tx];
    float4 b1 = *(float4*)&Bs[kk+1][4*tx];
    float4 b2 = *(float4*)&Bs[kk+2][4*tx];
    float4 b3 = *(float4*)&Bs[kk+3][4*tx];
    acc[0][0] += a0.x*b0.x + a0.y*b1.x + a0.z*b2.x + a0.w*b3.x;
    acc[0][1] += a0.x*b0.y + a0.y*b1.y + a0.z*b2.y + a0.w*b3.y;
    acc[0][2] += a0.x*b0.z + a0.y*b1.z + a0.z*b2.z + a0.w*b3.z;
    acc[0][3] += a0.x*b0.w + a0.y*b1.w + a0.z*b2.w + a0.w*b3.w;
    acc[1][0] += a1.x*b0.x + a1.y*b1.x + a1.z*b2.x + a1.w*b3.x;
    acc[1][1] += a1.x*b0.y + a1.y*b1.y + a1.z*b2.y + a1.w*b3.y;
    acc[1][2] += a1.x*b0.z + a1.y*b1.z + a1.z*b2.z + a1.w*b3.z;
    acc[1][3] += a1.x*b0.w + a1.y*b1.w + a1.z*b2.w + a1.w*b3.w;
    acc[2][0] += a2.x*b0.x + a2.y*b1.x + a2.z*b2.x + a2.w*b3.x;
    acc[2][1] += a2.x*b0.y + a2.y*b1.y + a2.z*b2.y + a2.w*b3.y;
    acc[2][2] += a2.x*b0.z + a2.y*b1.z + a2.z*b2.z + a2.w*b3.z;
    acc[2][3] += a2.x*b0.w + a2.y*b1.w + a2.z*b2.w + a2.w*b3.w;
    acc[3][0] += a3.x*b0.x + a3.y*b1.x + a3.z*b2.x + a3.w*b3.x;
    acc[3][1] += a3.x*b0.y + a3.y*b1.y + a3.z*b2.y + a3.w*b3.y;
    acc[3][2] += a3.x*b0.z + a3.y*b1.z + a3.z*b2.z + a3.w*b3.z;
    acc[3][3] += a3.x*b0.w + a3.y*b1.w + a3.z*b2.w + a3.w*b3.w;
  }
  float p[4][4];
  #pragma unroll
  for (int r = 0; r < 4; ++r){
    #pragma unroll
    for (int c = 0; c < 4; ++c)
      acc[r][c] = fmaxf(acc[r][c] + b1s[4*tx+c], 0.f);
    #pragma unroll
    for (int oc = 0; oc < 4; ++oc){
      p[r][oc] = acc[r][0]*W2s[(4*tx+0)*4+oc] + acc[r][1]*W2s[(4*tx+1)*4+oc]
               + acc[r][2]*W2s[(4*tx+2)*4+oc] + acc[r][3]*W2s[(4*tx+3)*4+oc];
    }
  }
  #pragma unroll
  for (int o = 8; o >= 1; o >>= 1){
    #pragma unroll
    for (int r = 0; r < 4; ++r){
      p[r][0] += __shfl_xor(p[r][0], o);
      p[r][1] += __shfl_xor(p[r][1], o);
      p[r][2] += __shfl_xor(p[r][2], o);
      p[r][3] += __shfl_xor(p[r][3], o);
    }
  }
  if (tx == 0){
    float4 bb = *(const float4*)bcl2;
    #pragma unroll
    for (int r = 0; r < 4; ++r){
      long gi = i0 + 4*ty + r;
      if (gi < N_NODES){
        float4 o;
        o.x = p[r][0] + bb.x; o.y = p[r][1] + bb.y;
        o.z = p[r][2] + bb.z; o.w = p[r][3] + bb.w;
        *(float4*)&out[gi*4] = o;
      }
    }
  }
}

extern "C" void kernel_launch(void* const* d_in, const int* in_sizes, int n_in,
                              void* d_out, int out_size, void* d_ws, size_t ws_size,
                              hipStream_t stream){
  const float* x    = (const float*)d_in[0];
  const float* cl   = (const float*)d_in[1];
  const int*   ei   = (const int*)d_in[2];
  const int*   batch= (const int*)d_in[3];
  const float* W1   = (const float*)d_in[4];
  const float* a1s  = (const float*)d_in[5];
  const float* a1d  = (const float*)d_in[6];
  const float* b1   = (const float*)d_in[7];
  const float* g1   = (const float*)d_in[8];
  const float* be1  = (const float*)d_in[9];
  const float* W2   = (const float*)d_in[10];
  const float* a2s  = (const float*)d_in[11];
  const float* a2d  = (const float*)d_in[12];
  const float* b2   = (const float*)d_in[13];
  const float* g2   = (const float*)d_in[14];
  const float* be2  = (const float*)d_in[15];
  const float* Wc   = (const float*)d_in[16];
  const float* bc   = (const float*)d_in[17];
  const float* Wcl1 = (const float*)d_in[18];
  const float* bcl1 = (const float*)d_in[19];
  const float* Wcl2 = (const float*)d_in[20];
  const float* bcl2 = (const float*)d_in[21];
  const int* srcE = ei;
  const int* dstE = ei + N_EDGES;
  float* out = (float*)d_out;

  char* w = (char*)d_ws;
  auto take = [&](size_t bytes)->char*{ char* p = w; w += (bytes + 255) & ~(size_t)255; return p; };
  ushort_t* h1b = (ushort_t*)take((size_t)50048*C1*2);     // padded to 782*64 rows
  ushort_t* y1b = (ushort_t*)take((size_t)N_NODES*C1*2);   // 25.6 MB bf16
  float* es1 = (float*)take((size_t)50048*NH*4);
  float* ed1 = (float*)take((size_t)50048*NH*4);
  float* es2 = (float*)take((size_t)N_NODES*4);
  float* ed2 = (float*)take((size_t)N_NODES*4);
  float* st  = (float*)take((2*C1 + 2*HID)*4);   // st1 | st2 contiguous -> one memset
  int* cnt  = (int*)take((size_t)CNT_PAD*4);
  int* off  = (int*)take((size_t)(CNT_PAD+16)*4);
  int* csr  = (int*)take((size_t)N_EDGES*4);
  int* rank = (int*)take((size_t)N_EDGES*4);
  float* st1 = st;
  float* st2 = st + 2*C1;
  // alias into dead h1b region after k_agg1: h2b (6.4 MB) at 0, y2 (12.8 MB) at +8 MB
  ushort_t* h2b = h1b;
  float* y2 = (float*)((char*)h1b + ((size_t)8 << 20));

  hipMemsetAsync(cnt, 0, (size_t)CNT_PAD*4, stream);
  hipMemsetAsync(st, 0, (2*C1 + 2*HID)*4, stream);

  k_pre<<<NB_N1 + NB_HIST, 256, 0, stream>>>(x, W1, a1s, a1d, h1b, es1, ed1, dstE, cnt, rank);
  k_scan<<<1, 1024, 0, stream>>>(cnt, off);
  k_scatter<<<(N_EDGES+255)/256, 256, 0, stream>>>(srcE, dstE, rank, off, csr);

  k_agg1<<<(N_NODES+3)/4, 256, 0, stream>>>(h1b, es1, ed1, off, csr, b1, y1b);
  k_colstats1<<<(N_NODES+127)/128, 256, 0, stream>>>(y1b, st1);
  k_gemm2<<<(N_NODES+63)/64, 256, 0, stream>>>(y1b, W2, st1, g1, be1, a2s, a2d, h2b, es2, ed2);
  k_agg2<<<(N_NODES+3)/4, 256, 0, stream>>>(h2b, es2, ed2, off, csr, b2, y2);
  k_colstats<HID,128><<<(N_NODES+127)/128, 256, 0, stream>>>(y2, st2);
  k_final<<<(N_NODES+63)/64, 256, 0, stream>>>(y2, st2, g2, be2, batch, cl, Wc, bc, Wcl1, bcl1, Wcl2, bcl2, out);
}